// Round 1
// baseline (2003.559 us; speedup 1.0000x reference)
//
#include <hip/hip_runtime.h>

#define B_EV 32
#define P_PT 2048
#define K_NN 20
#define NPTS (B_EV*P_PT)
#define EPS_BN 1e-5f
#define RINF 3.0e38f

// ---------------- ws layout (float offsets) ----------------
static constexpr int oWA10=0, oWB10=448, oB10=896, oT10=960,
  oW11=1024, oB11=5120, oT11=5184,
  oW12=5248, oB12=9344, oT12=9408,
  oWA20=9472, oWB20=17664, oB20=25856, oT20=25984;
static constexpr size_t oIDX = 32768;                      // int region, NPTS*20 ints
static constexpr size_t oA1  = 1343488;                    // NPTS*64 f32
static constexpr size_t oB1  = oA1 + (size_t)NPTS*64;      // NPTS*64 f32
static constexpr size_t oV2  = oB1 + (size_t)NPTS*64;      // NPTS*128 f32
static constexpr size_t oX1  = oV2 + (size_t)NPTS*128;     // NPTS*64 f32
static constexpr size_t oSQ  = oX1 + (size_t)NPTS*64;      // NPTS f32
static constexpr size_t oD   = oSQ + (size_t)NPTS;         // chunked 2048x2048 dist buf
static constexpr size_t oU2  = oA1;                        // U2 reuses A1+B1 (after ec1)

// ---------------- BN fold ----------------
__global__ __launch_bounds__(128) void k_prep(
  const float* w10,const float* b10,const float* g10,const float* e10,const float* m10,const float* v10,
  const float* w11,const float* b11,const float* g11,const float* e11,const float* m11,const float* v11,
  const float* w12,const float* b12,const float* g12,const float* e12,const float* m12,const float* v12,
  const float* w20,const float* b20,const float* g20,const float* e20,const float* m20,const float* v20,
  float* ws)
{
  int c = threadIdx.x;
  if (c < 64) {
    float s = g10[c]*rsqrtf(v10[c]+EPS_BN);
    ws[oB10+c]=b10[c]*s; ws[oT10+c]=e10[c]-m10[c]*s;
    for (int i=0;i<7;i++){
      ws[oWA10+i*64+c]=(w10[i*64+c]-w10[(7+i)*64+c])*s;
      ws[oWB10+i*64+c]=w10[(7+i)*64+c]*s;
    }
    float s1 = g11[c]*rsqrtf(v11[c]+EPS_BN);
    ws[oB11+c]=b11[c]*s1; ws[oT11+c]=e11[c]-m11[c]*s1;
    for (int i=0;i<64;i++) ws[oW11+i*64+c]=w11[i*64+c]*s1;
    float s2 = g12[c]*rsqrtf(v12[c]+EPS_BN);
    ws[oB12+c]=b12[c]*s2; ws[oT12+c]=e12[c]-m12[c]*s2;
    for (int i=0;i<64;i++) ws[oW12+i*64+c]=w12[i*64+c]*s2;
  }
  {
    float s = g20[c]*rsqrtf(v20[c]+EPS_BN);
    ws[oB20+c]=b20[c]*s; ws[oT20+c]=e20[c]-m20[c]*s;
    for (int i=0;i<64;i++){
      ws[oWA20+i*128+c]=(w20[i*128+c]-w20[(64+i)*128+c])*s;
      ws[oWB20+i*128+c]=w20[(64+i)*128+c]*s;
    }
  }
}

// ---------------- exact top-20 per wave (point), d[32] in regs ----------------
__device__ __forceinline__ void select20(float (&d)[32], int lane, int base, int g,
                                         int* __restrict__ idxout)
{
  float g4[4];
  #pragma unroll
  for (int k=0;k<4;k++){
    float m = d[8*k];
    #pragma unroll
    for (int j=1;j<8;j++) m = fminf(m, d[8*k+j]);
    g4[k]=m;
  }
  float T = 0.f;
  #pragma unroll 1
  for (int pass=0; pass<20; ++pass){
    float m = fminf(fminf(g4[0],g4[1]), fminf(g4[2],g4[3]));
    #pragma unroll
    for (int off=32; off>0; off>>=1) m = fminf(m, __shfl_xor(m, off, 64));
    if (pass==19){ T=m; break; }
    #pragma unroll
    for (int k=0;k<4;k++){
      if (g4[k]==m){
        #pragma unroll
        for (int j=0;j<8;j++) d[8*k+j] = (d[8*k+j]==m) ? RINF : d[8*k+j];
        float mm = d[8*k];
        #pragma unroll
        for (int j=1;j<8;j++) mm = fminf(mm, d[8*k+j]);
        g4[k]=mm;
      }
    }
  }
  int cnt=0;
  #pragma unroll
  for (int j=0;j<32;j++){
    bool take = (d[j]>=RINF) || (d[j]==T);
    unsigned long long mb = __ballot(take);
    if (take){
      int pos = cnt + (int)__popcll(mb & ((1ull<<lane)-1ull));
      if (pos < K_NN) idxout[(size_t)g*K_NN + pos] = base + j*64 + lane;
    }
    cnt += (int)__popcll(mb);
  }
  if (lane==0){
    for (int r=cnt; r<K_NN; ++r) idxout[(size_t)g*K_NN + r] = g;  // dup-self fallback (harmless under max)
  }
}

// ---------------- kNN on x (C=7), wave per point, event staged in LDS ----------------
__global__ __launch_bounds__(256) void k_knn1(const float* __restrict__ x, int* __restrict__ idxout)
{
  __shared__ float xs[P_PT*7];
  int t = threadIdx.x;
  int e = (int)(blockIdx.x >> 9);                  // 4 points/block, 512 blocks/event
  const float4* src = (const float4*)(x + (size_t)e*P_PT*7);
  #pragma unroll
  for (int u=0;u<14;u++) ((float4*)xs)[u*256+t] = src[u*256+t];
  __syncthreads();
  int lane = t & 63;
  int g = blockIdx.x*4 + (t>>6);
  int pin = g & (P_PT-1);
  float xp[7];
  #pragma unroll
  for (int i=0;i<7;i++) xp[i]=xs[pin*7+i];
  float d[32];
  #pragma unroll
  for (int j=0;j<32;j++){
    const float* xq = xs + (j*64+lane)*7;
    float s=0.f;
    #pragma unroll
    for (int i=0;i<7;i++){ float df=xp[i]-xq[i]; s=fmaf(df,df,s); }
    d[j]=s;
  }
  select20(d, lane, e*P_PT, g, idxout);
}

// ---------------- A/B precompute for EdgeConv1 layer 1 ----------------
__global__ __launch_bounds__(256) void k_ab1(const float* __restrict__ x, const float* __restrict__ W,
                                             float* __restrict__ A1, float* __restrict__ B1)
{
  int g = blockIdx.x*256+threadIdx.x;
  float xi[7];
  #pragma unroll
  for (int i=0;i<7;i++) xi[i]=x[(size_t)g*7+i];
  float a[64], b[64];
  #pragma unroll
  for (int c=0;c<64;c++){ a[c]=W[oB10+c]; b[c]=0.f; }
  #pragma unroll
  for (int i=0;i<7;i++){
    #pragma unroll
    for (int c=0;c<64;c++) a[c]=fmaf(xi[i], W[oWA10+i*64+c], a[c]);
    #pragma unroll
    for (int c=0;c<64;c++) b[c]=fmaf(xi[i], W[oWB10+i*64+c], b[c]);
  }
  #pragma unroll
  for (int c=0;c<64;c+=4){
    float4 oa; oa.x=a[c]; oa.y=a[c+1]; oa.z=a[c+2]; oa.w=a[c+3];
    *(float4*)(A1+(size_t)g*64+c)=oa;
    float4 ob; ob.x=b[c]; ob.y=b[c+1]; ob.z=b[c+2]; ob.w=b[c+3];
    *(float4*)(B1+(size_t)g*64+c)=ob;
  }
}

// ---------------- EdgeConv1: MLP layers 2,3 + max-aggr; thread per point ----------------
__global__ __launch_bounds__(64) void k_ec1(const int* __restrict__ idx, const float* __restrict__ W,
    const float* __restrict__ A1, const float* __restrict__ B1,
    float* __restrict__ x1, float* __restrict__ sqv, float* __restrict__ out)
{
  __shared__ float h2s[64][64];     // per-thread column scratch (no cross-thread use)
  int tid = threadIdx.x;
  int g = blockIdx.x*64 + tid;
  float mx[64];
  #pragma unroll
  for (int c=0;c<64;c++) mx[c]=-RINF;
  const float* Ap = A1 + (size_t)g*64;
  for (int k=0;k<K_NN;k++){
    int j = idx[(size_t)g*K_NN+k];
    const float* Bp = B1 + (size_t)j*64;
    float acc[64];
    #pragma unroll
    for (int c=0;c<64;c++) acc[c]=W[oB11+c];
    #pragma unroll 1
    for (int i=0;i<64;i+=4){
      float4 a4 = *(const float4*)(Ap+i);
      float4 b4 = *(const float4*)(Bp+i);
      float h0 = fmaxf(a4.x+b4.x,0.f)+W[oT10+i+0];
      float h1 = fmaxf(a4.y+b4.y,0.f)+W[oT10+i+1];
      float h2 = fmaxf(a4.z+b4.z,0.f)+W[oT10+i+2];
      float h3 = fmaxf(a4.w+b4.w,0.f)+W[oT10+i+3];
      #pragma unroll
      for (int c=0;c<64;c++) acc[c]=fmaf(h0, W[oW11+(i+0)*64+c], acc[c]);
      #pragma unroll
      for (int c=0;c<64;c++) acc[c]=fmaf(h1, W[oW11+(i+1)*64+c], acc[c]);
      #pragma unroll
      for (int c=0;c<64;c++) acc[c]=fmaf(h2, W[oW11+(i+2)*64+c], acc[c]);
      #pragma unroll
      for (int c=0;c<64;c++) acc[c]=fmaf(h3, W[oW11+(i+3)*64+c], acc[c]);
    }
    #pragma unroll
    for (int c=0;c<64;c++) h2s[c][tid] = fmaxf(acc[c],0.f)+W[oT11+c];
    #pragma unroll
    for (int c=0;c<64;c++) acc[c]=W[oB12+c];
    #pragma unroll 1
    for (int i=0;i<64;i++){
      float h = h2s[i][tid];
      #pragma unroll
      for (int c=0;c<64;c++) acc[c]=fmaf(h, W[oW12+i*64+c], acc[c]);
    }
    #pragma unroll
    for (int c=0;c<64;c++) mx[c]=fmaxf(mx[c], fmaxf(acc[c],0.f)+W[oT12+c]);
  }
  float sq=0.f;
  #pragma unroll
  for (int c=0;c<64;c++){
    x1[(size_t)g*64+c]=mx[c];
    out[(size_t)g*192+c]=mx[c];
    sq = fmaf(mx[c],mx[c],sq);
  }
  sqv[g]=sq;
}

// ---------------- kNN2 distance GEMM: D = sq_p + sq_q - 2*x1@x1^T, per-event chunk ----------------
__global__ __launch_bounds__(256) void k_dist2(const float* __restrict__ x1, const float* __restrict__ sqv,
                                               float* __restrict__ D, int e0)
{
  __shared__ float As[64][65], Bs[64][65];
  int e = e0 + blockIdx.z;
  const float* Xe = x1 + (size_t)e*P_PT*64;
  int rb = blockIdx.y*64, cb = blockIdx.x*64;
  int t = threadIdx.x;
  int tr = t>>4, tk=(t&15)*4;
  #pragma unroll
  for (int rr=0;rr<4;rr++){
    int r = tr + 16*rr;
    float4 va = *(const float4*)(Xe + (size_t)(rb+r)*64 + tk);
    As[r][tk]=va.x; As[r][tk+1]=va.y; As[r][tk+2]=va.z; As[r][tk+3]=va.w;
    float4 vb = *(const float4*)(Xe + (size_t)(cb+r)*64 + tk);
    Bs[r][tk]=vb.x; Bs[r][tk+1]=vb.y; Bs[r][tk+2]=vb.z; Bs[r][tk+3]=vb.w;
  }
  __syncthreads();
  int tx=t&15, ty=t>>4;
  float acc[4][4];
  #pragma unroll
  for (int i=0;i<4;i++){
    #pragma unroll
    for (int j=0;j<4;j++) acc[i][j]=0.f;
  }
  #pragma unroll 2
  for (int k=0;k<64;k++){
    float a0=As[ty*4+0][k], a1=As[ty*4+1][k], a2=As[ty*4+2][k], a3=As[ty*4+3][k];
    float b0=Bs[tx*4+0][k], b1=Bs[tx*4+1][k], b2=Bs[tx*4+2][k], b3=Bs[tx*4+3][k];
    acc[0][0]=fmaf(a0,b0,acc[0][0]); acc[0][1]=fmaf(a0,b1,acc[0][1]);
    acc[0][2]=fmaf(a0,b2,acc[0][2]); acc[0][3]=fmaf(a0,b3,acc[0][3]);
    acc[1][0]=fmaf(a1,b0,acc[1][0]); acc[1][1]=fmaf(a1,b1,acc[1][1]);
    acc[1][2]=fmaf(a1,b2,acc[1][2]); acc[1][3]=fmaf(a1,b3,acc[1][3]);
    acc[2][0]=fmaf(a2,b0,acc[2][0]); acc[2][1]=fmaf(a2,b1,acc[2][1]);
    acc[2][2]=fmaf(a2,b2,acc[2][2]); acc[2][3]=fmaf(a2,b3,acc[2][3]);
    acc[3][0]=fmaf(a3,b0,acc[3][0]); acc[3][1]=fmaf(a3,b1,acc[3][1]);
    acc[3][2]=fmaf(a3,b2,acc[3][2]); acc[3][3]=fmaf(a3,b3,acc[3][3]);
  }
  float sr[4], sc[4];
  #pragma unroll
  for (int i=0;i<4;i++){ sr[i]=sqv[e*P_PT + rb+ty*4+i]; sc[i]=sqv[e*P_PT + cb+tx*4+i]; }
  #pragma unroll
  for (int i=0;i<4;i++){
    float4 o;
    o.x = sr[i]+sc[0]-2.f*acc[i][0];
    o.y = sr[i]+sc[1]-2.f*acc[i][1];
    o.z = sr[i]+sc[2]-2.f*acc[i][2];
    o.w = sr[i]+sc[3]-2.f*acc[i][3];
    *(float4*)(D + (size_t)(blockIdx.z*P_PT + rb+ty*4+i)*P_PT + cb + tx*4) = o;
  }
}

// ---------------- kNN2 selection: wave per point, coalesced D-row read ----------------
__global__ __launch_bounds__(256) void k_sel2(const float* __restrict__ D, int* __restrict__ idxout, int e0)
{
  int t=threadIdx.x, lane=t&63;
  int pl = blockIdx.x*4 + (t>>6);                  // chunk-local point
  int le = pl>>11, pin = pl&(P_PT-1);
  int e = e0 + le;
  int g = e*P_PT + pin;
  const float* Dr = D + (size_t)pl*P_PT;
  float d[32];
  #pragma unroll
  for (int j=0;j<32;j++) d[j]=Dr[j*64+lane];
  select20(d, lane, e*P_PT, g, idxout);
}

// ---------------- EdgeConv2: U = x1@(Wt-Wb)+b, V = x1@Wb ----------------
__global__ __launch_bounds__(256) void k_uv2(const float* __restrict__ x1, const float* __restrict__ W,
                                             float* __restrict__ U2, float* __restrict__ V2)
{
  int g = blockIdx.x*256 + threadIdx.x;
  int half = blockIdx.y & 1;
  bool isU = blockIdx.y < 2;
  const float* Wb = W + (isU?oWA20:oWB20) + half*64;
  float acc[64];
  #pragma unroll
  for (int c=0;c<64;c++) acc[c] = isU ? W[oB20+half*64+c] : 0.f;
  const float* xp = x1 + (size_t)g*64;
  #pragma unroll 1
  for (int i=0;i<64;i+=4){
    float4 xv = *(const float4*)(xp+i);
    #pragma unroll
    for (int c=0;c<64;c++) acc[c]=fmaf(xv.x, Wb[(i+0)*128+c], acc[c]);
    #pragma unroll
    for (int c=0;c<64;c++) acc[c]=fmaf(xv.y, Wb[(i+1)*128+c], acc[c]);
    #pragma unroll
    for (int c=0;c<64;c++) acc[c]=fmaf(xv.z, Wb[(i+2)*128+c], acc[c]);
    #pragma unroll
    for (int c=0;c<64;c++) acc[c]=fmaf(xv.w, Wb[(i+3)*128+c], acc[c]);
  }
  float* dst = (isU?U2:V2) + (size_t)g*128 + half*64;
  #pragma unroll
  for (int c=0;c<64;c+=4){
    float4 o; o.x=acc[c]; o.y=acc[c+1]; o.z=acc[c+2]; o.w=acc[c+3];
    *(float4*)(dst+c)=o;
  }
}

// ---------------- EdgeConv2 gather-max + epilogue: x2 = relu(U + max V_j) + t ----------------
__global__ __launch_bounds__(256) void k_gather2(const int* __restrict__ idx, const float* __restrict__ U2,
     const float* __restrict__ V2, const float* __restrict__ W, float* __restrict__ out)
{
  int g = blockIdx.x*256 + threadIdx.x;
  int half = blockIdx.y;
  float mx[64];
  #pragma unroll
  for (int c=0;c<64;c++) mx[c]=-RINF;
  for (int k=0;k<K_NN;k++){
    int j = idx[(size_t)g*K_NN+k];
    const float4* vp = (const float4*)(V2 + (size_t)j*128 + half*64);
    #pragma unroll
    for (int c4=0;c4<16;c4++){
      float4 v=vp[c4];
      mx[c4*4+0]=fmaxf(mx[c4*4+0],v.x);
      mx[c4*4+1]=fmaxf(mx[c4*4+1],v.y);
      mx[c4*4+2]=fmaxf(mx[c4*4+2],v.z);
      mx[c4*4+3]=fmaxf(mx[c4*4+3],v.w);
    }
  }
  const float* Up = U2 + (size_t)g*128 + half*64;
  float* op = out + (size_t)g*192 + 64 + half*64;
  #pragma unroll
  for (int c=0;c<64;c+=4){
    float4 o;
    o.x = fmaxf(Up[c+0]+mx[c+0],0.f)+W[oT20+half*64+c+0];
    o.y = fmaxf(Up[c+1]+mx[c+1],0.f)+W[oT20+half*64+c+1];
    o.z = fmaxf(Up[c+2]+mx[c+2],0.f)+W[oT20+half*64+c+2];
    o.w = fmaxf(Up[c+3]+mx[c+3],0.f)+W[oT20+half*64+c+3];
    *(float4*)(op+c)=o;
  }
}

// ---------------- batch passthrough (harness reads whole out buffer as f32) ----------------
__global__ __launch_bounds__(256) void k_batchf(const int* __restrict__ batch, float* __restrict__ out){
  int i = blockIdx.x*256+threadIdx.x;
  out[(size_t)NPTS*192 + i] = (float)batch[i];
}

extern "C" void kernel_launch(void* const* d_in, const int* in_sizes, int n_in,
                              void* d_out, int out_size, void* d_ws, size_t ws_size,
                              hipStream_t stream)
{
  const float* x     = (const float*)d_in[0];
  const int*   batch = (const int*)d_in[1];
  const float* w10=(const float*)d_in[2],  *b10=(const float*)d_in[3],  *g10=(const float*)d_in[4],
             *e10=(const float*)d_in[5],  *m10=(const float*)d_in[6],  *v10=(const float*)d_in[7];
  const float* w11=(const float*)d_in[8],  *b11=(const float*)d_in[9],  *g11=(const float*)d_in[10],
             *e11=(const float*)d_in[11], *m11=(const float*)d_in[12], *v11=(const float*)d_in[13];
  const float* w12=(const float*)d_in[14], *b12=(const float*)d_in[15], *g12=(const float*)d_in[16],
             *e12=(const float*)d_in[17], *m12=(const float*)d_in[18], *v12=(const float*)d_in[19];
  const float* w20=(const float*)d_in[20], *b20=(const float*)d_in[21], *g20=(const float*)d_in[22],
             *e20=(const float*)d_in[23], *m20=(const float*)d_in[24], *v20=(const float*)d_in[25];

  float* ws  = (float*)d_ws;
  float* out = (float*)d_out;
  int*   idxp = (int*)(ws + oIDX);

  k_prep<<<1,128,0,stream>>>(w10,b10,g10,e10,m10,v10, w11,b11,g11,e11,m11,v11,
                             w12,b12,g12,e12,m12,v12, w20,b20,g20,e20,m20,v20, ws);
  k_knn1<<<NPTS/4, 256, 0, stream>>>(x, idxp);
  k_ab1<<<NPTS/256, 256, 0, stream>>>(x, ws, ws+oA1, ws+oB1);
  k_ec1<<<NPTS/64, 64, 0, stream>>>(idxp, ws, ws+oA1, ws+oB1, ws+oX1, ws+oSQ, out);

  // kNN2 in event chunks sized to available workspace
  size_t wsFloats = ws_size/4;
  long avail = (long)wsFloats - (long)oD;
  int CE = (int)(avail / (2048L*2048L));
  if (CE < 1) CE = 1;
  if (CE > 8) CE = 8;
  for (int e0=0; e0<B_EV; e0+=CE){
    int ce = (B_EV - e0 < CE) ? (B_EV - e0) : CE;
    k_dist2<<<dim3(32,32,ce),256,0,stream>>>(ws+oX1, ws+oSQ, ws+oD, e0);
    k_sel2<<<ce*512,256,0,stream>>>(ws+oD, idxp, e0);
  }

  k_uv2<<<dim3(NPTS/256,4),256,0,stream>>>(ws+oX1, ws, ws+oU2, ws+oV2);
  k_gather2<<<dim3(NPTS/256,2),256,0,stream>>>(idxp, ws+oU2, ws+oV2, ws, out);
  k_batchf<<<NPTS/256,256,0,stream>>>(batch, out);
}

// Round 4
// 1524.525 us; speedup vs baseline: 1.3142x; 1.3142x over previous
//
#include <hip/hip_runtime.h>

#define B_EV 32
#define P_PT 2048
#define K_NN 20
#define NPTS (B_EV*P_PT)
#define EPS_BN 1e-5f
#define RINF 3.0e38f

typedef _Float16 half8 __attribute__((ext_vector_type(8)));
typedef float f32x4 __attribute__((ext_vector_type(4)));

// ---------------- ws layout (float offsets) ----------------
static constexpr int oWA10=0, oWB10=448, oB10=896, oT10=960,
  oT11=5184,
  oT12=9408,
  oWA20=9472, oWB20=17664, oB20=25856, oT20=25984,
  oB11p=26048, oB12p=26112,
  oW11hi=26176, oW11lo=28224,   // each 64x64 f16 == 2048 floats, layout [n][k]
  oW12hi=30272, oW12lo=32320;
static constexpr size_t oIDX = 36864;                      // int region, NPTS*20 ints
static constexpr size_t oA1  = 1347584;                    // NPTS*64 f32
static constexpr size_t oB1  = oA1 + (size_t)NPTS*64;
static constexpr size_t oV2  = oB1 + (size_t)NPTS*64;      // NPTS*128 f32
static constexpr size_t oX1  = oV2 + (size_t)NPTS*128;     // NPTS*64 f32
static constexpr size_t oSQ  = oX1 + (size_t)NPTS*64;      // NPTS f32
static constexpr size_t oD   = oSQ + (size_t)NPTS;         // chunked 2048x2048 dist buf
static constexpr size_t oU2  = oA1;                        // U2 reuses A1+B1 (after ec1)

// ---------------- BN fold + split-f16 weight prep ----------------
__global__ __launch_bounds__(128) void k_prep(
  const float* w10,const float* b10,const float* g10,const float* e10,const float* m10,const float* v10,
  const float* w11,const float* b11,const float* g11,const float* e11,const float* m11,const float* v11,
  const float* w12,const float* b12,const float* g12,const float* e12,const float* m12,const float* v12,
  const float* w20,const float* b20,const float* g20,const float* e20,const float* m20,const float* v20,
  float* ws)
{
  __shared__ float t10s[64], t11s[64];
  int c = threadIdx.x;
  if (c < 64) {
    float s0 = g10[c]*rsqrtf(v10[c]+EPS_BN);
    ws[oB10+c]=b10[c]*s0;
    float t10 = e10[c]-m10[c]*s0; ws[oT10+c]=t10; t10s[c]=t10;
    for (int i=0;i<7;i++){
      ws[oWA10+i*64+c]=(w10[i*64+c]-w10[(7+i)*64+c])*s0;
      ws[oWB10+i*64+c]=w10[(7+i)*64+c]*s0;
    }
    float s1 = g11[c]*rsqrtf(v11[c]+EPS_BN);
    float t11 = e11[c]-m11[c]*s1; ws[oT11+c]=t11; t11s[c]=t11;
    float s2 = g12[c]*rsqrtf(v12[c]+EPS_BN);
    ws[oT12+c]=e12[c]-m12[c]*s2;
  }
  __syncthreads();
  if (c < 64) {
    float s1 = g11[c]*rsqrtf(v11[c]+EPS_BN);
    _Float16* W1hi = (_Float16*)(ws + oW11hi);
    _Float16* W1lo = (_Float16*)(ws + oW11lo);
    float acc = b11[c]*s1;
    for (int i=0;i<64;i++){
      float wv = w11[i*64+c]*s1;
      _Float16 h = (_Float16)wv;
      W1hi[c*64+i] = h;                       // [n=c][k=i]
      W1lo[c*64+i] = (_Float16)(wv - (float)h);
      acc = fmaf(t10s[i], wv, acc);
    }
    ws[oB11p+c]=acc;
    float s2 = g12[c]*rsqrtf(v12[c]+EPS_BN);
    _Float16* W2hi = (_Float16*)(ws + oW12hi);
    _Float16* W2lo = (_Float16*)(ws + oW12lo);
    float acc2 = b12[c]*s2;
    for (int i=0;i<64;i++){
      float wv = w12[i*64+c]*s2;
      _Float16 h = (_Float16)wv;
      W2hi[c*64+i] = h;
      W2lo[c*64+i] = (_Float16)(wv - (float)h);
      acc2 = fmaf(t11s[i], wv, acc2);
    }
    ws[oB12p+c]=acc2;
  }
  {
    float s = g20[c]*rsqrtf(v20[c]+EPS_BN);
    ws[oB20+c]=b20[c]*s; ws[oT20+c]=e20[c]-m20[c]*s;
    for (int i=0;i<64;i++){
      ws[oWA20+i*128+c]=(w20[i*128+c]-w20[(64+i)*128+c])*s;
      ws[oWB20+i*128+c]=w20[(64+i)*128+c]*s;
    }
  }
}

// ---------------- exact top-20 per wave (point), d[32] in regs ----------------
__device__ __forceinline__ void select20(float (&d)[32], int lane, int base, int g,
                                         int* __restrict__ idxout)
{
  float g4[4];
  #pragma unroll
  for (int k=0;k<4;k++){
    float m = d[8*k];
    #pragma unroll
    for (int j=1;j<8;j++) m = fminf(m, d[8*k+j]);
    g4[k]=m;
  }
  float T = 0.f;
  #pragma unroll 1
  for (int pass=0; pass<20; ++pass){
    float m = fminf(fminf(g4[0],g4[1]), fminf(g4[2],g4[3]));
    #pragma unroll
    for (int off=32; off>0; off>>=1) m = fminf(m, __shfl_xor(m, off, 64));
    if (pass==19){ T=m; break; }
    #pragma unroll
    for (int k=0;k<4;k++){
      if (g4[k]==m){
        #pragma unroll
        for (int j=0;j<8;j++) d[8*k+j] = (d[8*k+j]==m) ? RINF : d[8*k+j];
        float mm = d[8*k];
        #pragma unroll
        for (int j=1;j<8;j++) mm = fminf(mm, d[8*k+j]);
        g4[k]=mm;
      }
    }
  }
  int cnt=0;
  #pragma unroll
  for (int j=0;j<32;j++){
    bool take = (d[j]>=RINF) || (d[j]==T);
    unsigned long long mb = __ballot(take);
    if (take){
      int pos = cnt + (int)__popcll(mb & ((1ull<<lane)-1ull));
      if (pos < K_NN) idxout[(size_t)g*K_NN + pos] = base + j*64 + lane;
    }
    cnt += (int)__popcll(mb);
  }
  if (lane==0){
    for (int r=cnt; r<K_NN; ++r) idxout[(size_t)g*K_NN + r] = g;
  }
}

// ---------------- kNN on x (C=7), wave per point, event staged in LDS ----------------
__global__ __launch_bounds__(256) void k_knn1(const float* __restrict__ x, int* __restrict__ idxout)
{
  __shared__ float xs[P_PT*7];
  int t = threadIdx.x;
  int e = (int)(blockIdx.x >> 9);
  const float4* src = (const float4*)(x + (size_t)e*P_PT*7);
  #pragma unroll
  for (int u=0;u<14;u++) ((float4*)xs)[u*256+t] = src[u*256+t];
  __syncthreads();
  int lane = t & 63;
  int g = blockIdx.x*4 + (t>>6);
  int pin = g & (P_PT-1);
  float xp[7];
  #pragma unroll
  for (int i=0;i<7;i++) xp[i]=xs[pin*7+i];
  float d[32];
  #pragma unroll
  for (int j=0;j<32;j++){
    const float* xq = xs + (j*64+lane)*7;
    float s=0.f;
    #pragma unroll
    for (int i=0;i<7;i++){ float df=xp[i]-xq[i]; s=fmaf(df,df,s); }
    d[j]=s;
  }
  select20(d, lane, e*P_PT, g, idxout);
}

// ---------------- A/B precompute for EdgeConv1 layer 1 ----------------
__global__ __launch_bounds__(256) void k_ab1(const float* __restrict__ x, const float* __restrict__ W,
                                             float* __restrict__ A1, float* __restrict__ B1)
{
  int g = blockIdx.x*256+threadIdx.x;
  float xi[7];
  #pragma unroll
  for (int i=0;i<7;i++) xi[i]=x[(size_t)g*7+i];
  float a[64], b[64];
  #pragma unroll
  for (int c=0;c<64;c++){ a[c]=W[oB10+c]; b[c]=0.f; }
  #pragma unroll
  for (int i=0;i<7;i++){
    #pragma unroll
    for (int c=0;c<64;c++) a[c]=fmaf(xi[i], W[oWA10+i*64+c], a[c]);
    #pragma unroll
    for (int c=0;c<64;c++) b[c]=fmaf(xi[i], W[oWB10+i*64+c], b[c]);
  }
  #pragma unroll
  for (int c=0;c<64;c+=4){
    float4 oa; oa.x=a[c]; oa.y=a[c+1]; oa.z=a[c+2]; oa.w=a[c+3];
    *(float4*)(A1+(size_t)g*64+c)=oa;
    float4 ob; ob.x=b[c]; ob.y=b[c+1]; ob.z=b[c+2]; ob.w=b[c+3];
    *(float4*)(B1+(size_t)g*64+c)=ob;
  }
}

// ---------------- EdgeConv1 via split-f16 MFMA: wave per point ----------------
// a = a_hi + a_lo (f16 pair, ~22 mantissa bits); acc += ah*wh + al*wh + ah*wl
__global__ __launch_bounds__(256) void k_ec1m(const int* __restrict__ idx, const float* __restrict__ ws,
    const float* __restrict__ A1, const float* __restrict__ B1,
    float* __restrict__ x1, float* __restrict__ sqv, float* __restrict__ out)
{
  __shared__ _Float16 h2hi[4][32*64];   // per-wave swizzled H2 hi (4KB each)
  __shared__ _Float16 h2lo[4][32*64];   // per-wave swizzled H2 lo
  int t = threadIdx.x, w = t>>6, lane = t&63;
  int i = blockIdx.x*4 + w;
  int lg = lane>>4, lr = lane&15;

  int j0 = idx[(size_t)i*K_NN + lr];
  int j1 = (lr < 4) ? idx[(size_t)i*K_NN + 16 + lr] : i;   // rows 20..31 pad (masked later)

  // ---- GEMM1: H1(relu-only) @ W11' ----
  f32x4 acc[2][4];
  #pragma unroll
  for (int nt=0;nt<4;nt++){
    float bb = ws[oB11p + nt*16 + lr];
    f32x4 v = {bb,bb,bb,bb};
    acc[0][nt]=v; acc[1][nt]=v;
  }
  {
    const _Float16* W1hi = (const _Float16*)(ws + oW11hi);
    const _Float16* W1lo = (const _Float16*)(ws + oW11lo);
    half8 wh[4][2], wl[4][2];
    #pragma unroll
    for (int nt=0;nt<4;nt++){
      #pragma unroll
      for (int ks=0;ks<2;ks++){
        wh[nt][ks] = *(const half8*)(W1hi + (nt*16+lr)*64 + ks*32 + lg*8);
        wl[nt][ks] = *(const half8*)(W1lo + (nt*16+lr)*64 + ks*32 + lg*8);
      }
    }
    const float* Ap = A1 + (size_t)i*64;
    #pragma unroll
    for (int m=0;m<2;m++){
      const float* Bp = B1 + (size_t)(m ? j1 : j0)*64;
      #pragma unroll
      for (int ks=0;ks<2;ks++){
        int c0 = ks*32 + lg*8;
        float4 b0 = *(const float4*)(Bp+c0);
        float4 b1 = *(const float4*)(Bp+c0+4);
        float4 a0 = *(const float4*)(Ap+c0);
        float4 a1 = *(const float4*)(Ap+c0+4);
        float hv[8];
        hv[0]=fmaxf(a0.x+b0.x,0.f); hv[1]=fmaxf(a0.y+b0.y,0.f);
        hv[2]=fmaxf(a0.z+b0.z,0.f); hv[3]=fmaxf(a0.w+b0.w,0.f);
        hv[4]=fmaxf(a1.x+b1.x,0.f); hv[5]=fmaxf(a1.y+b1.y,0.f);
        hv[6]=fmaxf(a1.z+b1.z,0.f); hv[7]=fmaxf(a1.w+b1.w,0.f);
        half8 ah, al;
        #pragma unroll
        for (int q=0;q<8;q++){
          _Float16 h = (_Float16)hv[q];
          ah[q]=h; al[q]=(_Float16)(hv[q]-(float)h);
        }
        #pragma unroll
        for (int nt=0;nt<4;nt++){
          acc[m][nt] = __builtin_amdgcn_mfma_f32_16x16x32_f16(ah, wh[nt][ks], acc[m][nt], 0,0,0);
          acc[m][nt] = __builtin_amdgcn_mfma_f32_16x16x32_f16(al, wh[nt][ks], acc[m][nt], 0,0,0);
          acc[m][nt] = __builtin_amdgcn_mfma_f32_16x16x32_f16(ah, wl[nt][ks], acc[m][nt], 0,0,0);
        }
      }
    }
  }

  // ---- H2 -> LDS (swizzled hi/lo), relu only (t11 folded into B12p) ----
  _Float16* hbh = h2hi[w];
  _Float16* hbl = h2lo[w];
  #pragma unroll
  for (int m=0;m<2;m++){
    #pragma unroll
    for (int nt=0;nt<4;nt++){
      #pragma unroll
      for (int r=0;r<4;r++){
        int row = m*16 + lg*4 + r;
        int col = nt*16 + lr;
        int baddr = (row*128 + col*2) ^ ((row&7)<<4);
        float v = fmaxf(acc[m][nt][r], 0.f);
        _Float16 vh = (_Float16)v;
        *(_Float16*)((char*)hbh + baddr) = vh;
        *(_Float16*)((char*)hbl + baddr) = (_Float16)(v-(float)vh);
      }
    }
  }

  // ---- GEMM2: H2 @ W12' ----
  f32x4 acc2[2][4];
  #pragma unroll
  for (int nt=0;nt<4;nt++){
    float bb = ws[oB12p + nt*16 + lr];
    f32x4 v = {bb,bb,bb,bb};
    acc2[0][nt]=v; acc2[1][nt]=v;
  }
  {
    const _Float16* W2hi = (const _Float16*)(ws + oW12hi);
    const _Float16* W2lo = (const _Float16*)(ws + oW12lo);
    half8 wh[4][2], wl[4][2];
    #pragma unroll
    for (int nt=0;nt<4;nt++){
      #pragma unroll
      for (int ks=0;ks<2;ks++){
        wh[nt][ks] = *(const half8*)(W2hi + (nt*16+lr)*64 + ks*32 + lg*8);
        wl[nt][ks] = *(const half8*)(W2lo + (nt*16+lr)*64 + ks*32 + lg*8);
      }
    }
    #pragma unroll
    for (int m=0;m<2;m++){
      #pragma unroll
      for (int ks=0;ks<2;ks++){
        int row = m*16 + lr;
        int baddr = (row*128 + (ks*32 + lg*8)*2) ^ ((row&7)<<4);
        half8 ah = *(const half8*)((char*)hbh + baddr);
        half8 al = *(const half8*)((char*)hbl + baddr);
        #pragma unroll
        for (int nt=0;nt<4;nt++){
          acc2[m][nt] = __builtin_amdgcn_mfma_f32_16x16x32_f16(ah, wh[nt][ks], acc2[m][nt], 0,0,0);
          acc2[m][nt] = __builtin_amdgcn_mfma_f32_16x16x32_f16(al, wh[nt][ks], acc2[m][nt], 0,0,0);
          acc2[m][nt] = __builtin_amdgcn_mfma_f32_16x16x32_f16(ah, wl[nt][ks], acc2[m][nt], 0,0,0);
        }
      }
    }
  }

  // ---- epilogue: max over valid rows (0..19), relu, +t12, write ----
  float fin[4]; float sq = 0.f;
  #pragma unroll
  for (int nt=0;nt<4;nt++){
    float cv = -RINF;
    #pragma unroll
    for (int r=0;r<4;r++) cv = fmaxf(cv, acc2[0][nt][r]);       // rows 0..15 all valid
    if (lg==0){
      #pragma unroll
      for (int r=0;r<4;r++) cv = fmaxf(cv, acc2[1][nt][r]);     // rows 16..19
    }
    cv = fmaxf(cv, __shfl_xor(cv,16,64));
    cv = fmaxf(cv, __shfl_xor(cv,32,64));
    fin[nt] = fmaxf(cv, 0.f) + ws[oT12 + nt*16 + lr];
    sq = fmaf(fin[nt], fin[nt], sq);
  }
  if (lane < 16){
    #pragma unroll
    for (int nt=0;nt<4;nt++){
      x1[(size_t)i*64 + nt*16 + lane] = fin[nt];
      out[(size_t)i*192 + nt*16 + lane] = fin[nt];
    }
  }
  #pragma unroll
  for (int off=1; off<16; off<<=1) sq += __shfl_xor(sq, off, 64);
  if (lane == 0) sqv[i] = sq;
}

// ---------------- kNN2 distance GEMM: D = sq_p + sq_q - 2*x1@x1^T, per-event chunk ----------------
__global__ __launch_bounds__(256) void k_dist2(const float* __restrict__ x1, const float* __restrict__ sqv,
                                               float* __restrict__ D, int e0)
{
  __shared__ float As[64][65], Bs[64][65];
  int e = e0 + blockIdx.z;
  const float* Xe = x1 + (size_t)e*P_PT*64;
  int rb = blockIdx.y*64, cb = blockIdx.x*64;
  int t = threadIdx.x;
  int tr = t>>4, tk=(t&15)*4;
  #pragma unroll
  for (int rr=0;rr<4;rr++){
    int r = tr + 16*rr;
    float4 va = *(const float4*)(Xe + (size_t)(rb+r)*64 + tk);
    As[r][tk]=va.x; As[r][tk+1]=va.y; As[r][tk+2]=va.z; As[r][tk+3]=va.w;
    float4 vb = *(const float4*)(Xe + (size_t)(cb+r)*64 + tk);
    Bs[r][tk]=vb.x; Bs[r][tk+1]=vb.y; Bs[r][tk+2]=vb.z; Bs[r][tk+3]=vb.w;
  }
  __syncthreads();
  int tx=t&15, ty=t>>4;
  float acc[4][4];
  #pragma unroll
  for (int i=0;i<4;i++){
    #pragma unroll
    for (int j=0;j<4;j++) acc[i][j]=0.f;
  }
  #pragma unroll 2
  for (int k=0;k<64;k++){
    float a0=As[ty*4+0][k], a1=As[ty*4+1][k], a2=As[ty*4+2][k], a3=As[ty*4+3][k];
    float b0=Bs[tx*4+0][k], b1=Bs[tx*4+1][k], b2=Bs[tx*4+2][k], b3=Bs[tx*4+3][k];
    acc[0][0]=fmaf(a0,b0,acc[0][0]); acc[0][1]=fmaf(a0,b1,acc[0][1]);
    acc[0][2]=fmaf(a0,b2,acc[0][2]); acc[0][3]=fmaf(a0,b3,acc[0][3]);
    acc[1][0]=fmaf(a1,b0,acc[1][0]); acc[1][1]=fmaf(a1,b1,acc[1][1]);
    acc[1][2]=fmaf(a1,b2,acc[1][2]); acc[1][3]=fmaf(a1,b3,acc[1][3]);
    acc[2][0]=fmaf(a2,b0,acc[2][0]); acc[2][1]=fmaf(a2,b1,acc[2][1]);
    acc[2][2]=fmaf(a2,b2,acc[2][2]); acc[2][3]=fmaf(a2,b3,acc[2][3]);
    acc[3][0]=fmaf(a3,b0,acc[3][0]); acc[3][1]=fmaf(a3,b1,acc[3][1]);
    acc[3][2]=fmaf(a3,b2,acc[3][2]); acc[3][3]=fmaf(a3,b3,acc[3][3]);
  }
  float sr[4], sc[4];
  #pragma unroll
  for (int i=0;i<4;i++){ sr[i]=sqv[e*P_PT + rb+ty*4+i]; sc[i]=sqv[e*P_PT + cb+tx*4+i]; }
  #pragma unroll
  for (int i=0;i<4;i++){
    float4 o;
    o.x = sr[i]+sc[0]-2.f*acc[i][0];
    o.y = sr[i]+sc[1]-2.f*acc[i][1];
    o.z = sr[i]+sc[2]-2.f*acc[i][2];
    o.w = sr[i]+sc[3]-2.f*acc[i][3];
    *(float4*)(D + (size_t)(blockIdx.z*P_PT + rb+ty*4+i)*P_PT + cb + tx*4) = o;
  }
}

// ---------------- kNN2 selection ----------------
__global__ __launch_bounds__(256) void k_sel2(const float* __restrict__ D, int* __restrict__ idxout, int e0)
{
  int t=threadIdx.x, lane=t&63;
  int pl = blockIdx.x*4 + (t>>6);
  int le = pl>>11, pin = pl&(P_PT-1);
  int e = e0 + le;
  int g = e*P_PT + pin;
  const float* Dr = D + (size_t)pl*P_PT;
  float d[32];
  #pragma unroll
  for (int j=0;j<32;j++) d[j]=Dr[j*64+lane];
  select20(d, lane, e*P_PT, g, idxout);
}

// ---------------- EdgeConv2: U = x1@(Wt-Wb)+b, V = x1@Wb ----------------
__global__ __launch_bounds__(256) void k_uv2(const float* __restrict__ x1, const float* __restrict__ W,
                                             float* __restrict__ U2, float* __restrict__ V2)
{
  int g = blockIdx.x*256 + threadIdx.x;
  int half = blockIdx.y & 1;
  bool isU = blockIdx.y < 2;
  const float* Wb = W + (isU?oWA20:oWB20) + half*64;
  float acc[64];
  #pragma unroll
  for (int c=0;c<64;c++) acc[c] = isU ? W[oB20+half*64+c] : 0.f;
  const float* xp = x1 + (size_t)g*64;
  #pragma unroll 1
  for (int i=0;i<64;i+=4){
    float4 xv = *(const float4*)(xp+i);
    #pragma unroll
    for (int c=0;c<64;c++) acc[c]=fmaf(xv.x, Wb[(i+0)*128+c], acc[c]);
    #pragma unroll
    for (int c=0;c<64;c++) acc[c]=fmaf(xv.y, Wb[(i+1)*128+c], acc[c]);
    #pragma unroll
    for (int c=0;c<64;c++) acc[c]=fmaf(xv.z, Wb[(i+2)*128+c], acc[c]);
    #pragma unroll
    for (int c=0;c<64;c++) acc[c]=fmaf(xv.w, Wb[(i+3)*128+c], acc[c]);
  }
  float* dst = (isU?U2:V2) + (size_t)g*128 + half*64;
  #pragma unroll
  for (int c=0;c<64;c+=4){
    float4 o; o.x=acc[c]; o.y=acc[c+1]; o.z=acc[c+2]; o.w=acc[c+3];
    *(float4*)(dst+c)=o;
  }
}

// ---------------- EdgeConv2 gather-max + epilogue ----------------
__global__ __launch_bounds__(256) void k_gather2(const int* __restrict__ idx, const float* __restrict__ U2,
     const float* __restrict__ V2, const float* __restrict__ W, float* __restrict__ out)
{
  int g = blockIdx.x*256 + threadIdx.x;
  int half = blockIdx.y;
  float mx[64];
  #pragma unroll
  for (int c=0;c<64;c++) mx[c]=-RINF;
  for (int k=0;k<K_NN;k++){
    int j = idx[(size_t)g*K_NN+k];
    const float4* vp = (const float4*)(V2 + (size_t)j*128 + half*64);
    #pragma unroll
    for (int c4=0;c4<16;c4++){
      float4 v=vp[c4];
      mx[c4*4+0]=fmaxf(mx[c4*4+0],v.x);
      mx[c4*4+1]=fmaxf(mx[c4*4+1],v.y);
      mx[c4*4+2]=fmaxf(mx[c4*4+2],v.z);
      mx[c4*4+3]=fmaxf(mx[c4*4+3],v.w);
    }
  }
  const float* Up = U2 + (size_t)g*128 + half*64;
  float* op = out + (size_t)g*192 + 64 + half*64;
  #pragma unroll
  for (int c=0;c<64;c+=4){
    float4 o;
    o.x = fmaxf(Up[c+0]+mx[c+0],0.f)+W[oT20+half*64+c+0];
    o.y = fmaxf(Up[c+1]+mx[c+1],0.f)+W[oT20+half*64+c+1];
    o.z = fmaxf(Up[c+2]+mx[c+2],0.f)+W[oT20+half*64+c+2];
    o.w = fmaxf(Up[c+3]+mx[c+3],0.f)+W[oT20+half*64+c+3];
    *(float4*)(op+c)=o;
  }
}

// ---------------- batch passthrough ----------------
__global__ __launch_bounds__(256) void k_batchf(const int* __restrict__ batch, float* __restrict__ out){
  int i = blockIdx.x*256+threadIdx.x;
  out[(size_t)NPTS*192 + i] = (float)batch[i];
}

extern "C" void kernel_launch(void* const* d_in, const int* in_sizes, int n_in,
                              void* d_out, int out_size, void* d_ws, size_t ws_size,
                              hipStream_t stream)
{
  const float* x     = (const float*)d_in[0];
  const int*   batch = (const int*)d_in[1];
  const float* w10=(const float*)d_in[2],  *b10=(const float*)d_in[3],  *g10=(const float*)d_in[4],
             *e10=(const float*)d_in[5],  *m10=(const float*)d_in[6],  *v10=(const float*)d_in[7];
  const float* w11=(const float*)d_in[8],  *b11=(const float*)d_in[9],  *g11=(const float*)d_in[10],
             *e11=(const float*)d_in[11], *m11=(const float*)d_in[12], *v11=(const float*)d_in[13];
  const float* w12=(const float*)d_in[14], *b12=(const float*)d_in[15], *g12=(const float*)d_in[16],
             *e12=(const float*)d_in[17], *m12=(const float*)d_in[18], *v12=(const float*)d_in[19];
  const float* w20=(const float*)d_in[20], *b20=(const float*)d_in[21], *g20=(const float*)d_in[22],
             *e20=(const float*)d_in[23], *m20=(const float*)d_in[24], *v20=(const float*)d_in[25];

  float* ws  = (float*)d_ws;
  float* out = (float*)d_out;
  int*   idxp = (int*)(ws + oIDX);

  k_prep<<<1,128,0,stream>>>(w10,b10,g10,e10,m10,v10, w11,b11,g11,e11,m11,v11,
                             w12,b12,g12,e12,m12,v12, w20,b20,g20,e20,m20,v20, ws);
  k_knn1<<<NPTS/4, 256, 0, stream>>>(x, idxp);
  k_ab1<<<NPTS/256, 256, 0, stream>>>(x, ws, ws+oA1, ws+oB1);
  k_ec1m<<<NPTS/4, 256, 0, stream>>>(idxp, ws, ws+oA1, ws+oB1, ws+oX1, ws+oSQ, out);

  size_t wsFloats = ws_size/4;
  long avail = (long)wsFloats - (long)oD;
  int CE = (int)(avail / (2048L*2048L));
  if (CE < 1) CE = 1;
  if (CE > 8) CE = 8;
  for (int e0=0; e0<B_EV; e0+=CE){
    int ce = (B_EV - e0 < CE) ? (B_EV - e0) : CE;
    k_dist2<<<dim3(32,32,ce),256,0,stream>>>(ws+oX1, ws+oSQ, ws+oD, e0);
    k_sel2<<<ce*512,256,0,stream>>>(ws+oD, idxp, e0);
  }

  k_uv2<<<dim3(NPTS/256,4),256,0,stream>>>(ws+oX1, ws, ws+oU2, ws+oV2);
  k_gather2<<<dim3(NPTS/256,2),256,0,stream>>>(idxp, ws+oU2, ws+oV2, ws, out);
  k_batchf<<<NPTS/256,256,0,stream>>>(batch, out);
}

// Round 5
// 1368.058 us; speedup vs baseline: 1.4645x; 1.1144x over previous
//
#include <hip/hip_runtime.h>

#define B_EV 32
#define P_PT 2048
#define K_NN 20
#define NPTS (B_EV*P_PT)
#define EPS_BN 1e-5f
#define RINF 3.0e38f

typedef _Float16 half8 __attribute__((ext_vector_type(8)));
typedef float f32x4 __attribute__((ext_vector_type(4)));

// ---------------- ws layout (float offsets) ----------------
static constexpr int oWA10=0, oWB10=448, oB10=896, oT10=960,
  oT11=5184,
  oT12=9408,
  oWA20=9472, oWB20=17664, oB20=25856, oT20=25984,
  oB11p=26048, oB12p=26112,
  oW11hi=26176, oW11lo=28224,   // each 64x64 f16 == 2048 floats, layout [n][k]
  oW12hi=30272, oW12lo=32320;
static constexpr size_t oIDX = 36864;                      // int region, NPTS*20 ints
static constexpr size_t oA1  = 1347584;                    // NPTS*64 f32
static constexpr size_t oB1  = oA1 + (size_t)NPTS*64;
static constexpr size_t oV2  = oB1 + (size_t)NPTS*64;      // NPTS*128 f32
static constexpr size_t oX1  = oV2 + (size_t)NPTS*128;     // NPTS*64 f32
static constexpr size_t oSQ  = oX1 + (size_t)NPTS*64;      // NPTS f32
static constexpr size_t oD   = oSQ + (size_t)NPTS;         // chunked 2048x2048 dist buf
static constexpr size_t oU2  = oA1;                        // U2 reuses A1+B1 (after ec1)

// ---------------- BN fold + split-f16 weight prep ----------------
__global__ __launch_bounds__(128) void k_prep(
  const float* w10,const float* b10,const float* g10,const float* e10,const float* m10,const float* v10,
  const float* w11,const float* b11,const float* g11,const float* e11,const float* m11,const float* v11,
  const float* w12,const float* b12,const float* g12,const float* e12,const float* m12,const float* v12,
  const float* w20,const float* b20,const float* g20,const float* e20,const float* m20,const float* v20,
  float* ws)
{
  __shared__ float t10s[64], t11s[64];
  int c = threadIdx.x;
  if (c < 64) {
    float s0 = g10[c]*rsqrtf(v10[c]+EPS_BN);
    ws[oB10+c]=b10[c]*s0;
    float t10 = e10[c]-m10[c]*s0; ws[oT10+c]=t10; t10s[c]=t10;
    for (int i=0;i<7;i++){
      ws[oWA10+i*64+c]=(w10[i*64+c]-w10[(7+i)*64+c])*s0;
      ws[oWB10+i*64+c]=w10[(7+i)*64+c]*s0;
    }
    float s1 = g11[c]*rsqrtf(v11[c]+EPS_BN);
    float t11 = e11[c]-m11[c]*s1; ws[oT11+c]=t11; t11s[c]=t11;
    float s2 = g12[c]*rsqrtf(v12[c]+EPS_BN);
    ws[oT12+c]=e12[c]-m12[c]*s2;
  }
  __syncthreads();
  if (c < 64) {
    float s1 = g11[c]*rsqrtf(v11[c]+EPS_BN);
    _Float16* W1hi = (_Float16*)(ws + oW11hi);
    _Float16* W1lo = (_Float16*)(ws + oW11lo);
    float acc = b11[c]*s1;
    for (int i=0;i<64;i++){
      float wv = w11[i*64+c]*s1;
      _Float16 h = (_Float16)wv;
      W1hi[c*64+i] = h;                       // [n=c][k=i]
      W1lo[c*64+i] = (_Float16)(wv - (float)h);
      acc = fmaf(t10s[i], wv, acc);
    }
    ws[oB11p+c]=acc;
    float s2 = g12[c]*rsqrtf(v12[c]+EPS_BN);
    _Float16* W2hi = (_Float16*)(ws + oW12hi);
    _Float16* W2lo = (_Float16*)(ws + oW12lo);
    float acc2 = b12[c]*s2;
    for (int i=0;i<64;i++){
      float wv = w12[i*64+c]*s2;
      _Float16 h = (_Float16)wv;
      W2hi[c*64+i] = h;
      W2lo[c*64+i] = (_Float16)(wv - (float)h);
      acc2 = fmaf(t11s[i], wv, acc2);
    }
    ws[oB12p+c]=acc2;
  }
  {
    float s = g20[c]*rsqrtf(v20[c]+EPS_BN);
    ws[oB20+c]=b20[c]*s; ws[oT20+c]=e20[c]-m20[c]*s;
    for (int i=0;i<64;i++){
      ws[oWA20+i*128+c]=(w20[i*128+c]-w20[(64+i)*128+c])*s;
      ws[oWB20+i*128+c]=w20[(64+i)*128+c]*s;
    }
  }
}

// ---------------- exact top-20 per wave (point), d[32] in regs ----------------
__device__ __forceinline__ void select20(float (&d)[32], int lane, int base, int g,
                                         int* __restrict__ idxout)
{
  float g4[4];
  #pragma unroll
  for (int k=0;k<4;k++){
    float m = d[8*k];
    #pragma unroll
    for (int j=1;j<8;j++) m = fminf(m, d[8*k+j]);
    g4[k]=m;
  }
  float T = 0.f;
  #pragma unroll 1
  for (int pass=0; pass<20; ++pass){
    float m = fminf(fminf(g4[0],g4[1]), fminf(g4[2],g4[3]));
    #pragma unroll
    for (int off=32; off>0; off>>=1) m = fminf(m, __shfl_xor(m, off, 64));
    if (pass==19){ T=m; break; }
    #pragma unroll
    for (int k=0;k<4;k++){
      if (g4[k]==m){
        #pragma unroll
        for (int j=0;j<8;j++) d[8*k+j] = (d[8*k+j]==m) ? RINF : d[8*k+j];
        float mm = d[8*k];
        #pragma unroll
        for (int j=1;j<8;j++) mm = fminf(mm, d[8*k+j]);
        g4[k]=mm;
      }
    }
  }
  int cnt=0;
  #pragma unroll
  for (int j=0;j<32;j++){
    bool take = (d[j]>=RINF) || (d[j]==T);
    unsigned long long mb = __ballot(take);
    if (take){
      int pos = cnt + (int)__popcll(mb & ((1ull<<lane)-1ull));
      if (pos < K_NN) idxout[(size_t)g*K_NN + pos] = base + j*64 + lane;
    }
    cnt += (int)__popcll(mb);
  }
  if (lane==0){
    for (int r=cnt; r<K_NN; ++r) idxout[(size_t)g*K_NN + r] = g;
  }
}

// ---------------- kNN on x (C=7), wave per point, event staged in LDS ----------------
// 512 thr = 8 waves = 8 points/block: 2 blocks/CU (LDS) x 8 waves = 16 waves/CU
// (VGPR-quantum ceiling for 88 VGPRs) vs 8 waves/CU at 256 thr.
__global__ __launch_bounds__(512) void k_knn1(const float* __restrict__ x, int* __restrict__ idxout)
{
  __shared__ float xs[P_PT*7];
  int t = threadIdx.x;
  int e = (int)(blockIdx.x >> 8);                  // 8 points/block, 256 blocks/event
  const float4* src = (const float4*)(x + (size_t)e*P_PT*7);
  #pragma unroll
  for (int u=0;u<7;u++) ((float4*)xs)[u*512+t] = src[u*512+t];
  __syncthreads();
  int lane = t & 63;
  int g = blockIdx.x*8 + (t>>6);
  int pin = g & (P_PT-1);
  float xp[7];
  #pragma unroll
  for (int i=0;i<7;i++) xp[i]=xs[pin*7+i];
  float d[32];
  #pragma unroll
  for (int j=0;j<32;j++){
    const float* xq = xs + (j*64+lane)*7;
    float s=0.f;
    #pragma unroll
    for (int i=0;i<7;i++){ float df=xp[i]-xq[i]; s=fmaf(df,df,s); }
    d[j]=s;
  }
  select20(d, lane, e*P_PT, g, idxout);
}

// ---------------- A/B precompute for EdgeConv1 layer 1 ----------------
__global__ __launch_bounds__(256) void k_ab1(const float* __restrict__ x, const float* __restrict__ W,
                                             float* __restrict__ A1, float* __restrict__ B1)
{
  int g = blockIdx.x*256+threadIdx.x;
  float xi[7];
  #pragma unroll
  for (int i=0;i<7;i++) xi[i]=x[(size_t)g*7+i];
  float a[64], b[64];
  #pragma unroll
  for (int c=0;c<64;c++){ a[c]=W[oB10+c]; b[c]=0.f; }
  #pragma unroll
  for (int i=0;i<7;i++){
    #pragma unroll
    for (int c=0;c<64;c++) a[c]=fmaf(xi[i], W[oWA10+i*64+c], a[c]);
    #pragma unroll
    for (int c=0;c<64;c++) b[c]=fmaf(xi[i], W[oWB10+i*64+c], b[c]);
  }
  #pragma unroll
  for (int c=0;c<64;c+=4){
    float4 oa; oa.x=a[c]; oa.y=a[c+1]; oa.z=a[c+2]; oa.w=a[c+3];
    *(float4*)(A1+(size_t)g*64+c)=oa;
    float4 ob; ob.x=b[c]; ob.y=b[c+1]; ob.z=b[c+2]; ob.w=b[c+3];
    *(float4*)(B1+(size_t)g*64+c)=ob;
  }
}

// ---------------- EdgeConv1 via split-f16 MFMA: wave per point ----------------
// a = a_hi + a_lo (f16 pair, ~22 mantissa bits); acc += ah*wh + al*wh + ah*wl
__global__ __launch_bounds__(256) void k_ec1m(const int* __restrict__ idx, const float* __restrict__ ws,
    const float* __restrict__ A1, const float* __restrict__ B1,
    float* __restrict__ x1, float* __restrict__ sqv, float* __restrict__ out)
{
  __shared__ _Float16 h2hi[4][32*64];   // per-wave swizzled H2 hi (4KB each)
  __shared__ _Float16 h2lo[4][32*64];   // per-wave swizzled H2 lo
  int t = threadIdx.x, w = t>>6, lane = t&63;
  int i = blockIdx.x*4 + w;
  int lg = lane>>4, lr = lane&15;

  int j0 = idx[(size_t)i*K_NN + lr];
  int j1 = (lr < 4) ? idx[(size_t)i*K_NN + 16 + lr] : i;   // rows 20..31 pad (masked later)

  // ---- GEMM1: H1(relu-only) @ W11' ----
  f32x4 acc[2][4];
  #pragma unroll
  for (int nt=0;nt<4;nt++){
    float bb = ws[oB11p + nt*16 + lr];
    f32x4 v = {bb,bb,bb,bb};
    acc[0][nt]=v; acc[1][nt]=v;
  }
  {
    const _Float16* W1hi = (const _Float16*)(ws + oW11hi);
    const _Float16* W1lo = (const _Float16*)(ws + oW11lo);
    half8 wh[4][2], wl[4][2];
    #pragma unroll
    for (int nt=0;nt<4;nt++){
      #pragma unroll
      for (int ks=0;ks<2;ks++){
        wh[nt][ks] = *(const half8*)(W1hi + (nt*16+lr)*64 + ks*32 + lg*8);
        wl[nt][ks] = *(const half8*)(W1lo + (nt*16+lr)*64 + ks*32 + lg*8);
      }
    }
    const float* Ap = A1 + (size_t)i*64;
    #pragma unroll
    for (int m=0;m<2;m++){
      const float* Bp = B1 + (size_t)(m ? j1 : j0)*64;
      #pragma unroll
      for (int ks=0;ks<2;ks++){
        int c0 = ks*32 + lg*8;
        float4 b0 = *(const float4*)(Bp+c0);
        float4 b1 = *(const float4*)(Bp+c0+4);
        float4 a0 = *(const float4*)(Ap+c0);
        float4 a1 = *(const float4*)(Ap+c0+4);
        float hv[8];
        hv[0]=fmaxf(a0.x+b0.x,0.f); hv[1]=fmaxf(a0.y+b0.y,0.f);
        hv[2]=fmaxf(a0.z+b0.z,0.f); hv[3]=fmaxf(a0.w+b0.w,0.f);
        hv[4]=fmaxf(a1.x+b1.x,0.f); hv[5]=fmaxf(a1.y+b1.y,0.f);
        hv[6]=fmaxf(a1.z+b1.z,0.f); hv[7]=fmaxf(a1.w+b1.w,0.f);
        half8 ah, al;
        #pragma unroll
        for (int q=0;q<8;q++){
          _Float16 h = (_Float16)hv[q];
          ah[q]=h; al[q]=(_Float16)(hv[q]-(float)h);
        }
        #pragma unroll
        for (int nt=0;nt<4;nt++){
          acc[m][nt] = __builtin_amdgcn_mfma_f32_16x16x32_f16(ah, wh[nt][ks], acc[m][nt], 0,0,0);
          acc[m][nt] = __builtin_amdgcn_mfma_f32_16x16x32_f16(al, wh[nt][ks], acc[m][nt], 0,0,0);
          acc[m][nt] = __builtin_amdgcn_mfma_f32_16x16x32_f16(ah, wl[nt][ks], acc[m][nt], 0,0,0);
        }
      }
    }
  }

  // ---- H2 -> LDS (swizzled hi/lo), relu only (t11 folded into B12p) ----
  _Float16* hbh = h2hi[w];
  _Float16* hbl = h2lo[w];
  #pragma unroll
  for (int m=0;m<2;m++){
    #pragma unroll
    for (int nt=0;nt<4;nt++){
      #pragma unroll
      for (int r=0;r<4;r++){
        int row = m*16 + lg*4 + r;
        int col = nt*16 + lr;
        int baddr = (row*128 + col*2) ^ ((row&7)<<4);
        float v = fmaxf(acc[m][nt][r], 0.f);
        _Float16 vh = (_Float16)v;
        *(_Float16*)((char*)hbh + baddr) = vh;
        *(_Float16*)((char*)hbl + baddr) = (_Float16)(v-(float)vh);
      }
    }
  }

  // ---- GEMM2: H2 @ W12' ----
  f32x4 acc2[2][4];
  #pragma unroll
  for (int nt=0;nt<4;nt++){
    float bb = ws[oB12p + nt*16 + lr];
    f32x4 v = {bb,bb,bb,bb};
    acc2[0][nt]=v; acc2[1][nt]=v;
  }
  {
    const _Float16* W2hi = (const _Float16*)(ws + oW12hi);
    const _Float16* W2lo = (const _Float16*)(ws + oW12lo);
    half8 wh[4][2], wl[4][2];
    #pragma unroll
    for (int nt=0;nt<4;nt++){
      #pragma unroll
      for (int ks=0;ks<2;ks++){
        wh[nt][ks] = *(const half8*)(W2hi + (nt*16+lr)*64 + ks*32 + lg*8);
        wl[nt][ks] = *(const half8*)(W2lo + (nt*16+lr)*64 + ks*32 + lg*8);
      }
    }
    #pragma unroll
    for (int m=0;m<2;m++){
      #pragma unroll
      for (int ks=0;ks<2;ks++){
        int row = m*16 + lr;
        int baddr = (row*128 + (ks*32 + lg*8)*2) ^ ((row&7)<<4);
        half8 ah = *(const half8*)((char*)hbh + baddr);
        half8 al = *(const half8*)((char*)hbl + baddr);
        #pragma unroll
        for (int nt=0;nt<4;nt++){
          acc2[m][nt] = __builtin_amdgcn_mfma_f32_16x16x32_f16(ah, wh[nt][ks], acc2[m][nt], 0,0,0);
          acc2[m][nt] = __builtin_amdgcn_mfma_f32_16x16x32_f16(al, wh[nt][ks], acc2[m][nt], 0,0,0);
          acc2[m][nt] = __builtin_amdgcn_mfma_f32_16x16x32_f16(ah, wl[nt][ks], acc2[m][nt], 0,0,0);
        }
      }
    }
  }

  // ---- epilogue: max over valid rows (0..19), relu, +t12, write ----
  float fin[4]; float sq = 0.f;
  #pragma unroll
  for (int nt=0;nt<4;nt++){
    float cv = -RINF;
    #pragma unroll
    for (int r=0;r<4;r++) cv = fmaxf(cv, acc2[0][nt][r]);       // rows 0..15 all valid
    if (lg==0){
      #pragma unroll
      for (int r=0;r<4;r++) cv = fmaxf(cv, acc2[1][nt][r]);     // rows 16..19
    }
    cv = fmaxf(cv, __shfl_xor(cv,16,64));
    cv = fmaxf(cv, __shfl_xor(cv,32,64));
    fin[nt] = fmaxf(cv, 0.f) + ws[oT12 + nt*16 + lr];
    sq = fmaf(fin[nt], fin[nt], sq);
  }
  if (lane < 16){
    #pragma unroll
    for (int nt=0;nt<4;nt++){
      x1[(size_t)i*64 + nt*16 + lane] = fin[nt];
      out[(size_t)i*192 + nt*16 + lane] = fin[nt];
    }
  }
  #pragma unroll
  for (int off=1; off<16; off<<=1) sq += __shfl_xor(sq, off, 64);
  if (lane == 0) sqv[i] = sq;
}

// ---------------- kNN2 distance GEMM: D = sq_p + sq_q - 2*x1@x1^T, per-event chunk ----------------
__global__ __launch_bounds__(256) void k_dist2(const float* __restrict__ x1, const float* __restrict__ sqv,
                                               float* __restrict__ D, int e0)
{
  __shared__ float As[64][65], Bs[64][65];
  int e = e0 + blockIdx.z;
  const float* Xe = x1 + (size_t)e*P_PT*64;
  int rb = blockIdx.y*64, cb = blockIdx.x*64;
  int t = threadIdx.x;
  int tr = t>>4, tk=(t&15)*4;
  #pragma unroll
  for (int rr=0;rr<4;rr++){
    int r = tr + 16*rr;
    float4 va = *(const float4*)(Xe + (size_t)(rb+r)*64 + tk);
    As[r][tk]=va.x; As[r][tk+1]=va.y; As[r][tk+2]=va.z; As[r][tk+3]=va.w;
    float4 vb = *(const float4*)(Xe + (size_t)(cb+r)*64 + tk);
    Bs[r][tk]=vb.x; Bs[r][tk+1]=vb.y; Bs[r][tk+2]=vb.z; Bs[r][tk+3]=vb.w;
  }
  __syncthreads();
  int tx=t&15, ty=t>>4;
  float acc[4][4];
  #pragma unroll
  for (int i=0;i<4;i++){
    #pragma unroll
    for (int j=0;j<4;j++) acc[i][j]=0.f;
  }
  #pragma unroll 2
  for (int k=0;k<64;k++){
    float a0=As[ty*4+0][k], a1=As[ty*4+1][k], a2=As[ty*4+2][k], a3=As[ty*4+3][k];
    float b0=Bs[tx*4+0][k], b1=Bs[tx*4+1][k], b2=Bs[tx*4+2][k], b3=Bs[tx*4+3][k];
    acc[0][0]=fmaf(a0,b0,acc[0][0]); acc[0][1]=fmaf(a0,b1,acc[0][1]);
    acc[0][2]=fmaf(a0,b2,acc[0][2]); acc[0][3]=fmaf(a0,b3,acc[0][3]);
    acc[1][0]=fmaf(a1,b0,acc[1][0]); acc[1][1]=fmaf(a1,b1,acc[1][1]);
    acc[1][2]=fmaf(a1,b2,acc[1][2]); acc[1][3]=fmaf(a1,b3,acc[1][3]);
    acc[2][0]=fmaf(a2,b0,acc[2][0]); acc[2][1]=fmaf(a2,b1,acc[2][1]);
    acc[2][2]=fmaf(a2,b2,acc[2][2]); acc[2][3]=fmaf(a2,b3,acc[2][3]);
    acc[3][0]=fmaf(a3,b0,acc[3][0]); acc[3][1]=fmaf(a3,b1,acc[3][1]);
    acc[3][2]=fmaf(a3,b2,acc[3][2]); acc[3][3]=fmaf(a3,b3,acc[3][3]);
  }
  float sr[4], sc[4];
  #pragma unroll
  for (int i=0;i<4;i++){ sr[i]=sqv[e*P_PT + rb+ty*4+i]; sc[i]=sqv[e*P_PT + cb+tx*4+i]; }
  #pragma unroll
  for (int i=0;i<4;i++){
    float4 o;
    o.x = sr[i]+sc[0]-2.f*acc[i][0];
    o.y = sr[i]+sc[1]-2.f*acc[i][1];
    o.z = sr[i]+sc[2]-2.f*acc[i][2];
    o.w = sr[i]+sc[3]-2.f*acc[i][3];
    *(float4*)(D + (size_t)(blockIdx.z*P_PT + rb+ty*4+i)*P_PT + cb + tx*4) = o;
  }
}

// ---------------- kNN2 selection ----------------
__global__ __launch_bounds__(256) void k_sel2(const float* __restrict__ D, int* __restrict__ idxout, int e0)
{
  int t=threadIdx.x, lane=t&63;
  int pl = blockIdx.x*4 + (t>>6);
  int le = pl>>11, pin = pl&(P_PT-1);
  int e = e0 + le;
  int g = e*P_PT + pin;
  const float* Dr = D + (size_t)pl*P_PT;
  float d[32];
  #pragma unroll
  for (int j=0;j<32;j++) d[j]=Dr[j*64+lane];
  select20(d, lane, e*P_PT, g, idxout);
}

// ---------------- EdgeConv2: U = x1@(Wt-Wb)+b, V = x1@Wb ----------------
__global__ __launch_bounds__(256) void k_uv2(const float* __restrict__ x1, const float* __restrict__ W,
                                             float* __restrict__ U2, float* __restrict__ V2)
{
  int g = blockIdx.x*256 + threadIdx.x;
  int half = blockIdx.y & 1;
  bool isU = blockIdx.y < 2;
  const float* Wb = W + (isU?oWA20:oWB20) + half*64;
  float acc[64];
  #pragma unroll
  for (int c=0;c<64;c++) acc[c] = isU ? W[oB20+half*64+c] : 0.f;
  const float* xp = x1 + (size_t)g*64;
  #pragma unroll 1
  for (int i=0;i<64;i+=4){
    float4 xv = *(const float4*)(xp+i);
    #pragma unroll
    for (int c=0;c<64;c++) acc[c]=fmaf(xv.x, Wb[(i+0)*128+c], acc[c]);
    #pragma unroll
    for (int c=0;c<64;c++) acc[c]=fmaf(xv.y, Wb[(i+1)*128+c], acc[c]);
    #pragma unroll
    for (int c=0;c<64;c++) acc[c]=fmaf(xv.z, Wb[(i+2)*128+c], acc[c]);
    #pragma unroll
    for (int c=0;c<64;c++) acc[c]=fmaf(xv.w, Wb[(i+3)*128+c], acc[c]);
  }
  float* dst = (isU?U2:V2) + (size_t)g*128 + half*64;
  #pragma unroll
  for (int c=0;c<64;c+=4){
    float4 o; o.x=acc[c]; o.y=acc[c+1]; o.z=acc[c+2]; o.w=acc[c+3];
    *(float4*)(dst+c)=o;
  }
}

// ---------------- EdgeConv2 gather-max + epilogue ----------------
__global__ __launch_bounds__(256) void k_gather2(const int* __restrict__ idx, const float* __restrict__ U2,
     const float* __restrict__ V2, const float* __restrict__ W, float* __restrict__ out)
{
  int g = blockIdx.x*256 + threadIdx.x;
  int half = blockIdx.y;
  float mx[64];
  #pragma unroll
  for (int c=0;c<64;c++) mx[c]=-RINF;
  for (int k=0;k<K_NN;k++){
    int j = idx[(size_t)g*K_NN+k];
    const float4* vp = (const float4*)(V2 + (size_t)j*128 + half*64);
    #pragma unroll
    for (int c4=0;c4<16;c4++){
      float4 v=vp[c4];
      mx[c4*4+0]=fmaxf(mx[c4*4+0],v.x);
      mx[c4*4+1]=fmaxf(mx[c4*4+1],v.y);
      mx[c4*4+2]=fmaxf(mx[c4*4+2],v.z);
      mx[c4*4+3]=fmaxf(mx[c4*4+3],v.w);
    }
  }
  const float* Up = U2 + (size_t)g*128 + half*64;
  float* op = out + (size_t)g*192 + 64 + half*64;
  #pragma unroll
  for (int c=0;c<64;c+=4){
    float4 o;
    o.x = fmaxf(Up[c+0]+mx[c+0],0.f)+W[oT20+half*64+c+0];
    o.y = fmaxf(Up[c+1]+mx[c+1],0.f)+W[oT20+half*64+c+1];
    o.z = fmaxf(Up[c+2]+mx[c+2],0.f)+W[oT20+half*64+c+2];
    o.w = fmaxf(Up[c+3]+mx[c+3],0.f)+W[oT20+half*64+c+3];
    *(float4*)(op+c)=o;
  }
}

// ---------------- batch passthrough ----------------
__global__ __launch_bounds__(256) void k_batchf(const int* __restrict__ batch, float* __restrict__ out){
  int i = blockIdx.x*256+threadIdx.x;
  out[(size_t)NPTS*192 + i] = (float)batch[i];
}

extern "C" void kernel_launch(void* const* d_in, const int* in_sizes, int n_in,
                              void* d_out, int out_size, void* d_ws, size_t ws_size,
                              hipStream_t stream)
{
  const float* x     = (const float*)d_in[0];
  const int*   batch = (const int*)d_in[1];
  const float* w10=(const float*)d_in[2],  *b10=(const float*)d_in[3],  *g10=(const float*)d_in[4],
             *e10=(const float*)d_in[5],  *m10=(const float*)d_in[6],  *v10=(const float*)d_in[7];
  const float* w11=(const float*)d_in[8],  *b11=(const float*)d_in[9],  *g11=(const float*)d_in[10],
             *e11=(const float*)d_in[11], *m11=(const float*)d_in[12], *v11=(const float*)d_in[13];
  const float* w12=(const float*)d_in[14], *b12=(const float*)d_in[15], *g12=(const float*)d_in[16],
             *e12=(const float*)d_in[17], *m12=(const float*)d_in[18], *v12=(const float*)d_in[19];
  const float* w20=(const float*)d_in[20], *b20=(const float*)d_in[21], *g20=(const float*)d_in[22],
             *e20=(const float*)d_in[23], *m20=(const float*)d_in[24], *v20=(const float*)d_in[25];

  float* ws  = (float*)d_ws;
  float* out = (float*)d_out;
  int*   idxp = (int*)(ws + oIDX);

  k_prep<<<1,128,0,stream>>>(w10,b10,g10,e10,m10,v10, w11,b11,g11,e11,m11,v11,
                             w12,b12,g12,e12,m12,v12, w20,b20,g20,e20,m20,v20, ws);
  k_knn1<<<NPTS/8, 512, 0, stream>>>(x, idxp);
  k_ab1<<<NPTS/256, 256, 0, stream>>>(x, ws, ws+oA1, ws+oB1);
  k_ec1m<<<NPTS/4, 256, 0, stream>>>(idxp, ws, ws+oA1, ws+oB1, ws+oX1, ws+oSQ, out);

  size_t wsFloats = ws_size/4;
  long avail = (long)wsFloats - (long)oD;
  int CE = (int)(avail / (2048L*2048L));
  if (CE < 1) CE = 1;
  if (CE > 8) CE = 8;
  for (int e0=0; e0<B_EV; e0+=CE){
    int ce = (B_EV - e0 < CE) ? (B_EV - e0) : CE;
    k_dist2<<<dim3(32,32,ce),256,0,stream>>>(ws+oX1, ws+oSQ, ws+oD, e0);
    k_sel2<<<ce*512,256,0,stream>>>(ws+oD, idxp, e0);
  }

  k_uv2<<<dim3(NPTS/256,4),256,0,stream>>>(ws+oX1, ws, ws+oU2, ws+oV2);
  k_gather2<<<dim3(NPTS/256,2),256,0,stream>>>(idxp, ws+oU2, ws+oV2, ws, out);
  k_batchf<<<NPTS/256,256,0,stream>>>(batch, out);
}

// Round 6
// 1182.312 us; speedup vs baseline: 1.6946x; 1.1571x over previous
//
#include <hip/hip_runtime.h>

#define B_EV 32
#define P_PT 2048
#define K_NN 20
#define NPTS (B_EV*P_PT)
#define EPS_BN 1e-5f
#define RINF 3.0e38f

typedef _Float16 half8 __attribute__((ext_vector_type(8)));
typedef float f32x4 __attribute__((ext_vector_type(4)));

// ---------------- ws layout (float offsets) ----------------
static constexpr int oWA10=0, oWB10=448, oB10=896, oT10=960,
  oT11=5184,
  oT12=9408,
  oWA20=9472, oWB20=17664, oB20=25856, oT20=25984,
  oB11p=26048, oB12p=26112,
  oW11hi=26176, oW11lo=28224,   // each 64x64 f16 == 2048 floats, layout [n][k]
  oW12hi=30272, oW12lo=32320;
static constexpr size_t oIDX = 36864;                      // int region, NPTS*20 ints
static constexpr size_t oA1  = 1347584;                    // NPTS*64 f32
static constexpr size_t oB1  = oA1 + (size_t)NPTS*64;
static constexpr size_t oV2  = oB1 + (size_t)NPTS*64;      // NPTS*128 f32
static constexpr size_t oX1  = oV2 + (size_t)NPTS*128;     // NPTS*64 f32
static constexpr size_t oSQ  = oX1 + (size_t)NPTS*64;      // NPTS f32
static constexpr size_t oD   = oSQ + (size_t)NPTS;         // chunked 2048x2048 dist buf
static constexpr size_t oU2  = oA1;                        // U2 reuses A1+B1 (after ec1)

// ---------------- BN fold + split-f16 weight prep ----------------
__global__ __launch_bounds__(128) void k_prep(
  const float* w10,const float* b10,const float* g10,const float* e10,const float* m10,const float* v10,
  const float* w11,const float* b11,const float* g11,const float* e11,const float* m11,const float* v11,
  const float* w12,const float* b12,const float* g12,const float* e12,const float* m12,const float* v12,
  const float* w20,const float* b20,const float* g20,const float* e20,const float* m20,const float* v20,
  float* ws)
{
  __shared__ float t10s[64], t11s[64];
  int c = threadIdx.x;
  if (c < 64) {
    float s0 = g10[c]*rsqrtf(v10[c]+EPS_BN);
    ws[oB10+c]=b10[c]*s0;
    float t10 = e10[c]-m10[c]*s0; ws[oT10+c]=t10; t10s[c]=t10;
    for (int i=0;i<7;i++){
      ws[oWA10+i*64+c]=(w10[i*64+c]-w10[(7+i)*64+c])*s0;
      ws[oWB10+i*64+c]=w10[(7+i)*64+c]*s0;
    }
    float s1 = g11[c]*rsqrtf(v11[c]+EPS_BN);
    float t11 = e11[c]-m11[c]*s1; ws[oT11+c]=t11; t11s[c]=t11;
    float s2 = g12[c]*rsqrtf(v12[c]+EPS_BN);
    ws[oT12+c]=e12[c]-m12[c]*s2;
  }
  __syncthreads();
  if (c < 64) {
    float s1 = g11[c]*rsqrtf(v11[c]+EPS_BN);
    _Float16* W1hi = (_Float16*)(ws + oW11hi);
    _Float16* W1lo = (_Float16*)(ws + oW11lo);
    float acc = b11[c]*s1;
    for (int i=0;i<64;i++){
      float wv = w11[i*64+c]*s1;
      _Float16 h = (_Float16)wv;
      W1hi[c*64+i] = h;                       // [n=c][k=i]
      W1lo[c*64+i] = (_Float16)(wv - (float)h);
      acc = fmaf(t10s[i], wv, acc);
    }
    ws[oB11p+c]=acc;
    float s2 = g12[c]*rsqrtf(v12[c]+EPS_BN);
    _Float16* W2hi = (_Float16*)(ws + oW12hi);
    _Float16* W2lo = (_Float16*)(ws + oW12lo);
    float acc2 = b12[c]*s2;
    for (int i=0;i<64;i++){
      float wv = w12[i*64+c]*s2;
      _Float16 h = (_Float16)wv;
      W2hi[c*64+i] = h;
      W2lo[c*64+i] = (_Float16)(wv - (float)h);
      acc2 = fmaf(t11s[i], wv, acc2);
    }
    ws[oB12p+c]=acc2;
  }
  {
    float s = g20[c]*rsqrtf(v20[c]+EPS_BN);
    ws[oB20+c]=b20[c]*s; ws[oT20+c]=e20[c]-m20[c]*s;
    for (int i=0;i<64;i++){
      ws[oWA20+i*128+c]=(w20[i*128+c]-w20[(64+i)*128+c])*s;
      ws[oWB20+i*128+c]=w20[(64+i)*128+c]*s;
    }
  }
}

// ---------------- exact top-20 per wave (point), d[32] in regs ----------------
__device__ __forceinline__ void select20(float (&d)[32], int lane, int base, int g,
                                         int* __restrict__ idxout)
{
  float g4[4];
  #pragma unroll
  for (int k=0;k<4;k++){
    float m = d[8*k];
    #pragma unroll
    for (int j=1;j<8;j++) m = fminf(m, d[8*k+j]);
    g4[k]=m;
  }
  float T = 0.f;
  #pragma unroll 1
  for (int pass=0; pass<20; ++pass){
    float m = fminf(fminf(g4[0],g4[1]), fminf(g4[2],g4[3]));
    #pragma unroll
    for (int off=32; off>0; off>>=1) m = fminf(m, __shfl_xor(m, off, 64));
    if (pass==19){ T=m; break; }
    #pragma unroll
    for (int k=0;k<4;k++){
      if (g4[k]==m){
        #pragma unroll
        for (int j=0;j<8;j++) d[8*k+j] = (d[8*k+j]==m) ? RINF : d[8*k+j];
        float mm = d[8*k];
        #pragma unroll
        for (int j=1;j<8;j++) mm = fminf(mm, d[8*k+j]);
        g4[k]=mm;
      }
    }
  }
  int cnt=0;
  #pragma unroll
  for (int j=0;j<32;j++){
    bool take = (d[j]>=RINF) || (d[j]==T);
    unsigned long long mb = __ballot(take);
    if (take){
      int pos = cnt + (int)__popcll(mb & ((1ull<<lane)-1ull));
      if (pos < K_NN) idxout[(size_t)g*K_NN + pos] = base + j*64 + lane;
    }
    cnt += (int)__popcll(mb);
  }
  if (lane==0){
    for (int r=cnt; r<K_NN; ++r) idxout[(size_t)g*K_NN + r] = g;
  }
}

// ---------------- kNN on x (C=7), wave per point, event staged in LDS ----------------
__global__ __launch_bounds__(512) void k_knn1(const float* __restrict__ x, int* __restrict__ idxout)
{
  __shared__ float xs[P_PT*7];
  int t = threadIdx.x;
  int e = (int)(blockIdx.x >> 8);                  // 8 points/block, 256 blocks/event
  const float4* src = (const float4*)(x + (size_t)e*P_PT*7);
  #pragma unroll
  for (int u=0;u<7;u++) ((float4*)xs)[u*512+t] = src[u*512+t];
  __syncthreads();
  int lane = t & 63;
  int g = blockIdx.x*8 + (t>>6);
  int pin = g & (P_PT-1);
  float xp[7];
  #pragma unroll
  for (int i=0;i<7;i++) xp[i]=xs[pin*7+i];
  float d[32];
  #pragma unroll
  for (int j=0;j<32;j++){
    const float* xq = xs + (j*64+lane)*7;
    float s=0.f;
    #pragma unroll
    for (int i=0;i<7;i++){ float df=xp[i]-xq[i]; s=fmaf(df,df,s); }
    d[j]=s;
  }
  select20(d, lane, e*P_PT, g, idxout);
}

// ---------------- A/B precompute for EdgeConv1 layer 1 ----------------
__global__ __launch_bounds__(256) void k_ab1(const float* __restrict__ x, const float* __restrict__ W,
                                             float* __restrict__ A1, float* __restrict__ B1)
{
  int g = blockIdx.x*256+threadIdx.x;
  float xi[7];
  #pragma unroll
  for (int i=0;i<7;i++) xi[i]=x[(size_t)g*7+i];
  float a[64], b[64];
  #pragma unroll
  for (int c=0;c<64;c++){ a[c]=W[oB10+c]; b[c]=0.f; }
  #pragma unroll
  for (int i=0;i<7;i++){
    #pragma unroll
    for (int c=0;c<64;c++) a[c]=fmaf(xi[i], W[oWA10+i*64+c], a[c]);
    #pragma unroll
    for (int c=0;c<64;c++) b[c]=fmaf(xi[i], W[oWB10+i*64+c], b[c]);
  }
  #pragma unroll
  for (int c=0;c<64;c+=4){
    float4 oa; oa.x=a[c]; oa.y=a[c+1]; oa.z=a[c+2]; oa.w=a[c+3];
    *(float4*)(A1+(size_t)g*64+c)=oa;
    float4 ob; ob.x=b[c]; ob.y=b[c+1]; ob.z=b[c+2]; ob.w=b[c+3];
    *(float4*)(B1+(size_t)g*64+c)=ob;
  }
}

// ---------------- EdgeConv1 via split-f16 MFMA: wave per point ----------------
// __launch_bounds__(256,2): allow ~256 VGPR/wave so the 64-VGPR weight-fragment
// sets stay RESIDENT (at the default budget the compiler rematerializes them as
// global loads inside the MFMA loops -> latency-bound, VGPR_Count=88, MfmaUtil 12%).
__global__ __launch_bounds__(256, 2) void k_ec1m(const int* __restrict__ idx, const float* __restrict__ ws,
    const float* __restrict__ A1, const float* __restrict__ B1,
    float* __restrict__ x1, float* __restrict__ sqv, float* __restrict__ out)
{
  __shared__ _Float16 h2hi[4][32*64];   // per-wave swizzled H2 hi (4KB each)
  __shared__ _Float16 h2lo[4][32*64];   // per-wave swizzled H2 lo
  int t = threadIdx.x, w = t>>6, lane = t&63;
  int i = blockIdx.x*4 + w;
  int lg = lane>>4, lr = lane&15;

  int j0 = idx[(size_t)i*K_NN + lr];
  int j1 = (lr < 4) ? idx[(size_t)i*K_NN + 16 + lr] : i;   // rows 20..31 pad (masked later)

  // ---- GEMM1: H1(relu-only) @ W11' ----
  f32x4 acc[2][4];
  #pragma unroll
  for (int nt=0;nt<4;nt++){
    float bb = ws[oB11p + nt*16 + lr];
    f32x4 v = {bb,bb,bb,bb};
    acc[0][nt]=v; acc[1][nt]=v;
  }
  {
    const _Float16* W1hi = (const _Float16*)(ws + oW11hi);
    const _Float16* W1lo = (const _Float16*)(ws + oW11lo);
    half8 wh[4][2], wl[4][2];
    #pragma unroll
    for (int nt=0;nt<4;nt++){
      #pragma unroll
      for (int ks=0;ks<2;ks++){
        wh[nt][ks] = *(const half8*)(W1hi + (nt*16+lr)*64 + ks*32 + lg*8);
        wl[nt][ks] = *(const half8*)(W1lo + (nt*16+lr)*64 + ks*32 + lg*8);
      }
    }
    const float* Ap = A1 + (size_t)i*64;
    #pragma unroll
    for (int m=0;m<2;m++){
      const float* Bp = B1 + (size_t)(m ? j1 : j0)*64;
      #pragma unroll
      for (int ks=0;ks<2;ks++){
        int c0 = ks*32 + lg*8;
        float4 b0 = *(const float4*)(Bp+c0);
        float4 b1 = *(const float4*)(Bp+c0+4);
        float4 a0 = *(const float4*)(Ap+c0);
        float4 a1 = *(const float4*)(Ap+c0+4);
        float hv[8];
        hv[0]=fmaxf(a0.x+b0.x,0.f); hv[1]=fmaxf(a0.y+b0.y,0.f);
        hv[2]=fmaxf(a0.z+b0.z,0.f); hv[3]=fmaxf(a0.w+b0.w,0.f);
        hv[4]=fmaxf(a1.x+b1.x,0.f); hv[5]=fmaxf(a1.y+b1.y,0.f);
        hv[6]=fmaxf(a1.z+b1.z,0.f); hv[7]=fmaxf(a1.w+b1.w,0.f);
        half8 ah, al;
        #pragma unroll
        for (int q=0;q<8;q++){
          _Float16 h = (_Float16)hv[q];
          ah[q]=h; al[q]=(_Float16)(hv[q]-(float)h);
        }
        #pragma unroll
        for (int nt=0;nt<4;nt++){
          acc[m][nt] = __builtin_amdgcn_mfma_f32_16x16x32_f16(ah, wh[nt][ks], acc[m][nt], 0,0,0);
          acc[m][nt] = __builtin_amdgcn_mfma_f32_16x16x32_f16(al, wh[nt][ks], acc[m][nt], 0,0,0);
          acc[m][nt] = __builtin_amdgcn_mfma_f32_16x16x32_f16(ah, wl[nt][ks], acc[m][nt], 0,0,0);
        }
      }
    }
  }

  // ---- H2 -> LDS (swizzled hi/lo), relu only (t11 folded into B12p) ----
  _Float16* hbh = h2hi[w];
  _Float16* hbl = h2lo[w];
  #pragma unroll
  for (int m=0;m<2;m++){
    #pragma unroll
    for (int nt=0;nt<4;nt++){
      #pragma unroll
      for (int r=0;r<4;r++){
        int row = m*16 + lg*4 + r;
        int col = nt*16 + lr;
        int baddr = (row*128 + col*2) ^ ((row&7)<<4);
        float v = fmaxf(acc[m][nt][r], 0.f);
        _Float16 vh = (_Float16)v;
        *(_Float16*)((char*)hbh + baddr) = vh;
        *(_Float16*)((char*)hbl + baddr) = (_Float16)(v-(float)vh);
      }
    }
  }

  // ---- GEMM2: H2 @ W12' ----
  f32x4 acc2[2][4];
  #pragma unroll
  for (int nt=0;nt<4;nt++){
    float bb = ws[oB12p + nt*16 + lr];
    f32x4 v = {bb,bb,bb,bb};
    acc2[0][nt]=v; acc2[1][nt]=v;
  }
  {
    const _Float16* W2hi = (const _Float16*)(ws + oW12hi);
    const _Float16* W2lo = (const _Float16*)(ws + oW12lo);
    half8 wh[4][2], wl[4][2];
    #pragma unroll
    for (int nt=0;nt<4;nt++){
      #pragma unroll
      for (int ks=0;ks<2;ks++){
        wh[nt][ks] = *(const half8*)(W2hi + (nt*16+lr)*64 + ks*32 + lg*8);
        wl[nt][ks] = *(const half8*)(W2lo + (nt*16+lr)*64 + ks*32 + lg*8);
      }
    }
    #pragma unroll
    for (int m=0;m<2;m++){
      #pragma unroll
      for (int ks=0;ks<2;ks++){
        int row = m*16 + lr;
        int baddr = (row*128 + (ks*32 + lg*8)*2) ^ ((row&7)<<4);
        half8 ah = *(const half8*)((char*)hbh + baddr);
        half8 al = *(const half8*)((char*)hbl + baddr);
        #pragma unroll
        for (int nt=0;nt<4;nt++){
          acc2[m][nt] = __builtin_amdgcn_mfma_f32_16x16x32_f16(ah, wh[nt][ks], acc2[m][nt], 0,0,0);
          acc2[m][nt] = __builtin_amdgcn_mfma_f32_16x16x32_f16(al, wh[nt][ks], acc2[m][nt], 0,0,0);
          acc2[m][nt] = __builtin_amdgcn_mfma_f32_16x16x32_f16(ah, wl[nt][ks], acc2[m][nt], 0,0,0);
        }
      }
    }
  }

  // ---- epilogue: max over valid rows (0..19), relu, +t12, write ----
  float fin[4]; float sq = 0.f;
  #pragma unroll
  for (int nt=0;nt<4;nt++){
    float cv = -RINF;
    #pragma unroll
    for (int r=0;r<4;r++) cv = fmaxf(cv, acc2[0][nt][r]);       // rows 0..15 all valid
    if (lg==0){
      #pragma unroll
      for (int r=0;r<4;r++) cv = fmaxf(cv, acc2[1][nt][r]);     // rows 16..19
    }
    cv = fmaxf(cv, __shfl_xor(cv,16,64));
    cv = fmaxf(cv, __shfl_xor(cv,32,64));
    fin[nt] = fmaxf(cv, 0.f) + ws[oT12 + nt*16 + lr];
    sq = fmaf(fin[nt], fin[nt], sq);
  }
  if (lane < 16){
    #pragma unroll
    for (int nt=0;nt<4;nt++){
      x1[(size_t)i*64 + nt*16 + lane] = fin[nt];
      out[(size_t)i*192 + nt*16 + lane] = fin[nt];
    }
  }
  #pragma unroll
  for (int off=1; off<16; off<<=1) sq += __shfl_xor(sq, off, 64);
  if (lane == 0) sqv[i] = sq;
}

// ---------------- kNN2 distance GEMM: D = sq_p + sq_q - 2*x1@x1^T ----------------
// LDS staged k-major (As[k][row], row-stride 68 so &As[k][4*ty] is 16B aligned):
// inner loop reads become 2x ds_read_b128 (A is a 16-lane broadcast) instead of
// 8 strided ds_read_b32. FMA order unchanged -> bitwise-identical D.
__global__ __launch_bounds__(256) void k_dist2(const float* __restrict__ x1, const float* __restrict__ sqv,
                                               float* __restrict__ D, int e0)
{
  __shared__ float As[64][68], Bs[64][68];   // [k][row]
  int e = e0 + blockIdx.z;
  const float* Xe = x1 + (size_t)e*P_PT*64;
  int rb = blockIdx.y*64, cb = blockIdx.x*64;
  int t = threadIdx.x;
  int tr = t>>4, tk=(t&15)*4;
  #pragma unroll
  for (int rr=0;rr<4;rr++){
    int r = tr + 16*rr;
    float4 va = *(const float4*)(Xe + (size_t)(rb+r)*64 + tk);
    As[tk][r]=va.x; As[tk+1][r]=va.y; As[tk+2][r]=va.z; As[tk+3][r]=va.w;
    float4 vb = *(const float4*)(Xe + (size_t)(cb+r)*64 + tk);
    Bs[tk][r]=vb.x; Bs[tk+1][r]=vb.y; Bs[tk+2][r]=vb.z; Bs[tk+3][r]=vb.w;
  }
  __syncthreads();
  int tx=t&15, ty=t>>4;
  float acc[4][4];
  #pragma unroll
  for (int i=0;i<4;i++){
    #pragma unroll
    for (int j=0;j<4;j++) acc[i][j]=0.f;
  }
  #pragma unroll 4
  for (int k=0;k<64;k++){
    float4 a4 = *(const float4*)(&As[k][ty*4]);
    float4 b4 = *(const float4*)(&Bs[k][tx*4]);
    float a0=a4.x, a1=a4.y, a2=a4.z, a3=a4.w;
    float b0=b4.x, b1=b4.y, b2=b4.z, b3=b4.w;
    acc[0][0]=fmaf(a0,b0,acc[0][0]); acc[0][1]=fmaf(a0,b1,acc[0][1]);
    acc[0][2]=fmaf(a0,b2,acc[0][2]); acc[0][3]=fmaf(a0,b3,acc[0][3]);
    acc[1][0]=fmaf(a1,b0,acc[1][0]); acc[1][1]=fmaf(a1,b1,acc[1][1]);
    acc[1][2]=fmaf(a1,b2,acc[1][2]); acc[1][3]=fmaf(a1,b3,acc[1][3]);
    acc[2][0]=fmaf(a2,b0,acc[2][0]); acc[2][1]=fmaf(a2,b1,acc[2][1]);
    acc[2][2]=fmaf(a2,b2,acc[2][2]); acc[2][3]=fmaf(a2,b3,acc[2][3]);
    acc[3][0]=fmaf(a3,b0,acc[3][0]); acc[3][1]=fmaf(a3,b1,acc[3][1]);
    acc[3][2]=fmaf(a3,b2,acc[3][2]); acc[3][3]=fmaf(a3,b3,acc[3][3]);
  }
  float sr[4], sc[4];
  #pragma unroll
  for (int i=0;i<4;i++){ sr[i]=sqv[e*P_PT + rb+ty*4+i]; sc[i]=sqv[e*P_PT + cb+tx*4+i]; }
  #pragma unroll
  for (int i=0;i<4;i++){
    float4 o;
    o.x = sr[i]+sc[0]-2.f*acc[i][0];
    o.y = sr[i]+sc[1]-2.f*acc[i][1];
    o.z = sr[i]+sc[2]-2.f*acc[i][2];
    o.w = sr[i]+sc[3]-2.f*acc[i][3];
    *(float4*)(D + (size_t)(blockIdx.z*P_PT + rb+ty*4+i)*P_PT + cb + tx*4) = o;
  }
}

// ---------------- kNN2 selection ----------------
__global__ __launch_bounds__(256) void k_sel2(const float* __restrict__ D, int* __restrict__ idxout, int e0)
{
  int t=threadIdx.x, lane=t&63;
  int pl = blockIdx.x*4 + (t>>6);
  int le = pl>>11, pin = pl&(P_PT-1);
  int e = e0 + le;
  int g = e*P_PT + pin;
  const float* Dr = D + (size_t)pl*P_PT;
  float d[32];
  #pragma unroll
  for (int j=0;j<32;j++) d[j]=Dr[j*64+lane];
  select20(d, lane, e*P_PT, g, idxout);
}

// ---------------- EdgeConv2: U = x1@(Wt-Wb)+b, V = x1@Wb ----------------
__global__ __launch_bounds__(256) void k_uv2(const float* __restrict__ x1, const float* __restrict__ W,
                                             float* __restrict__ U2, float* __restrict__ V2)
{
  int g = blockIdx.x*256 + threadIdx.x;
  int half = blockIdx.y & 1;
  bool isU = blockIdx.y < 2;
  const float* Wb = W + (isU?oWA20:oWB20) + half*64;
  float acc[64];
  #pragma unroll
  for (int c=0;c<64;c++) acc[c] = isU ? W[oB20+half*64+c] : 0.f;
  const float* xp = x1 + (size_t)g*64;
  #pragma unroll 1
  for (int i=0;i<64;i+=4){
    float4 xv = *(const float4*)(xp+i);
    #pragma unroll
    for (int c=0;c<64;c++) acc[c]=fmaf(xv.x, Wb[(i+0)*128+c], acc[c]);
    #pragma unroll
    for (int c=0;c<64;c++) acc[c]=fmaf(xv.y, Wb[(i+1)*128+c], acc[c]);
    #pragma unroll
    for (int c=0;c<64;c++) acc[c]=fmaf(xv.z, Wb[(i+2)*128+c], acc[c]);
    #pragma unroll
    for (int c=0;c<64;c++) acc[c]=fmaf(xv.w, Wb[(i+3)*128+c], acc[c]);
  }
  float* dst = (isU?U2:V2) + (size_t)g*128 + half*64;
  #pragma unroll
  for (int c=0;c<64;c+=4){
    float4 o; o.x=acc[c]; o.y=acc[c+1]; o.z=acc[c+2]; o.w=acc[c+3];
    *(float4*)(dst+c)=o;
  }
}

// ---------------- EdgeConv2 gather-max + epilogue ----------------
__global__ __launch_bounds__(256) void k_gather2(const int* __restrict__ idx, const float* __restrict__ U2,
     const float* __restrict__ V2, const float* __restrict__ W, float* __restrict__ out)
{
  int g = blockIdx.x*256 + threadIdx.x;
  int half = blockIdx.y;
  float mx[64];
  #pragma unroll
  for (int c=0;c<64;c++) mx[c]=-RINF;
  for (int k=0;k<K_NN;k++){
    int j = idx[(size_t)g*K_NN+k];
    const float4* vp = (const float4*)(V2 + (size_t)j*128 + half*64);
    #pragma unroll
    for (int c4=0;c4<16;c4++){
      float4 v=vp[c4];
      mx[c4*4+0]=fmaxf(mx[c4*4+0],v.x);
      mx[c4*4+1]=fmaxf(mx[c4*4+1],v.y);
      mx[c4*4+2]=fmaxf(mx[c4*4+2],v.z);
      mx[c4*4+3]=fmaxf(mx[c4*4+3],v.w);
    }
  }
  const float* Up = U2 + (size_t)g*128 + half*64;
  float* op = out + (size_t)g*192 + 64 + half*64;
  #pragma unroll
  for (int c=0;c<64;c+=4){
    float4 o;
    o.x = fmaxf(Up[c+0]+mx[c+0],0.f)+W[oT20+half*64+c+0];
    o.y = fmaxf(Up[c+1]+mx[c+1],0.f)+W[oT20+half*64+c+1];
    o.z = fmaxf(Up[c+2]+mx[c+2],0.f)+W[oT20+half*64+c+2];
    o.w = fmaxf(Up[c+3]+mx[c+3],0.f)+W[oT20+half*64+c+3];
    *(float4*)(op+c)=o;
  }
}

// ---------------- batch passthrough ----------------
__global__ __launch_bounds__(256) void k_batchf(const int* __restrict__ batch, float* __restrict__ out){
  int i = blockIdx.x*256+threadIdx.x;
  out[(size_t)NPTS*192 + i] = (float)batch[i];
}

extern "C" void kernel_launch(void* const* d_in, const int* in_sizes, int n_in,
                              void* d_out, int out_size, void* d_ws, size_t ws_size,
                              hipStream_t stream)
{
  const float* x     = (const float*)d_in[0];
  const int*   batch = (const int*)d_in[1];
  const float* w10=(const float*)d_in[2],  *b10=(const float*)d_in[3],  *g10=(const float*)d_in[4],
             *e10=(const float*)d_in[5],  *m10=(const float*)d_in[6],  *v10=(const float*)d_in[7];
  const float* w11=(const float*)d_in[8],  *b11=(const float*)d_in[9],  *g11=(const float*)d_in[10],
             *e11=(const float*)d_in[11], *m11=(const float*)d_in[12], *v11=(const float*)d_in[13];
  const float* w12=(const float*)d_in[14], *b12=(const float*)d_in[15], *g12=(const float*)d_in[16],
             *e12=(const float*)d_in[17], *m12=(const float*)d_in[18], *v12=(const float*)d_in[19];
  const float* w20=(const float*)d_in[20], *b20=(const float*)d_in[21], *g20=(const float*)d_in[22],
             *e20=(const float*)d_in[23], *m20=(const float*)d_in[24], *v20=(const float*)d_in[25];

  float* ws  = (float*)d_ws;
  float* out = (float*)d_out;
  int*   idxp = (int*)(ws + oIDX);

  k_prep<<<1,128,0,stream>>>(w10,b10,g10,e10,m10,v10, w11,b11,g11,e11,m11,v11,
                             w12,b12,g12,e12,m12,v12, w20,b20,g20,e20,m20,v20, ws);
  k_knn1<<<NPTS/8, 512, 0, stream>>>(x, idxp);
  k_ab1<<<NPTS/256, 256, 0, stream>>>(x, ws, ws+oA1, ws+oB1);
  k_ec1m<<<NPTS/4, 256, 0, stream>>>(idxp, ws, ws+oA1, ws+oB1, ws+oX1, ws+oSQ, out);

  size_t wsFloats = ws_size/4;
  long avail = (long)wsFloats - (long)oD;
  int CE = (int)(avail / (2048L*2048L));
  if (CE < 1) CE = 1;
  if (CE > 8) CE = 8;
  for (int e0=0; e0<B_EV; e0+=CE){
    int ce = (B_EV - e0 < CE) ? (B_EV - e0) : CE;
    k_dist2<<<dim3(32,32,ce),256,0,stream>>>(ws+oX1, ws+oSQ, ws+oD, e0);
    k_sel2<<<ce*512,256,0,stream>>>(ws+oD, idxp, e0);
  }

  k_uv2<<<dim3(NPTS/256,4),256,0,stream>>>(ws+oX1, ws, ws+oU2, ws+oV2);
  k_gather2<<<dim3(NPTS/256,2),256,0,stream>>>(idxp, ws+oU2, ws+oV2, ws, out);
  k_batchf<<<NPTS/256,256,0,stream>>>(batch, out);
}

// Round 7
// 1171.433 us; speedup vs baseline: 1.7103x; 1.0093x over previous
//
#include <hip/hip_runtime.h>

#define B_EV 32
#define P_PT 2048
#define K_NN 20
#define NPTS (B_EV*P_PT)
#define EPS_BN 1e-5f
#define RINF 3.0e38f

typedef _Float16 half8 __attribute__((ext_vector_type(8)));
typedef float f32x4 __attribute__((ext_vector_type(4)));

// ---------------- ws layout (float offsets) ----------------
static constexpr int oWA10=0, oWB10=448, oB10=896, oT10=960,
  oT11=5184,
  oT12=9408,
  oWA20=9472, oWB20=17664, oB20=25856, oT20=25984,
  oB11p=26048, oB12p=26112,
  oW11hi=26176, oW11lo=28224,   // each 64x64 f16 == 2048 floats, layout [n][k]
  oW12hi=30272, oW12lo=32320;
static constexpr size_t oIDX = 36864;                      // int region, NPTS*20 ints
static constexpr size_t oA1  = 1347584;                    // NPTS*64 f32
static constexpr size_t oB1  = oA1 + (size_t)NPTS*64;
static constexpr size_t oV2  = oB1 + (size_t)NPTS*64;      // NPTS*128 f32
static constexpr size_t oX1  = oV2 + (size_t)NPTS*128;     // NPTS*64 f32
static constexpr size_t oSQ  = oX1 + (size_t)NPTS*64;      // NPTS f32
static constexpr size_t oD   = oSQ + (size_t)NPTS;         // chunked 2048x2048 dist buf
static constexpr size_t oU2  = oA1;                        // U2 reuses A1+B1 (after ec1)

// ---------------- BN fold + split-f16 weight prep ----------------
__global__ __launch_bounds__(128) void k_prep(
  const float* w10,const float* b10,const float* g10,const float* e10,const float* m10,const float* v10,
  const float* w11,const float* b11,const float* g11,const float* e11,const float* m11,const float* v11,
  const float* w12,const float* b12,const float* g12,const float* e12,const float* m12,const float* v12,
  const float* w20,const float* b20,const float* g20,const float* e20,const float* m20,const float* v20,
  float* ws)
{
  __shared__ float t10s[64], t11s[64];
  int c = threadIdx.x;
  if (c < 64) {
    float s0 = g10[c]*rsqrtf(v10[c]+EPS_BN);
    ws[oB10+c]=b10[c]*s0;
    float t10 = e10[c]-m10[c]*s0; ws[oT10+c]=t10; t10s[c]=t10;
    for (int i=0;i<7;i++){
      ws[oWA10+i*64+c]=(w10[i*64+c]-w10[(7+i)*64+c])*s0;
      ws[oWB10+i*64+c]=w10[(7+i)*64+c]*s0;
    }
    float s1 = g11[c]*rsqrtf(v11[c]+EPS_BN);
    float t11 = e11[c]-m11[c]*s1; ws[oT11+c]=t11; t11s[c]=t11;
    float s2 = g12[c]*rsqrtf(v12[c]+EPS_BN);
    ws[oT12+c]=e12[c]-m12[c]*s2;
  }
  __syncthreads();
  if (c < 64) {
    float s1 = g11[c]*rsqrtf(v11[c]+EPS_BN);
    _Float16* W1hi = (_Float16*)(ws + oW11hi);
    _Float16* W1lo = (_Float16*)(ws + oW11lo);
    float acc = b11[c]*s1;
    for (int i=0;i<64;i++){
      float wv = w11[i*64+c]*s1;
      _Float16 h = (_Float16)wv;
      W1hi[c*64+i] = h;                       // [n=c][k=i]
      W1lo[c*64+i] = (_Float16)(wv - (float)h);
      acc = fmaf(t10s[i], wv, acc);
    }
    ws[oB11p+c]=acc;
    float s2 = g12[c]*rsqrtf(v12[c]+EPS_BN);
    _Float16* W2hi = (_Float16*)(ws + oW12hi);
    _Float16* W2lo = (_Float16*)(ws + oW12lo);
    float acc2 = b12[c]*s2;
    for (int i=0;i<64;i++){
      float wv = w12[i*64+c]*s2;
      _Float16 h = (_Float16)wv;
      W2hi[c*64+i] = h;
      W2lo[c*64+i] = (_Float16)(wv - (float)h);
      acc2 = fmaf(t11s[i], wv, acc2);
    }
    ws[oB12p+c]=acc2;
  }
  {
    float s = g20[c]*rsqrtf(v20[c]+EPS_BN);
    ws[oB20+c]=b20[c]*s; ws[oT20+c]=e20[c]-m20[c]*s;
    for (int i=0;i<64;i++){
      ws[oWA20+i*128+c]=(w20[i*128+c]-w20[(64+i)*128+c])*s;
      ws[oWB20+i*128+c]=w20[(64+i)*128+c]*s;
    }
  }
}

// ---------------- exact top-20 per wave (point), d[32] in regs ----------------
__device__ __forceinline__ void select20(float (&d)[32], int lane, int base, int g,
                                         int* __restrict__ idxout)
{
  float g4[4];
  #pragma unroll
  for (int k=0;k<4;k++){
    float m = d[8*k];
    #pragma unroll
    for (int j=1;j<8;j++) m = fminf(m, d[8*k+j]);
    g4[k]=m;
  }
  float T = 0.f;
  #pragma unroll 1
  for (int pass=0; pass<20; ++pass){
    float m = fminf(fminf(g4[0],g4[1]), fminf(g4[2],g4[3]));
    #pragma unroll
    for (int off=32; off>0; off>>=1) m = fminf(m, __shfl_xor(m, off, 64));
    if (pass==19){ T=m; break; }
    #pragma unroll
    for (int k=0;k<4;k++){
      if (g4[k]==m){
        #pragma unroll
        for (int j=0;j<8;j++) d[8*k+j] = (d[8*k+j]==m) ? RINF : d[8*k+j];
        float mm = d[8*k];
        #pragma unroll
        for (int j=1;j<8;j++) mm = fminf(mm, d[8*k+j]);
        g4[k]=mm;
      }
    }
  }
  int cnt=0;
  #pragma unroll
  for (int j=0;j<32;j++){
    bool take = (d[j]>=RINF) || (d[j]==T);
    unsigned long long mb = __ballot(take);
    if (take){
      int pos = cnt + (int)__popcll(mb & ((1ull<<lane)-1ull));
      if (pos < K_NN) idxout[(size_t)g*K_NN + pos] = base + j*64 + lane;
    }
    cnt += (int)__popcll(mb);
  }
  if (lane==0){
    for (int r=cnt; r<K_NN; ++r) idxout[(size_t)g*K_NN + r] = g;
  }
}

// ---------------- kNN on x (C=7), wave per point, event staged in LDS ----------------
// XCD-affinity swizzle: each XCD owns 4 whole events -> x event slice (57KB) L2-resident.
__global__ __launch_bounds__(512) void k_knn1(const float* __restrict__ x, int* __restrict__ idxout)
{
  __shared__ float xs[P_PT*7];
  int t = threadIdx.x;
  int b = blockIdx.x;                              // 8192 blocks
  int xcd = b & 7, kk = b >> 3;                    // kk in [0,1024)
  int e = xcd + ((kk >> 8) << 3);                  // events {xcd, xcd+8, xcd+16, xcd+24}
  int blk = kk & 255;                              // 256 blocks/event, 8 pts each
  const float4* src = (const float4*)(x + (size_t)e*P_PT*7);
  #pragma unroll
  for (int u=0;u<7;u++) ((float4*)xs)[u*512+t] = src[u*512+t];
  __syncthreads();
  int lane = t & 63;
  int g = e*P_PT + blk*8 + (t>>6);
  int pin = g & (P_PT-1);
  float xp[7];
  #pragma unroll
  for (int i=0;i<7;i++) xp[i]=xs[pin*7+i];
  float d[32];
  #pragma unroll
  for (int j=0;j<32;j++){
    const float* xq = xs + (j*64+lane)*7;
    float s=0.f;
    #pragma unroll
    for (int i=0;i<7;i++){ float df=xp[i]-xq[i]; s=fmaf(df,df,s); }
    d[j]=s;
  }
  select20(d, lane, e*P_PT, g, idxout);
}

// ---------------- A/B precompute for EdgeConv1 layer 1 ----------------
__global__ __launch_bounds__(256) void k_ab1(const float* __restrict__ x, const float* __restrict__ W,
                                             float* __restrict__ A1, float* __restrict__ B1)
{
  int g = blockIdx.x*256+threadIdx.x;
  float xi[7];
  #pragma unroll
  for (int i=0;i<7;i++) xi[i]=x[(size_t)g*7+i];
  float a[64], b[64];
  #pragma unroll
  for (int c=0;c<64;c++){ a[c]=W[oB10+c]; b[c]=0.f; }
  #pragma unroll
  for (int i=0;i<7;i++){
    #pragma unroll
    for (int c=0;c<64;c++) a[c]=fmaf(xi[i], W[oWA10+i*64+c], a[c]);
    #pragma unroll
    for (int c=0;c<64;c++) b[c]=fmaf(xi[i], W[oWB10+i*64+c], b[c]);
  }
  #pragma unroll
  for (int c=0;c<64;c+=4){
    float4 oa; oa.x=a[c]; oa.y=a[c+1]; oa.z=a[c+2]; oa.w=a[c+3];
    *(float4*)(A1+(size_t)g*64+c)=oa;
    float4 ob; ob.x=b[c]; ob.y=b[c+1]; ob.z=b[c+2]; ob.w=b[c+3];
    *(float4*)(B1+(size_t)g*64+c)=ob;
  }
}

// ---------------- EdgeConv1 via split-f16 MFMA: wave per point ----------------
// XCD-affinity swizzle (B1 event slice 512KB -> L2-resident on one XCD) and
// hoisted gathers: all 12 float4 loaded up front, all 8 A-fragments converted,
// then nt-outer MFMA blocks with only 4 weight fragments live at a time
// (removes register-pressure motive for the compiler's weight-reload remat).
// Per-accumulator MFMA order unchanged -> bitwise-identical output.
__global__ __launch_bounds__(256, 2) void k_ec1m(const int* __restrict__ idx, const float* __restrict__ ws,
    const float* __restrict__ A1, const float* __restrict__ B1,
    float* __restrict__ x1, float* __restrict__ sqv, float* __restrict__ out)
{
  __shared__ _Float16 h2hi[4][32*64];   // per-wave swizzled H2 hi (4KB each)
  __shared__ _Float16 h2lo[4][32*64];   // per-wave swizzled H2 lo
  int t = threadIdx.x, w = t>>6, lane = t&63;
  int b = blockIdx.x;                    // 16384 blocks
  int xcd = b & 7, kk = b >> 3;          // kk in [0,2048)
  int ev = xcd + ((kk >> 9) << 3);       // events {xcd, xcd+8, xcd+16, xcd+24}
  int i = ev*P_PT + (kk & 511)*4 + w;
  int lg = lane>>4, lr = lane&15;

  int j0 = idx[(size_t)i*K_NN + lr];
  int j1 = (lr < 4) ? idx[(size_t)i*K_NN + 16 + lr] : i;   // rows 20..31 pad (masked later)

  // ---- hoisted gather loads ----
  const float* Ap  = A1 + (size_t)i*64;
  const float* Bp0 = B1 + (size_t)j0*64;
  const float* Bp1 = B1 + (size_t)j1*64;
  float4 av[2][2], bv[2][2][2];
  #pragma unroll
  for (int ks=0;ks<2;ks++){
    int c0 = ks*32 + lg*8;
    av[ks][0]    = *(const float4*)(Ap +c0);
    av[ks][1]    = *(const float4*)(Ap +c0+4);
    bv[0][ks][0] = *(const float4*)(Bp0+c0);
    bv[0][ks][1] = *(const float4*)(Bp0+c0+4);
    bv[1][ks][0] = *(const float4*)(Bp1+c0);
    bv[1][ks][1] = *(const float4*)(Bp1+c0+4);
  }

  // ---- all A-fragments (split-f16) ----
  half8 AH[2][2], AL[2][2];
  #pragma unroll
  for (int m=0;m<2;m++){
    #pragma unroll
    for (int ks=0;ks<2;ks++){
      float hv[8];
      hv[0]=fmaxf(av[ks][0].x+bv[m][ks][0].x,0.f);
      hv[1]=fmaxf(av[ks][0].y+bv[m][ks][0].y,0.f);
      hv[2]=fmaxf(av[ks][0].z+bv[m][ks][0].z,0.f);
      hv[3]=fmaxf(av[ks][0].w+bv[m][ks][0].w,0.f);
      hv[4]=fmaxf(av[ks][1].x+bv[m][ks][1].x,0.f);
      hv[5]=fmaxf(av[ks][1].y+bv[m][ks][1].y,0.f);
      hv[6]=fmaxf(av[ks][1].z+bv[m][ks][1].z,0.f);
      hv[7]=fmaxf(av[ks][1].w+bv[m][ks][1].w,0.f);
      half8 ah, al;
      #pragma unroll
      for (int q=0;q<8;q++){
        _Float16 h = (_Float16)hv[q];
        ah[q]=h; al[q]=(_Float16)(hv[q]-(float)h);
      }
      AH[m][ks]=ah; AL[m][ks]=al;
    }
  }

  // ---- GEMM1: H1 @ W11', nt-outer ----
  f32x4 acc[2][4];
  #pragma unroll
  for (int nt=0;nt<4;nt++){
    float bb = ws[oB11p + nt*16 + lr];
    f32x4 v = {bb,bb,bb,bb};
    acc[0][nt]=v; acc[1][nt]=v;
  }
  {
    const _Float16* W1hi = (const _Float16*)(ws + oW11hi);
    const _Float16* W1lo = (const _Float16*)(ws + oW11lo);
    #pragma unroll
    for (int nt=0;nt<4;nt++){
      const _Float16* whp = W1hi + (nt*16+lr)*64 + lg*8;
      const _Float16* wlp = W1lo + (nt*16+lr)*64 + lg*8;
      half8 wh0 = *(const half8*)(whp);
      half8 wh1 = *(const half8*)(whp+32);
      half8 wl0 = *(const half8*)(wlp);
      half8 wl1 = *(const half8*)(wlp+32);
      #pragma unroll
      for (int m=0;m<2;m++){
        acc[m][nt] = __builtin_amdgcn_mfma_f32_16x16x32_f16(AH[m][0], wh0, acc[m][nt], 0,0,0);
        acc[m][nt] = __builtin_amdgcn_mfma_f32_16x16x32_f16(AL[m][0], wh0, acc[m][nt], 0,0,0);
        acc[m][nt] = __builtin_amdgcn_mfma_f32_16x16x32_f16(AH[m][0], wl0, acc[m][nt], 0,0,0);
        acc[m][nt] = __builtin_amdgcn_mfma_f32_16x16x32_f16(AH[m][1], wh1, acc[m][nt], 0,0,0);
        acc[m][nt] = __builtin_amdgcn_mfma_f32_16x16x32_f16(AL[m][1], wh1, acc[m][nt], 0,0,0);
        acc[m][nt] = __builtin_amdgcn_mfma_f32_16x16x32_f16(AH[m][1], wl1, acc[m][nt], 0,0,0);
      }
    }
  }

  // ---- H2 -> LDS (swizzled hi/lo), relu only (t11 folded into B12p) ----
  _Float16* hbh = h2hi[w];
  _Float16* hbl = h2lo[w];
  #pragma unroll
  for (int m=0;m<2;m++){
    #pragma unroll
    for (int nt=0;nt<4;nt++){
      #pragma unroll
      for (int r=0;r<4;r++){
        int row = m*16 + lg*4 + r;
        int col = nt*16 + lr;
        int baddr = (row*128 + col*2) ^ ((row&7)<<4);
        float v = fmaxf(acc[m][nt][r], 0.f);
        _Float16 vh = (_Float16)v;
        *(_Float16*)((char*)hbh + baddr) = vh;
        *(_Float16*)((char*)hbl + baddr) = (_Float16)(v-(float)vh);
      }
    }
  }

  // ---- GEMM2 A-fragments from LDS ----
  half8 AH2[2][2], AL2[2][2];
  #pragma unroll
  for (int m=0;m<2;m++){
    #pragma unroll
    for (int ks=0;ks<2;ks++){
      int row = m*16 + lr;
      int baddr = (row*128 + (ks*32 + lg*8)*2) ^ ((row&7)<<4);
      AH2[m][ks] = *(const half8*)((char*)hbh + baddr);
      AL2[m][ks] = *(const half8*)((char*)hbl + baddr);
    }
  }

  // ---- GEMM2: H2 @ W12', nt-outer ----
  f32x4 acc2[2][4];
  #pragma unroll
  for (int nt=0;nt<4;nt++){
    float bb = ws[oB12p + nt*16 + lr];
    f32x4 v = {bb,bb,bb,bb};
    acc2[0][nt]=v; acc2[1][nt]=v;
  }
  {
    const _Float16* W2hi = (const _Float16*)(ws + oW12hi);
    const _Float16* W2lo = (const _Float16*)(ws + oW12lo);
    #pragma unroll
    for (int nt=0;nt<4;nt++){
      const _Float16* whp = W2hi + (nt*16+lr)*64 + lg*8;
      const _Float16* wlp = W2lo + (nt*16+lr)*64 + lg*8;
      half8 wh0 = *(const half8*)(whp);
      half8 wh1 = *(const half8*)(whp+32);
      half8 wl0 = *(const half8*)(wlp);
      half8 wl1 = *(const half8*)(wlp+32);
      #pragma unroll
      for (int m=0;m<2;m++){
        acc2[m][nt] = __builtin_amdgcn_mfma_f32_16x16x32_f16(AH2[m][0], wh0, acc2[m][nt], 0,0,0);
        acc2[m][nt] = __builtin_amdgcn_mfma_f32_16x16x32_f16(AL2[m][0], wh0, acc2[m][nt], 0,0,0);
        acc2[m][nt] = __builtin_amdgcn_mfma_f32_16x16x32_f16(AH2[m][0], wl0, acc2[m][nt], 0,0,0);
        acc2[m][nt] = __builtin_amdgcn_mfma_f32_16x16x32_f16(AH2[m][1], wh1, acc2[m][nt], 0,0,0);
        acc2[m][nt] = __builtin_amdgcn_mfma_f32_16x16x32_f16(AL2[m][1], wh1, acc2[m][nt], 0,0,0);
        acc2[m][nt] = __builtin_amdgcn_mfma_f32_16x16x32_f16(AH2[m][1], wl1, acc2[m][nt], 0,0,0);
      }
    }
  }

  // ---- epilogue: max over valid rows (0..19), relu, +t12, write ----
  float fin[4]; float sq = 0.f;
  #pragma unroll
  for (int nt=0;nt<4;nt++){
    float cv = -RINF;
    #pragma unroll
    for (int r=0;r<4;r++) cv = fmaxf(cv, acc2[0][nt][r]);       // rows 0..15 all valid
    if (lg==0){
      #pragma unroll
      for (int r=0;r<4;r++) cv = fmaxf(cv, acc2[1][nt][r]);     // rows 16..19
    }
    cv = fmaxf(cv, __shfl_xor(cv,16,64));
    cv = fmaxf(cv, __shfl_xor(cv,32,64));
    fin[nt] = fmaxf(cv, 0.f) + ws[oT12 + nt*16 + lr];
    sq = fmaf(fin[nt], fin[nt], sq);
  }
  if (lane < 16){
    #pragma unroll
    for (int nt=0;nt<4;nt++){
      x1[(size_t)i*64 + nt*16 + lane] = fin[nt];
      out[(size_t)i*192 + nt*16 + lane] = fin[nt];
    }
  }
  #pragma unroll
  for (int off=1; off<16; off<<=1) sq += __shfl_xor(sq, off, 64);
  if (lane == 0) sqv[i] = sq;
}

// ---------------- kNN2 distance GEMM: D = sq_p + sq_q - 2*x1@x1^T ----------------
// 1D grid with event-per-XCD swizzle when ce==8 (x1 event slice L2-resident).
__global__ __launch_bounds__(256) void k_dist2(const float* __restrict__ x1, const float* __restrict__ sqv,
                                               float* __restrict__ D, int e0, int ce)
{
  __shared__ float As[64][68], Bs[64][68];   // [k][row]
  int b = blockIdx.x;
  int z, inner;
  if (ce == 8){ z = b & 7; inner = b >> 3; }
  else        { z = b / 1024; inner = b % 1024; }
  int by = inner >> 5, bx = inner & 31;
  int e = e0 + z;
  const float* Xe = x1 + (size_t)e*P_PT*64;
  int rb = by*64, cb = bx*64;
  int t = threadIdx.x;
  int tr = t>>4, tk=(t&15)*4;
  #pragma unroll
  for (int rr=0;rr<4;rr++){
    int r = tr + 16*rr;
    float4 va = *(const float4*)(Xe + (size_t)(rb+r)*64 + tk);
    As[tk][r]=va.x; As[tk+1][r]=va.y; As[tk+2][r]=va.z; As[tk+3][r]=va.w;
    float4 vb = *(const float4*)(Xe + (size_t)(cb+r)*64 + tk);
    Bs[tk][r]=vb.x; Bs[tk+1][r]=vb.y; Bs[tk+2][r]=vb.z; Bs[tk+3][r]=vb.w;
  }
  __syncthreads();
  int tx=t&15, ty=t>>4;
  float acc[4][4];
  #pragma unroll
  for (int i=0;i<4;i++){
    #pragma unroll
    for (int j=0;j<4;j++) acc[i][j]=0.f;
  }
  #pragma unroll 4
  for (int k=0;k<64;k++){
    float4 a4 = *(const float4*)(&As[k][ty*4]);
    float4 b4 = *(const float4*)(&Bs[k][tx*4]);
    float a0=a4.x, a1=a4.y, a2=a4.z, a3=a4.w;
    float b0=b4.x, b1=b4.y, b2=b4.z, b3=b4.w;
    acc[0][0]=fmaf(a0,b0,acc[0][0]); acc[0][1]=fmaf(a0,b1,acc[0][1]);
    acc[0][2]=fmaf(a0,b2,acc[0][2]); acc[0][3]=fmaf(a0,b3,acc[0][3]);
    acc[1][0]=fmaf(a1,b0,acc[1][0]); acc[1][1]=fmaf(a1,b1,acc[1][1]);
    acc[1][2]=fmaf(a1,b2,acc[1][2]); acc[1][3]=fmaf(a1,b3,acc[1][3]);
    acc[2][0]=fmaf(a2,b0,acc[2][0]); acc[2][1]=fmaf(a2,b1,acc[2][1]);
    acc[2][2]=fmaf(a2,b2,acc[2][2]); acc[2][3]=fmaf(a2,b3,acc[2][3]);
    acc[3][0]=fmaf(a3,b0,acc[3][0]); acc[3][1]=fmaf(a3,b1,acc[3][1]);
    acc[3][2]=fmaf(a3,b2,acc[3][2]); acc[3][3]=fmaf(a3,b3,acc[3][3]);
  }
  float sr[4], sc[4];
  #pragma unroll
  for (int i=0;i<4;i++){ sr[i]=sqv[e*P_PT + rb+ty*4+i]; sc[i]=sqv[e*P_PT + cb+tx*4+i]; }
  #pragma unroll
  for (int i=0;i<4;i++){
    float4 o;
    o.x = sr[i]+sc[0]-2.f*acc[i][0];
    o.y = sr[i]+sc[1]-2.f*acc[i][1];
    o.z = sr[i]+sc[2]-2.f*acc[i][2];
    o.w = sr[i]+sc[3]-2.f*acc[i][3];
    *(float4*)(D + (size_t)(z*P_PT + rb+ty*4+i)*P_PT + cb + tx*4) = o;
  }
}

// ---------------- kNN2 selection ----------------
__global__ __launch_bounds__(256) void k_sel2(const float* __restrict__ D, int* __restrict__ idxout, int e0)
{
  int t=threadIdx.x, lane=t&63;
  int pl = blockIdx.x*4 + (t>>6);
  int le = pl>>11, pin = pl&(P_PT-1);
  int e = e0 + le;
  int g = e*P_PT + pin;
  const float* Dr = D + (size_t)pl*P_PT;
  float d[32];
  #pragma unroll
  for (int j=0;j<32;j++) d[j]=Dr[j*64+lane];
  select20(d, lane, e*P_PT, g, idxout);
}

// ---------------- EdgeConv2: U = x1@(Wt-Wb)+b, V = x1@Wb ----------------
__global__ __launch_bounds__(256) void k_uv2(const float* __restrict__ x1, const float* __restrict__ W,
                                             float* __restrict__ U2, float* __restrict__ V2)
{
  int g = blockIdx.x*256 + threadIdx.x;
  int half = blockIdx.y & 1;
  bool isU = blockIdx.y < 2;
  const float* Wb = W + (isU?oWA20:oWB20) + half*64;
  float acc[64];
  #pragma unroll
  for (int c=0;c<64;c++) acc[c] = isU ? W[oB20+half*64+c] : 0.f;
  const float* xp = x1 + (size_t)g*64;
  #pragma unroll 1
  for (int i=0;i<64;i+=4){
    float4 xv = *(const float4*)(xp+i);
    #pragma unroll
    for (int c=0;c<64;c++) acc[c]=fmaf(xv.x, Wb[(i+0)*128+c], acc[c]);
    #pragma unroll
    for (int c=0;c<64;c++) acc[c]=fmaf(xv.y, Wb[(i+1)*128+c], acc[c]);
    #pragma unroll
    for (int c=0;c<64;c++) acc[c]=fmaf(xv.z, Wb[(i+2)*128+c], acc[c]);
    #pragma unroll
    for (int c=0;c<64;c++) acc[c]=fmaf(xv.w, Wb[(i+3)*128+c], acc[c]);
  }
  float* dst = (isU?U2:V2) + (size_t)g*128 + half*64;
  #pragma unroll
  for (int c=0;c<64;c+=4){
    float4 o; o.x=acc[c]; o.y=acc[c+1]; o.z=acc[c+2]; o.w=acc[c+3];
    *(float4*)(dst+c)=o;
  }
}

// ---------------- EdgeConv2 gather-max + epilogue ----------------
// XCD-affinity swizzle: V2 event slice (1MB) L2-resident on one XCD.
__global__ __launch_bounds__(256) void k_gather2(const int* __restrict__ idx, const float* __restrict__ U2,
     const float* __restrict__ V2, const float* __restrict__ W, float* __restrict__ out)
{
  int b = blockIdx.x;                    // 256 blocks
  int xcd = b & 7, kk = b >> 3;          // kk in [0,32)
  int ev = xcd + ((kk >> 3) << 3);       // events {xcd, xcd+8, xcd+16, xcd+24}
  int g = ev*P_PT + (kk & 7)*256 + threadIdx.x;
  int half = blockIdx.y;
  float mx[64];
  #pragma unroll
  for (int c=0;c<64;c++) mx[c]=-RINF;
  for (int k=0;k<K_NN;k++){
    int j = idx[(size_t)g*K_NN+k];
    const float4* vp = (const float4*)(V2 + (size_t)j*128 + half*64);
    #pragma unroll
    for (int c4=0;c4<16;c4++){
      float4 v=vp[c4];
      mx[c4*4+0]=fmaxf(mx[c4*4+0],v.x);
      mx[c4*4+1]=fmaxf(mx[c4*4+1],v.y);
      mx[c4*4+2]=fmaxf(mx[c4*4+2],v.z);
      mx[c4*4+3]=fmaxf(mx[c4*4+3],v.w);
    }
  }
  const float* Up = U2 + (size_t)g*128 + half*64;
  float* op = out + (size_t)g*192 + 64 + half*64;
  #pragma unroll
  for (int c=0;c<64;c+=4){
    float4 o;
    o.x = fmaxf(Up[c+0]+mx[c+0],0.f)+W[oT20+half*64+c+0];
    o.y = fmaxf(Up[c+1]+mx[c+1],0.f)+W[oT20+half*64+c+1];
    o.z = fmaxf(Up[c+2]+mx[c+2],0.f)+W[oT20+half*64+c+2];
    o.w = fmaxf(Up[c+3]+mx[c+3],0.f)+W[oT20+half*64+c+3];
    *(float4*)(op+c)=o;
  }
}

// ---------------- batch passthrough ----------------
__global__ __launch_bounds__(256) void k_batchf(const int* __restrict__ batch, float* __restrict__ out){
  int i = blockIdx.x*256+threadIdx.x;
  out[(size_t)NPTS*192 + i] = (float)batch[i];
}

extern "C" void kernel_launch(void* const* d_in, const int* in_sizes, int n_in,
                              void* d_out, int out_size, void* d_ws, size_t ws_size,
                              hipStream_t stream)
{
  const float* x     = (const float*)d_in[0];
  const int*   batch = (const int*)d_in[1];
  const float* w10=(const float*)d_in[2],  *b10=(const float*)d_in[3],  *g10=(const float*)d_in[4],
             *e10=(const float*)d_in[5],  *m10=(const float*)d_in[6],  *v10=(const float*)d_in[7];
  const float* w11=(const float*)d_in[8],  *b11=(const float*)d_in[9],  *g11=(const float*)d_in[10],
             *e11=(const float*)d_in[11], *m11=(const float*)d_in[12], *v11=(const float*)d_in[13];
  const float* w12=(const float*)d_in[14], *b12=(const float*)d_in[15], *g12=(const float*)d_in[16],
             *e12=(const float*)d_in[17], *m12=(const float*)d_in[18], *v12=(const float*)d_in[19];
  const float* w20=(const float*)d_in[20], *b20=(const float*)d_in[21], *g20=(const float*)d_in[22],
             *e20=(const float*)d_in[23], *m20=(const float*)d_in[24], *v20=(const float*)d_in[25];

  float* ws  = (float*)d_ws;
  float* out = (float*)d_out;
  int*   idxp = (int*)(ws + oIDX);

  k_prep<<<1,128,0,stream>>>(w10,b10,g10,e10,m10,v10, w11,b11,g11,e11,m11,v11,
                             w12,b12,g12,e12,m12,v12, w20,b20,g20,e20,m20,v20, ws);
  k_knn1<<<NPTS/8, 512, 0, stream>>>(x, idxp);
  k_ab1<<<NPTS/256, 256, 0, stream>>>(x, ws, ws+oA1, ws+oB1);
  k_ec1m<<<NPTS/4, 256, 0, stream>>>(idxp, ws, ws+oA1, ws+oB1, ws+oX1, ws+oSQ, out);

  size_t wsFloats = ws_size/4;
  long avail = (long)wsFloats - (long)oD;
  int CE = (int)(avail / (2048L*2048L));
  if (CE < 1) CE = 1;
  if (CE > 8) CE = 8;
  for (int e0=0; e0<B_EV; e0+=CE){
    int ce = (B_EV - e0 < CE) ? (B_EV - e0) : CE;
    k_dist2<<<ce*1024,256,0,stream>>>(ws+oX1, ws+oSQ, ws+oD, e0, ce);
    k_sel2<<<ce*512,256,0,stream>>>(ws+oD, idxp, e0);
  }

  k_uv2<<<dim3(NPTS/256,4),256,0,stream>>>(ws+oX1, ws, ws+oU2, ws+oV2);
  k_gather2<<<dim3(NPTS/256,2),256,0,stream>>>(idxp, ws+oU2, ws+oV2, ws, out);
  k_batchf<<<NPTS/256,256,0,stream>>>(batch, out);
}

// Round 8
// 1064.003 us; speedup vs baseline: 1.8830x; 1.1010x over previous
//
#include <hip/hip_runtime.h>

#define B_EV 32
#define P_PT 2048
#define K_NN 20
#define NPTS (B_EV*P_PT)
#define EPS_BN 1e-5f
#define RINF 3.0e38f

typedef _Float16 half8 __attribute__((ext_vector_type(8)));
typedef float f32x4 __attribute__((ext_vector_type(4)));

// ---------------- ws layout (float offsets) ----------------
static constexpr int oWA10=0, oWB10=448, oB10=896, oT10=960,
  oT11=5184,
  oT12=9408,
  oWA20=9472, oWB20=17664, oB20=25856, oT20=25984,
  oB11p=26048, oB12p=26112,
  oW11hi=26176, oW11lo=28224,   // each 64x64 f16 == 2048 floats, layout [n][k]
  oW12hi=30272, oW12lo=32320;
static constexpr size_t oIDX = 36864;                      // int region, NPTS*20 ints
static constexpr size_t oA1  = 1347584;                    // NPTS*64 f32
static constexpr size_t oB1  = oA1 + (size_t)NPTS*64;
static constexpr size_t oV2  = oB1 + (size_t)NPTS*64;      // NPTS*128 f32
static constexpr size_t oX1  = oV2 + (size_t)NPTS*128;     // NPTS*64 f32
static constexpr size_t oSQ  = oX1 + (size_t)NPTS*64;      // NPTS f32
static constexpr size_t oD   = oSQ + (size_t)NPTS;         // chunked 2048x2048 dist buf
static constexpr size_t oU2  = oA1;                        // U2 reuses A1+B1 (after ec1)

// ---------------- BN fold + split-f16 weight prep ----------------
__global__ __launch_bounds__(128) void k_prep(
  const float* w10,const float* b10,const float* g10,const float* e10,const float* m10,const float* v10,
  const float* w11,const float* b11,const float* g11,const float* e11,const float* m11,const float* v11,
  const float* w12,const float* b12,const float* g12,const float* e12,const float* m12,const float* v12,
  const float* w20,const float* b20,const float* g20,const float* e20,const float* m20,const float* v20,
  float* ws)
{
  __shared__ float t10s[64], t11s[64];
  int c = threadIdx.x;
  if (c < 64) {
    float s0 = g10[c]*rsqrtf(v10[c]+EPS_BN);
    ws[oB10+c]=b10[c]*s0;
    float t10 = e10[c]-m10[c]*s0; ws[oT10+c]=t10; t10s[c]=t10;
    for (int i=0;i<7;i++){
      ws[oWA10+i*64+c]=(w10[i*64+c]-w10[(7+i)*64+c])*s0;
      ws[oWB10+i*64+c]=w10[(7+i)*64+c]*s0;
    }
    float s1 = g11[c]*rsqrtf(v11[c]+EPS_BN);
    float t11 = e11[c]-m11[c]*s1; ws[oT11+c]=t11; t11s[c]=t11;
    float s2 = g12[c]*rsqrtf(v12[c]+EPS_BN);
    ws[oT12+c]=e12[c]-m12[c]*s2;
  }
  __syncthreads();
  if (c < 64) {
    float s1 = g11[c]*rsqrtf(v11[c]+EPS_BN);
    _Float16* W1hi = (_Float16*)(ws + oW11hi);
    _Float16* W1lo = (_Float16*)(ws + oW11lo);
    float acc = b11[c]*s1;
    for (int i=0;i<64;i++){
      float wv = w11[i*64+c]*s1;
      _Float16 h = (_Float16)wv;
      W1hi[c*64+i] = h;                       // [n=c][k=i]
      W1lo[c*64+i] = (_Float16)(wv - (float)h);
      acc = fmaf(t10s[i], wv, acc);
    }
    ws[oB11p+c]=acc;
    float s2 = g12[c]*rsqrtf(v12[c]+EPS_BN);
    _Float16* W2hi = (_Float16*)(ws + oW12hi);
    _Float16* W2lo = (_Float16*)(ws + oW12lo);
    float acc2 = b12[c]*s2;
    for (int i=0;i<64;i++){
      float wv = w12[i*64+c]*s2;
      _Float16 h = (_Float16)wv;
      W2hi[c*64+i] = h;
      W2lo[c*64+i] = (_Float16)(wv - (float)h);
      acc2 = fmaf(t11s[i], wv, acc2);
    }
    ws[oB12p+c]=acc2;
  }
  {
    float s = g20[c]*rsqrtf(v20[c]+EPS_BN);
    ws[oB20+c]=b20[c]*s; ws[oT20+c]=e20[c]-m20[c]*s;
    for (int i=0;i<64;i++){
      ws[oWA20+i*128+c]=(w20[i*128+c]-w20[(64+i)*128+c])*s;
      ws[oWB20+i*128+c]=w20[(64+i)*128+c]*s;
    }
  }
}

// ---------------- exact top-20 per wave (point), d[32] in regs ----------------
__device__ __forceinline__ void select20(float (&d)[32], int lane, int base, int g,
                                         int* __restrict__ idxout)
{
  float g4[4];
  #pragma unroll
  for (int k=0;k<4;k++){
    float m = d[8*k];
    #pragma unroll
    for (int j=1;j<8;j++) m = fminf(m, d[8*k+j]);
    g4[k]=m;
  }
  float T = 0.f;
  #pragma unroll 1
  for (int pass=0; pass<20; ++pass){
    float m = fminf(fminf(g4[0],g4[1]), fminf(g4[2],g4[3]));
    #pragma unroll
    for (int off=32; off>0; off>>=1) m = fminf(m, __shfl_xor(m, off, 64));
    if (pass==19){ T=m; break; }
    #pragma unroll
    for (int k=0;k<4;k++){
      if (g4[k]==m){
        #pragma unroll
        for (int j=0;j<8;j++) d[8*k+j] = (d[8*k+j]==m) ? RINF : d[8*k+j];
        float mm = d[8*k];
        #pragma unroll
        for (int j=1;j<8;j++) mm = fminf(mm, d[8*k+j]);
        g4[k]=mm;
      }
    }
  }
  int cnt=0;
  #pragma unroll
  for (int j=0;j<32;j++){
    bool take = (d[j]>=RINF) || (d[j]==T);
    unsigned long long mb = __ballot(take);
    if (take){
      int pos = cnt + (int)__popcll(mb & ((1ull<<lane)-1ull));
      if (pos < K_NN) idxout[(size_t)g*K_NN + pos] = base + j*64 + lane;
    }
    cnt += (int)__popcll(mb);
  }
  if (lane==0){
    for (int r=cnt; r<K_NN; ++r) idxout[(size_t)g*K_NN + r] = g;
  }
}

// ---------------- kNN on x (C=7), wave per point, event staged in LDS ----------------
__global__ __launch_bounds__(512) void k_knn1(const float* __restrict__ x, int* __restrict__ idxout)
{
  __shared__ float xs[P_PT*7];
  int t = threadIdx.x;
  int b = blockIdx.x;                              // 8192 blocks
  int xcd = b & 7, kk = b >> 3;                    // kk in [0,1024)
  int e = xcd + ((kk >> 8) << 3);                  // events {xcd, xcd+8, xcd+16, xcd+24}
  int blk = kk & 255;                              // 256 blocks/event, 8 pts each
  const float4* src = (const float4*)(x + (size_t)e*P_PT*7);
  #pragma unroll
  for (int u=0;u<7;u++) ((float4*)xs)[u*512+t] = src[u*512+t];
  __syncthreads();
  int lane = t & 63;
  int g = e*P_PT + blk*8 + (t>>6);
  int pin = g & (P_PT-1);
  float xp[7];
  #pragma unroll
  for (int i=0;i<7;i++) xp[i]=xs[pin*7+i];
  float d[32];
  #pragma unroll
  for (int j=0;j<32;j++){
    const float* xq = xs + (j*64+lane)*7;
    float s=0.f;
    #pragma unroll
    for (int i=0;i<7;i++){ float df=xp[i]-xq[i]; s=fmaf(df,df,s); }
    d[j]=s;
  }
  select20(d, lane, e*P_PT, g, idxout);
}

// ---------------- A/B precompute for EdgeConv1 layer 1 ----------------
__global__ __launch_bounds__(256) void k_ab1(const float* __restrict__ x, const float* __restrict__ W,
                                             float* __restrict__ A1, float* __restrict__ B1)
{
  int g = blockIdx.x*256+threadIdx.x;
  float xi[7];
  #pragma unroll
  for (int i=0;i<7;i++) xi[i]=x[(size_t)g*7+i];
  float a[64], b[64];
  #pragma unroll
  for (int c=0;c<64;c++){ a[c]=W[oB10+c]; b[c]=0.f; }
  #pragma unroll
  for (int i=0;i<7;i++){
    #pragma unroll
    for (int c=0;c<64;c++) a[c]=fmaf(xi[i], W[oWA10+i*64+c], a[c]);
    #pragma unroll
    for (int c=0;c<64;c++) b[c]=fmaf(xi[i], W[oWB10+i*64+c], b[c]);
  }
  #pragma unroll
  for (int c=0;c<64;c+=4){
    float4 oa; oa.x=a[c]; oa.y=a[c+1]; oa.z=a[c+2]; oa.w=a[c+3];
    *(float4*)(A1+(size_t)g*64+c)=oa;
    float4 ob; ob.x=b[c]; ob.y=b[c+1]; ob.z=b[c+2]; ob.w=b[c+3];
    *(float4*)(B1+(size_t)g*64+c)=ob;
  }
}

// ---------------- EdgeConv1 v3: 2 points per wave, 3 M-tiles, split-f16 MFMA ----------
// Tiles: t0 = A edges 0..15, t1 = B edges 0..15, t2 = [A e16..19 | B e16..19 | 8 pad].
// H2 staged in LDS as f32 (single copy); hi/lo split recomputed identically on read
// -> bitwise-identical x1 vs the 1-point version. Instruction count per point ~1/2.
__global__ __launch_bounds__(256, 2) void k_ec1m(const int* __restrict__ idx, const float* __restrict__ ws,
    const float* __restrict__ A1, const float* __restrict__ B1,
    float* __restrict__ x1, float* __restrict__ sqv, float* __restrict__ out)
{
  __shared__ float h2s[4][48*64];       // 12KB per wave (48 rows x 64 ch f32)
  int t = threadIdx.x, w = t>>6, lane = t&63;
  int b = blockIdx.x;                    // 8192 blocks
  int xcd = b & 7, kk = b >> 3;          // kk in [0,1024)
  int ev = xcd + ((kk >> 8) << 3);       // events {xcd, xcd+8, xcd+16, xcd+24}
  int iA = ev*P_PT + (kk & 255)*8 + w*2;
  int iB = iA + 1;
  int lg = lane>>4, lr = lane&15;

  // ---- neighbor indices ----
  int jT0 = idx[(size_t)iA*K_NN + lr];
  int jT1 = idx[(size_t)iB*K_NN + lr];
  int a2 = (lr < 4) ? iA*K_NN + 16 + lr : iB*K_NN + 12 + lr;  // lr in [4,8): iB*20+16+(lr-4)
  a2 = (lr < 8) ? a2 : 0;
  int jT2 = (lr < 8) ? idx[a2] : iA;                           // rows 8..15 pad (masked later)

  // ---- hoisted gathers ----
  const float* ApA = A1 + (size_t)iA*64;
  const float* ApB = A1 + (size_t)iB*64;
  float4 avA[2][2], avB[2][2], bv[3][2][2];
  const float* Bp0 = B1 + (size_t)jT0*64;
  const float* Bp1 = B1 + (size_t)jT1*64;
  const float* Bp2 = B1 + (size_t)jT2*64;
  #pragma unroll
  for (int ks=0;ks<2;ks++){
    int c0 = ks*32 + lg*8;
    avA[ks][0] = *(const float4*)(ApA+c0); avA[ks][1] = *(const float4*)(ApA+c0+4);
    avB[ks][0] = *(const float4*)(ApB+c0); avB[ks][1] = *(const float4*)(ApB+c0+4);
    bv[0][ks][0] = *(const float4*)(Bp0+c0); bv[0][ks][1] = *(const float4*)(Bp0+c0+4);
    bv[1][ks][0] = *(const float4*)(Bp1+c0); bv[1][ks][1] = *(const float4*)(Bp1+c0+4);
    bv[2][ks][0] = *(const float4*)(Bp2+c0); bv[2][ks][1] = *(const float4*)(Bp2+c0+4);
  }

  // ---- A-fragments (split-f16): tile2's A-row is lr-dependent ----
  bool useB2 = (lr >= 4) && (lr < 8);
  half8 AH[3][2], AL[3][2];
  #pragma unroll
  for (int tile=0;tile<3;tile++){
    #pragma unroll
    for (int ks=0;ks<2;ks++){
      float4 a0, a1;
      if (tile==0){ a0 = avA[ks][0]; a1 = avA[ks][1]; }
      else if (tile==1){ a0 = avB[ks][0]; a1 = avB[ks][1]; }
      else {
        a0.x = useB2 ? avB[ks][0].x : avA[ks][0].x;  a0.y = useB2 ? avB[ks][0].y : avA[ks][0].y;
        a0.z = useB2 ? avB[ks][0].z : avA[ks][0].z;  a0.w = useB2 ? avB[ks][0].w : avA[ks][0].w;
        a1.x = useB2 ? avB[ks][1].x : avA[ks][1].x;  a1.y = useB2 ? avB[ks][1].y : avA[ks][1].y;
        a1.z = useB2 ? avB[ks][1].z : avA[ks][1].z;  a1.w = useB2 ? avB[ks][1].w : avA[ks][1].w;
      }
      float hv[8];
      hv[0]=fmaxf(a0.x+bv[tile][ks][0].x,0.f); hv[1]=fmaxf(a0.y+bv[tile][ks][0].y,0.f);
      hv[2]=fmaxf(a0.z+bv[tile][ks][0].z,0.f); hv[3]=fmaxf(a0.w+bv[tile][ks][0].w,0.f);
      hv[4]=fmaxf(a1.x+bv[tile][ks][1].x,0.f); hv[5]=fmaxf(a1.y+bv[tile][ks][1].y,0.f);
      hv[6]=fmaxf(a1.z+bv[tile][ks][1].z,0.f); hv[7]=fmaxf(a1.w+bv[tile][ks][1].w,0.f);
      half8 ah, al;
      #pragma unroll
      for (int q=0;q<8;q++){
        _Float16 h = (_Float16)hv[q];
        ah[q]=h; al[q]=(_Float16)(hv[q]-(float)h);
      }
      AH[tile][ks]=ah; AL[tile][ks]=al;
    }
  }

  // ---- GEMM1: nt-outer, 72 MFMAs ----
  f32x4 acc[3][4];
  #pragma unroll
  for (int nt=0;nt<4;nt++){
    float bb = ws[oB11p + nt*16 + lr];
    f32x4 v = {bb,bb,bb,bb};
    acc[0][nt]=v; acc[1][nt]=v; acc[2][nt]=v;
  }
  {
    const _Float16* W1hi = (const _Float16*)(ws + oW11hi);
    const _Float16* W1lo = (const _Float16*)(ws + oW11lo);
    #pragma unroll
    for (int nt=0;nt<4;nt++){
      const _Float16* whp = W1hi + (nt*16+lr)*64 + lg*8;
      const _Float16* wlp = W1lo + (nt*16+lr)*64 + lg*8;
      half8 wh0 = *(const half8*)(whp);
      half8 wh1 = *(const half8*)(whp+32);
      half8 wl0 = *(const half8*)(wlp);
      half8 wl1 = *(const half8*)(wlp+32);
      #pragma unroll
      for (int tile=0;tile<3;tile++){
        acc[tile][nt] = __builtin_amdgcn_mfma_f32_16x16x32_f16(AH[tile][0], wh0, acc[tile][nt], 0,0,0);
        acc[tile][nt] = __builtin_amdgcn_mfma_f32_16x16x32_f16(AL[tile][0], wh0, acc[tile][nt], 0,0,0);
        acc[tile][nt] = __builtin_amdgcn_mfma_f32_16x16x32_f16(AH[tile][0], wl0, acc[tile][nt], 0,0,0);
        acc[tile][nt] = __builtin_amdgcn_mfma_f32_16x16x32_f16(AH[tile][1], wh1, acc[tile][nt], 0,0,0);
        acc[tile][nt] = __builtin_amdgcn_mfma_f32_16x16x32_f16(AL[tile][1], wh1, acc[tile][nt], 0,0,0);
        acc[tile][nt] = __builtin_amdgcn_mfma_f32_16x16x32_f16(AH[tile][1], wl1, acc[tile][nt], 0,0,0);
      }
    }
  }

  // ---- H2 -> LDS (f32 single copy, swizzled), relu only ----
  float* hb = h2s[w];
  #pragma unroll
  for (int tile=0;tile<3;tile++){
    #pragma unroll
    for (int nt=0;nt<4;nt++){
      #pragma unroll
      for (int r=0;r<4;r++){
        int row = tile*16 + lg*4 + r;
        int col = nt*16 + lr;
        int baddr = (row*256 + col*4) ^ ((row&7)<<4);
        *(float*)((char*)hb + baddr) = fmaxf(acc[tile][nt][r], 0.f);
      }
    }
  }

  // ---- GEMM2 A-fragments from LDS (split on read: identical hi/lo values) ----
  half8 AH2[3][2], AL2[3][2];
  #pragma unroll
  for (int tile=0;tile<3;tile++){
    #pragma unroll
    for (int ks=0;ks<2;ks++){
      int row = tile*16 + lr;
      int byte0 = (row*256 + (ks*32 + lg*8)*4);
      int s = (row&7)<<4;
      f32x4 v0 = *(const f32x4*)((char*)hb + ((byte0)^s));
      f32x4 v1 = *(const f32x4*)((char*)hb + ((byte0+16)^s));
      half8 ah, al;
      #pragma unroll
      for (int q=0;q<4;q++){
        _Float16 h = (_Float16)v0[q];
        ah[q]=h; al[q]=(_Float16)(v0[q]-(float)h);
      }
      #pragma unroll
      for (int q=0;q<4;q++){
        _Float16 h = (_Float16)v1[q];
        ah[4+q]=h; al[4+q]=(_Float16)(v1[q]-(float)h);
      }
      AH2[tile][ks]=ah; AL2[tile][ks]=al;
    }
  }

  // ---- GEMM2: nt-outer, 72 MFMAs ----
  f32x4 acc2[3][4];
  #pragma unroll
  for (int nt=0;nt<4;nt++){
    float bb = ws[oB12p + nt*16 + lr];
    f32x4 v = {bb,bb,bb,bb};
    acc2[0][nt]=v; acc2[1][nt]=v; acc2[2][nt]=v;
  }
  {
    const _Float16* W2hi = (const _Float16*)(ws + oW12hi);
    const _Float16* W2lo = (const _Float16*)(ws + oW12lo);
    #pragma unroll
    for (int nt=0;nt<4;nt++){
      const _Float16* whp = W2hi + (nt*16+lr)*64 + lg*8;
      const _Float16* wlp = W2lo + (nt*16+lr)*64 + lg*8;
      half8 wh0 = *(const half8*)(whp);
      half8 wh1 = *(const half8*)(whp+32);
      half8 wl0 = *(const half8*)(wlp);
      half8 wl1 = *(const half8*)(wlp+32);
      #pragma unroll
      for (int tile=0;tile<3;tile++){
        acc2[tile][nt] = __builtin_amdgcn_mfma_f32_16x16x32_f16(AH2[tile][0], wh0, acc2[tile][nt], 0,0,0);
        acc2[tile][nt] = __builtin_amdgcn_mfma_f32_16x16x32_f16(AL2[tile][0], wh0, acc2[tile][nt], 0,0,0);
        acc2[tile][nt] = __builtin_amdgcn_mfma_f32_16x16x32_f16(AH2[tile][0], wl0, acc2[tile][nt], 0,0,0);
        acc2[tile][nt] = __builtin_amdgcn_mfma_f32_16x16x32_f16(AH2[tile][1], wh1, acc2[tile][nt], 0,0,0);
        acc2[tile][nt] = __builtin_amdgcn_mfma_f32_16x16x32_f16(AL2[tile][1], wh1, acc2[tile][nt], 0,0,0);
        acc2[tile][nt] = __builtin_amdgcn_mfma_f32_16x16x32_f16(AH2[tile][1], wl1, acc2[tile][nt], 0,0,0);
      }
    }
  }

  // ---- epilogue: per-point max over valid edge rows, relu, +t12, write ----
  // C-layout rows within a tile: 4*lg + reg. Tile2 rows 0..3 (lg==0) = A e16..19,
  // rows 4..7 (lg==1) = B e16..19, rows >=8 pad (never read).
  float finA[4], finB[4];
  float sqA = 0.f, sqB = 0.f;
  #pragma unroll
  for (int nt=0;nt<4;nt++){
    float cvA = -RINF;
    #pragma unroll
    for (int r=0;r<4;r++) cvA = fmaxf(cvA, acc2[0][nt][r]);
    if (lg==0){
      #pragma unroll
      for (int r=0;r<4;r++) cvA = fmaxf(cvA, acc2[2][nt][r]);
    }
    cvA = fmaxf(cvA, __shfl_xor(cvA,16,64));
    cvA = fmaxf(cvA, __shfl_xor(cvA,32,64));
    finA[nt] = fmaxf(cvA, 0.f) + ws[oT12 + nt*16 + lr];
    sqA = fmaf(finA[nt], finA[nt], sqA);

    float cvB = -RINF;
    #pragma unroll
    for (int r=0;r<4;r++) cvB = fmaxf(cvB, acc2[1][nt][r]);
    if (lg==1){
      #pragma unroll
      for (int r=0;r<4;r++) cvB = fmaxf(cvB, acc2[2][nt][r]);
    }
    cvB = fmaxf(cvB, __shfl_xor(cvB,16,64));
    cvB = fmaxf(cvB, __shfl_xor(cvB,32,64));
    finB[nt] = fmaxf(cvB, 0.f) + ws[oT12 + nt*16 + lr];
    sqB = fmaf(finB[nt], finB[nt], sqB);
  }
  if (lane < 16){
    #pragma unroll
    for (int nt=0;nt<4;nt++){
      x1[(size_t)iA*64 + nt*16 + lane] = finA[nt];
      out[(size_t)iA*192 + nt*16 + lane] = finA[nt];
      x1[(size_t)iB*64 + nt*16 + lane] = finB[nt];
      out[(size_t)iB*192 + nt*16 + lane] = finB[nt];
    }
  }
  #pragma unroll
  for (int off=1; off<16; off<<=1){
    sqA += __shfl_xor(sqA, off, 64);
    sqB += __shfl_xor(sqB, off, 64);
  }
  if (lane == 0){ sqv[iA] = sqA; sqv[iB] = sqB; }
}

// ---------------- kNN2 distance GEMM: D = sq_p + sq_q - 2*x1@x1^T ----------------
__global__ __launch_bounds__(256) void k_dist2(const float* __restrict__ x1, const float* __restrict__ sqv,
                                               float* __restrict__ D, int e0, int ce)
{
  __shared__ float As[64][68], Bs[64][68];   // [k][row]
  int b = blockIdx.x;
  int z, inner;
  if (ce == 8){ z = b & 7; inner = b >> 3; }
  else        { z = b / 1024; inner = b % 1024; }
  int by = inner >> 5, bx = inner & 31;
  int e = e0 + z;
  const float* Xe = x1 + (size_t)e*P_PT*64;
  int rb = by*64, cb = bx*64;
  int t = threadIdx.x;
  int tr = t>>4, tk=(t&15)*4;
  #pragma unroll
  for (int rr=0;rr<4;rr++){
    int r = tr + 16*rr;
    float4 va = *(const float4*)(Xe + (size_t)(rb+r)*64 + tk);
    As[tk][r]=va.x; As[tk+1][r]=va.y; As[tk+2][r]=va.z; As[tk+3][r]=va.w;
    float4 vb = *(const float4*)(Xe + (size_t)(cb+r)*64 + tk);
    Bs[tk][r]=vb.x; Bs[tk+1][r]=vb.y; Bs[tk+2][r]=vb.z; Bs[tk+3][r]=vb.w;
  }
  __syncthreads();
  int tx=t&15, ty=t>>4;
  float acc[4][4];
  #pragma unroll
  for (int i=0;i<4;i++){
    #pragma unroll
    for (int j=0;j<4;j++) acc[i][j]=0.f;
  }
  #pragma unroll 4
  for (int k=0;k<64;k++){
    float4 a4 = *(const float4*)(&As[k][ty*4]);
    float4 b4 = *(const float4*)(&Bs[k][tx*4]);
    float a0=a4.x, a1=a4.y, a2=a4.z, a3=a4.w;
    float b0=b4.x, b1=b4.y, b2=b4.z, b3=b4.w;
    acc[0][0]=fmaf(a0,b0,acc[0][0]); acc[0][1]=fmaf(a0,b1,acc[0][1]);
    acc[0][2]=fmaf(a0,b2,acc[0][2]); acc[0][3]=fmaf(a0,b3,acc[0][3]);
    acc[1][0]=fmaf(a1,b0,acc[1][0]); acc[1][1]=fmaf(a1,b1,acc[1][1]);
    acc[1][2]=fmaf(a1,b2,acc[1][2]); acc[1][3]=fmaf(a1,b3,acc[1][3]);
    acc[2][0]=fmaf(a2,b0,acc[2][0]); acc[2][1]=fmaf(a2,b1,acc[2][1]);
    acc[2][2]=fmaf(a2,b2,acc[2][2]); acc[2][3]=fmaf(a2,b3,acc[2][3]);
    acc[3][0]=fmaf(a3,b0,acc[3][0]); acc[3][1]=fmaf(a3,b1,acc[3][1]);
    acc[3][2]=fmaf(a3,b2,acc[3][2]); acc[3][3]=fmaf(a3,b3,acc[3][3]);
  }
  float sr[4], sc[4];
  #pragma unroll
  for (int i=0;i<4;i++){ sr[i]=sqv[e*P_PT + rb+ty*4+i]; sc[i]=sqv[e*P_PT + cb+tx*4+i]; }
  #pragma unroll
  for (int i=0;i<4;i++){
    float4 o;
    o.x = sr[i]+sc[0]-2.f*acc[i][0];
    o.y = sr[i]+sc[1]-2.f*acc[i][1];
    o.z = sr[i]+sc[2]-2.f*acc[i][2];
    o.w = sr[i]+sc[3]-2.f*acc[i][3];
    *(float4*)(D + (size_t)(z*P_PT + rb+ty*4+i)*P_PT + cb + tx*4) = o;
  }
}

// ---------------- kNN2 selection ----------------
__global__ __launch_bounds__(256) void k_sel2(const float* __restrict__ D, int* __restrict__ idxout, int e0)
{
  int t=threadIdx.x, lane=t&63;
  int pl = blockIdx.x*4 + (t>>6);
  int le = pl>>11, pin = pl&(P_PT-1);
  int e = e0 + le;
  int g = e*P_PT + pin;
  const float* Dr = D + (size_t)pl*P_PT;
  float d[32];
  #pragma unroll
  for (int j=0;j<32;j++) d[j]=Dr[j*64+lane];
  select20(d, lane, e*P_PT, g, idxout);
}

// ---------------- EdgeConv2: U = x1@(Wt-Wb)+b, V = x1@Wb ----------------
__global__ __launch_bounds__(256) void k_uv2(const float* __restrict__ x1, const float* __restrict__ W,
                                             float* __restrict__ U2, float* __restrict__ V2)
{
  int g = blockIdx.x*256 + threadIdx.x;
  int half = blockIdx.y & 1;
  bool isU = blockIdx.y < 2;
  const float* Wb = W + (isU?oWA20:oWB20) + half*64;
  float acc[64];
  #pragma unroll
  for (int c=0;c<64;c++) acc[c] = isU ? W[oB20+half*64+c] : 0.f;
  const float* xp = x1 + (size_t)g*64;
  #pragma unroll 1
  for (int i=0;i<64;i+=4){
    float4 xv = *(const float4*)(xp+i);
    #pragma unroll
    for (int c=0;c<64;c++) acc[c]=fmaf(xv.x, Wb[(i+0)*128+c], acc[c]);
    #pragma unroll
    for (int c=0;c<64;c++) acc[c]=fmaf(xv.y, Wb[(i+1)*128+c], acc[c]);
    #pragma unroll
    for (int c=0;c<64;c++) acc[c]=fmaf(xv.z, Wb[(i+2)*128+c], acc[c]);
    #pragma unroll
    for (int c=0;c<64;c++) acc[c]=fmaf(xv.w, Wb[(i+3)*128+c], acc[c]);
  }
  float* dst = (isU?U2:V2) + (size_t)g*128 + half*64;
  #pragma unroll
  for (int c=0;c<64;c+=4){
    float4 o; o.x=acc[c]; o.y=acc[c+1]; o.z=acc[c+2]; o.w=acc[c+3];
    *(float4*)(dst+c)=o;
  }
}

// ---------------- EdgeConv2 gather-max + epilogue ----------------
__global__ __launch_bounds__(256) void k_gather2(const int* __restrict__ idx, const float* __restrict__ U2,
     const float* __restrict__ V2, const float* __restrict__ W, float* __restrict__ out)
{
  int b = blockIdx.x;                    // 256 blocks
  int xcd = b & 7, kk = b >> 3;          // kk in [0,32)
  int ev = xcd + ((kk >> 3) << 3);       // events {xcd, xcd+8, xcd+16, xcd+24}
  int g = ev*P_PT + (kk & 7)*256 + threadIdx.x;
  int half = blockIdx.y;
  float mx[64];
  #pragma unroll
  for (int c=0;c<64;c++) mx[c]=-RINF;
  for (int k=0;k<K_NN;k++){
    int j = idx[(size_t)g*K_NN+k];
    const float4* vp = (const float4*)(V2 + (size_t)j*128 + half*64);
    #pragma unroll
    for (int c4=0;c4<16;c4++){
      float4 v=vp[c4];
      mx[c4*4+0]=fmaxf(mx[c4*4+0],v.x);
      mx[c4*4+1]=fmaxf(mx[c4*4+1],v.y);
      mx[c4*4+2]=fmaxf(mx[c4*4+2],v.z);
      mx[c4*4+3]=fmaxf(mx[c4*4+3],v.w);
    }
  }
  const float* Up = U2 + (size_t)g*128 + half*64;
  float* op = out + (size_t)g*192 + 64 + half*64;
  #pragma unroll
  for (int c=0;c<64;c+=4){
    float4 o;
    o.x = fmaxf(Up[c+0]+mx[c+0],0.f)+W[oT20+half*64+c+0];
    o.y = fmaxf(Up[c+1]+mx[c+1],0.f)+W[oT20+half*64+c+1];
    o.z = fmaxf(Up[c+2]+mx[c+2],0.f)+W[oT20+half*64+c+2];
    o.w = fmaxf(Up[c+3]+mx[c+3],0.f)+W[oT20+half*64+c+3];
    *(float4*)(op+c)=o;
  }
}

// ---------------- batch passthrough ----------------
__global__ __launch_bounds__(256) void k_batchf(const int* __restrict__ batch, float* __restrict__ out){
  int i = blockIdx.x*256+threadIdx.x;
  out[(size_t)NPTS*192 + i] = (float)batch[i];
}

extern "C" void kernel_launch(void* const* d_in, const int* in_sizes, int n_in,
                              void* d_out, int out_size, void* d_ws, size_t ws_size,
                              hipStream_t stream)
{
  const float* x     = (const float*)d_in[0];
  const int*   batch = (const int*)d_in[1];
  const float* w10=(const float*)d_in[2],  *b10=(const float*)d_in[3],  *g10=(const float*)d_in[4],
             *e10=(const float*)d_in[5],  *m10=(const float*)d_in[6],  *v10=(const float*)d_in[7];
  const float* w11=(const float*)d_in[8],  *b11=(const float*)d_in[9],  *g11=(const float*)d_in[10],
             *e11=(const float*)d_in[11], *m11=(const float*)d_in[12], *v11=(const float*)d_in[13];
  const float* w12=(const float*)d_in[14], *b12=(const float*)d_in[15], *g12=(const float*)d_in[16],
             *e12=(const float*)d_in[17], *m12=(const float*)d_in[18], *v12=(const float*)d_in[19];
  const float* w20=(const float*)d_in[20], *b20=(const float*)d_in[21], *g20=(const float*)d_in[22],
             *e20=(const float*)d_in[23], *m20=(const float*)d_in[24], *v20=(const float*)d_in[25];

  float* ws  = (float*)d_ws;
  float* out = (float*)d_out;
  int*   idxp = (int*)(ws + oIDX);

  k_prep<<<1,128,0,stream>>>(w10,b10,g10,e10,m10,v10, w11,b11,g11,e11,m11,v11,
                             w12,b12,g12,e12,m12,v12, w20,b20,g20,e20,m20,v20, ws);
  k_knn1<<<NPTS/8, 512, 0, stream>>>(x, idxp);
  k_ab1<<<NPTS/256, 256, 0, stream>>>(x, ws, ws+oA1, ws+oB1);
  k_ec1m<<<NPTS/8, 256, 0, stream>>>(idxp, ws, ws+oA1, ws+oB1, ws+oX1, ws+oSQ, out);

  size_t wsFloats = ws_size/4;
  long avail = (long)wsFloats - (long)oD;
  int CE = (int)(avail / (2048L*2048L));
  if (CE < 1) CE = 1;
  if (CE > 8) CE = 8;
  for (int e0=0; e0<B_EV; e0+=CE){
    int ce = (B_EV - e0 < CE) ? (B_EV - e0) : CE;
    k_dist2<<<ce*1024,256,0,stream>>>(ws+oX1, ws+oSQ, ws+oD, e0, ce);
    k_sel2<<<ce*512,256,0,stream>>>(ws+oD, idxp, e0);
  }

  k_uv2<<<dim3(NPTS/256,4),256,0,stream>>>(ws+oX1, ws, ws+oU2, ws+oV2);
  k_gather2<<<dim3(NPTS/256,2),256,0,stream>>>(idxp, ws+oU2, ws+oV2, ws, out);
  k_batchf<<<NPTS/256,256,0,stream>>>(batch, out);
}

// Round 9
// 1002.196 us; speedup vs baseline: 1.9992x; 1.0617x over previous
//
#include <hip/hip_runtime.h>

#define B_EV 32
#define P_PT 2048
#define K_NN 20
#define NPTS (B_EV*P_PT)
#define EPS_BN 1e-5f
#define RINF 3.0e38f

typedef _Float16 half8 __attribute__((ext_vector_type(8)));
typedef float f32x4 __attribute__((ext_vector_type(4)));

// ---------------- ws layout (float offsets) ----------------
static constexpr int oWA10=0, oWB10=448, oB10=896, oT10=960,
  oT11=5184,
  oT12=9408,
  oWA20=9472, oWB20=17664, oB20=25856, oT20=25984,
  oB11p=26048, oB12p=26112,
  oW11hi=26176, oW11lo=28224,   // each 64x64 f16 == 2048 floats, layout [n][k]
  oW12hi=30272, oW12lo=32320;
static constexpr size_t oIDX = 36864;                      // int region, NPTS*20 ints
static constexpr size_t oA1  = 1347584;                    // NPTS*64 f32
static constexpr size_t oB1  = oA1 + (size_t)NPTS*64;
static constexpr size_t oV2  = oB1 + (size_t)NPTS*64;      // NPTS*128 f32
static constexpr size_t oX1  = oV2 + (size_t)NPTS*128;     // NPTS*64 f32
static constexpr size_t oSQ  = oX1 + (size_t)NPTS*64;      // NPTS f32
static constexpr size_t oD   = oSQ + (size_t)NPTS;         // chunked 2048x2048 dist buf
static constexpr size_t oU2  = oA1;                        // U2 reuses A1+B1 (after ec1)

// ---------------- BN fold + split-f16 weight prep ----------------
__global__ __launch_bounds__(128) void k_prep(
  const float* w10,const float* b10,const float* g10,const float* e10,const float* m10,const float* v10,
  const float* w11,const float* b11,const float* g11,const float* e11,const float* m11,const float* v11,
  const float* w12,const float* b12,const float* g12,const float* e12,const float* m12,const float* v12,
  const float* w20,const float* b20,const float* g20,const float* e20,const float* m20,const float* v20,
  float* ws)
{
  __shared__ float t10s[64], t11s[64];
  int c = threadIdx.x;
  if (c < 64) {
    float s0 = g10[c]*rsqrtf(v10[c]+EPS_BN);
    ws[oB10+c]=b10[c]*s0;
    float t10 = e10[c]-m10[c]*s0; ws[oT10+c]=t10; t10s[c]=t10;
    for (int i=0;i<7;i++){
      ws[oWA10+i*64+c]=(w10[i*64+c]-w10[(7+i)*64+c])*s0;
      ws[oWB10+i*64+c]=w10[(7+i)*64+c]*s0;
    }
    float s1 = g11[c]*rsqrtf(v11[c]+EPS_BN);
    float t11 = e11[c]-m11[c]*s1; ws[oT11+c]=t11; t11s[c]=t11;
    float s2 = g12[c]*rsqrtf(v12[c]+EPS_BN);
    ws[oT12+c]=e12[c]-m12[c]*s2;
  }
  __syncthreads();
  if (c < 64) {
    float s1 = g11[c]*rsqrtf(v11[c]+EPS_BN);
    _Float16* W1hi = (_Float16*)(ws + oW11hi);
    _Float16* W1lo = (_Float16*)(ws + oW11lo);
    float acc = b11[c]*s1;
    for (int i=0;i<64;i++){
      float wv = w11[i*64+c]*s1;
      _Float16 h = (_Float16)wv;
      W1hi[c*64+i] = h;                       // [n=c][k=i]
      W1lo[c*64+i] = (_Float16)(wv - (float)h);
      acc = fmaf(t10s[i], wv, acc);
    }
    ws[oB11p+c]=acc;
    float s2 = g12[c]*rsqrtf(v12[c]+EPS_BN);
    _Float16* W2hi = (_Float16*)(ws + oW12hi);
    _Float16* W2lo = (_Float16*)(ws + oW12lo);
    float acc2 = b12[c]*s2;
    for (int i=0;i<64;i++){
      float wv = w12[i*64+c]*s2;
      _Float16 h = (_Float16)wv;
      W2hi[c*64+i] = h;
      W2lo[c*64+i] = (_Float16)(wv - (float)h);
      acc2 = fmaf(t11s[i], wv, acc2);
    }
    ws[oB12p+c]=acc2;
  }
  {
    float s = g20[c]*rsqrtf(v20[c]+EPS_BN);
    ws[oB20+c]=b20[c]*s; ws[oT20+c]=e20[c]-m20[c]*s;
    for (int i=0;i<64;i++){
      ws[oWA20+i*128+c]=(w20[i*128+c]-w20[(64+i)*128+c])*s;
      ws[oWB20+i*128+c]=w20[(64+i)*128+c]*s;
    }
  }
}

// ---------------- exact top-20 per wave (point), d[32] in regs ----------------
__device__ __forceinline__ void select20(float (&d)[32], int lane, int base, int g,
                                         int* __restrict__ idxout)
{
  float g4[4];
  #pragma unroll
  for (int k=0;k<4;k++){
    float m = d[8*k];
    #pragma unroll
    for (int j=1;j<8;j++) m = fminf(m, d[8*k+j]);
    g4[k]=m;
  }
  float T = 0.f;
  #pragma unroll 1
  for (int pass=0; pass<20; ++pass){
    float m = fminf(fminf(g4[0],g4[1]), fminf(g4[2],g4[3]));
    #pragma unroll
    for (int off=32; off>0; off>>=1) m = fminf(m, __shfl_xor(m, off, 64));
    if (pass==19){ T=m; break; }
    #pragma unroll
    for (int k=0;k<4;k++){
      if (g4[k]==m){
        #pragma unroll
        for (int j=0;j<8;j++) d[8*k+j] = (d[8*k+j]==m) ? RINF : d[8*k+j];
        float mm = d[8*k];
        #pragma unroll
        for (int j=1;j<8;j++) mm = fminf(mm, d[8*k+j]);
        g4[k]=mm;
      }
    }
  }
  int cnt=0;
  #pragma unroll
  for (int j=0;j<32;j++){
    bool take = (d[j]>=RINF) || (d[j]==T);
    unsigned long long mb = __ballot(take);
    if (take){
      int pos = cnt + (int)__popcll(mb & ((1ull<<lane)-1ull));
      if (pos < K_NN) idxout[(size_t)g*K_NN + pos] = base + j*64 + lane;
    }
    cnt += (int)__popcll(mb);
  }
  if (lane==0){
    for (int r=cnt; r<K_NN; ++r) idxout[(size_t)g*K_NN + r] = g;
  }
}

// ---------------- kNN on x (C=7), wave per point ----------------
// v2: 1024-thread blocks (16 pts/block) -> 2 blocks/CU x 16 waves = 32 waves/CU
// (8/SIMD, HW max) to hide select20's dependent-shfl latency. Event staged at
// stride 8 with XOR swizzle (w = p*8 ^ ((p&7)<<2)): candidate reads become
// 2x ds_read_b128 (8-way quad spread = b128 minimum) instead of 7x ds_read_b32.
// Distance fma chain unchanged (c=0..6 order) -> bitwise-identical idx.
__global__ __launch_bounds__(1024, 8) void k_knn1(const float* __restrict__ x, int* __restrict__ idxout)
{
  __shared__ float xs[P_PT*8];                     // 64KB, swizzled stride-8
  int t = threadIdx.x;
  int b = blockIdx.x;                              // 4096 blocks
  int xcd = b & 7, kk = b >> 3;                    // kk in [0,512)
  int e = xcd + ((kk >> 7) << 3);                  // events {xcd, xcd+8, xcd+16, xcd+24}
  int blk = kk & 127;                              // 128 blocks/event, 16 pts each
  {
    const float* xe = x + (size_t)e*P_PT*7;
    #pragma unroll
    for (int u=0; u<2; u++){
      int p = t + u*1024;
      float v0=xe[p*7+0], v1=xe[p*7+1], v2=xe[p*7+2], v3=xe[p*7+3];
      float v4=xe[p*7+4], v5=xe[p*7+5], v6=xe[p*7+6];
      int s = (p&7)<<2;
      int w0 = (p*8) ^ s;
      int w1 = (p*8+4) ^ s;
      f32x4 lo = {v0,v1,v2,v3};
      f32x4 hi = {v4,v5,v6,0.f};
      *(f32x4*)(xs + w0) = lo;
      *(f32x4*)(xs + w1) = hi;
    }
  }
  __syncthreads();
  int lane = t & 63;
  int g = e*P_PT + blk*16 + (t>>6);
  int pin = g & (P_PT-1);
  float xp[7];
  {
    int s = (pin&7)<<2;
    f32x4 lo = *(const f32x4*)(xs + ((pin*8)^s));
    f32x4 hi = *(const f32x4*)(xs + ((pin*8+4)^s));
    xp[0]=lo[0]; xp[1]=lo[1]; xp[2]=lo[2]; xp[3]=lo[3];
    xp[4]=hi[0]; xp[5]=hi[1]; xp[6]=hi[2];
  }
  int sl = (lane&7)<<2;
  const float* base0 = xs + ((lane*8)^sl);
  const float* base1 = xs + ((lane*8+4)^sl);
  float d[32];
  #pragma unroll
  for (int j=0;j<32;j++){
    f32x4 lo = *(const f32x4*)(base0 + j*512);
    f32x4 hi = *(const f32x4*)(base1 + j*512);
    float s=0.f, df;
    df = xp[0]-lo[0]; s=fmaf(df,df,s);
    df = xp[1]-lo[1]; s=fmaf(df,df,s);
    df = xp[2]-lo[2]; s=fmaf(df,df,s);
    df = xp[3]-lo[3]; s=fmaf(df,df,s);
    df = xp[4]-hi[0]; s=fmaf(df,df,s);
    df = xp[5]-hi[1]; s=fmaf(df,df,s);
    df = xp[6]-hi[2]; s=fmaf(df,df,s);
    d[j]=s;
  }
  select20(d, lane, e*P_PT, g, idxout);
}

// ---------------- A/B precompute for EdgeConv1 layer 1 ----------------
__global__ __launch_bounds__(256) void k_ab1(const float* __restrict__ x, const float* __restrict__ W,
                                             float* __restrict__ A1, float* __restrict__ B1)
{
  int g = blockIdx.x*256+threadIdx.x;
  float xi[7];
  #pragma unroll
  for (int i=0;i<7;i++) xi[i]=x[(size_t)g*7+i];
  float a[64], b[64];
  #pragma unroll
  for (int c=0;c<64;c++){ a[c]=W[oB10+c]; b[c]=0.f; }
  #pragma unroll
  for (int i=0;i<7;i++){
    #pragma unroll
    for (int c=0;c<64;c++) a[c]=fmaf(xi[i], W[oWA10+i*64+c], a[c]);
    #pragma unroll
    for (int c=0;c<64;c++) b[c]=fmaf(xi[i], W[oWB10+i*64+c], b[c]);
  }
  #pragma unroll
  for (int c=0;c<64;c+=4){
    float4 oa; oa.x=a[c]; oa.y=a[c+1]; oa.z=a[c+2]; oa.w=a[c+3];
    *(float4*)(A1+(size_t)g*64+c)=oa;
    float4 ob; ob.x=b[c]; ob.y=b[c+1]; ob.z=b[c+2]; ob.w=b[c+3];
    *(float4*)(B1+(size_t)g*64+c)=ob;
  }
}

// ---------------- EdgeConv1 v3: 2 points per wave, 3 M-tiles, split-f16 MFMA ----------
__global__ __launch_bounds__(256, 2) void k_ec1m(const int* __restrict__ idx, const float* __restrict__ ws,
    const float* __restrict__ A1, const float* __restrict__ B1,
    float* __restrict__ x1, float* __restrict__ sqv, float* __restrict__ out)
{
  __shared__ float h2s[4][48*64];       // 12KB per wave (48 rows x 64 ch f32)
  int t = threadIdx.x, w = t>>6, lane = t&63;
  int b = blockIdx.x;                    // 8192 blocks
  int xcd = b & 7, kk = b >> 3;          // kk in [0,1024)
  int ev = xcd + ((kk >> 8) << 3);       // events {xcd, xcd+8, xcd+16, xcd+24}
  int iA = ev*P_PT + (kk & 255)*8 + w*2;
  int iB = iA + 1;
  int lg = lane>>4, lr = lane&15;

  // ---- neighbor indices ----
  int jT0 = idx[(size_t)iA*K_NN + lr];
  int jT1 = idx[(size_t)iB*K_NN + lr];
  int a2 = (lr < 4) ? iA*K_NN + 16 + lr : iB*K_NN + 12 + lr;
  a2 = (lr < 8) ? a2 : 0;
  int jT2 = (lr < 8) ? idx[a2] : iA;

  // ---- hoisted gathers ----
  const float* ApA = A1 + (size_t)iA*64;
  const float* ApB = A1 + (size_t)iB*64;
  float4 avA[2][2], avB[2][2], bv[3][2][2];
  const float* Bp0 = B1 + (size_t)jT0*64;
  const float* Bp1 = B1 + (size_t)jT1*64;
  const float* Bp2 = B1 + (size_t)jT2*64;
  #pragma unroll
  for (int ks=0;ks<2;ks++){
    int c0 = ks*32 + lg*8;
    avA[ks][0] = *(const float4*)(ApA+c0); avA[ks][1] = *(const float4*)(ApA+c0+4);
    avB[ks][0] = *(const float4*)(ApB+c0); avB[ks][1] = *(const float4*)(ApB+c0+4);
    bv[0][ks][0] = *(const float4*)(Bp0+c0); bv[0][ks][1] = *(const float4*)(Bp0+c0+4);
    bv[1][ks][0] = *(const float4*)(Bp1+c0); bv[1][ks][1] = *(const float4*)(Bp1+c0+4);
    bv[2][ks][0] = *(const float4*)(Bp2+c0); bv[2][ks][1] = *(const float4*)(Bp2+c0+4);
  }

  // ---- A-fragments (split-f16): tile2's A-row is lr-dependent ----
  bool useB2 = (lr >= 4) && (lr < 8);
  half8 AH[3][2], AL[3][2];
  #pragma unroll
  for (int tile=0;tile<3;tile++){
    #pragma unroll
    for (int ks=0;ks<2;ks++){
      float4 a0, a1;
      if (tile==0){ a0 = avA[ks][0]; a1 = avA[ks][1]; }
      else if (tile==1){ a0 = avB[ks][0]; a1 = avB[ks][1]; }
      else {
        a0.x = useB2 ? avB[ks][0].x : avA[ks][0].x;  a0.y = useB2 ? avB[ks][0].y : avA[ks][0].y;
        a0.z = useB2 ? avB[ks][0].z : avA[ks][0].z;  a0.w = useB2 ? avB[ks][0].w : avA[ks][0].w;
        a1.x = useB2 ? avB[ks][1].x : avA[ks][1].x;  a1.y = useB2 ? avB[ks][1].y : avA[ks][1].y;
        a1.z = useB2 ? avB[ks][1].z : avA[ks][1].z;  a1.w = useB2 ? avB[ks][1].w : avA[ks][1].w;
      }
      float hv[8];
      hv[0]=fmaxf(a0.x+bv[tile][ks][0].x,0.f); hv[1]=fmaxf(a0.y+bv[tile][ks][0].y,0.f);
      hv[2]=fmaxf(a0.z+bv[tile][ks][0].z,0.f); hv[3]=fmaxf(a0.w+bv[tile][ks][0].w,0.f);
      hv[4]=fmaxf(a1.x+bv[tile][ks][1].x,0.f); hv[5]=fmaxf(a1.y+bv[tile][ks][1].y,0.f);
      hv[6]=fmaxf(a1.z+bv[tile][ks][1].z,0.f); hv[7]=fmaxf(a1.w+bv[tile][ks][1].w,0.f);
      half8 ah, al;
      #pragma unroll
      for (int q=0;q<8;q++){
        _Float16 h = (_Float16)hv[q];
        ah[q]=h; al[q]=(_Float16)(hv[q]-(float)h);
      }
      AH[tile][ks]=ah; AL[tile][ks]=al;
    }
  }

  // ---- GEMM1: nt-outer, 72 MFMAs ----
  f32x4 acc[3][4];
  #pragma unroll
  for (int nt=0;nt<4;nt++){
    float bb = ws[oB11p + nt*16 + lr];
    f32x4 v = {bb,bb,bb,bb};
    acc[0][nt]=v; acc[1][nt]=v; acc[2][nt]=v;
  }
  {
    const _Float16* W1hi = (const _Float16*)(ws + oW11hi);
    const _Float16* W1lo = (const _Float16*)(ws + oW11lo);
    #pragma unroll
    for (int nt=0;nt<4;nt++){
      const _Float16* whp = W1hi + (nt*16+lr)*64 + lg*8;
      const _Float16* wlp = W1lo + (nt*16+lr)*64 + lg*8;
      half8 wh0 = *(const half8*)(whp);
      half8 wh1 = *(const half8*)(whp+32);
      half8 wl0 = *(const half8*)(wlp);
      half8 wl1 = *(const half8*)(wlp+32);
      #pragma unroll
      for (int tile=0;tile<3;tile++){
        acc[tile][nt] = __builtin_amdgcn_mfma_f32_16x16x32_f16(AH[tile][0], wh0, acc[tile][nt], 0,0,0);
        acc[tile][nt] = __builtin_amdgcn_mfma_f32_16x16x32_f16(AL[tile][0], wh0, acc[tile][nt], 0,0,0);
        acc[tile][nt] = __builtin_amdgcn_mfma_f32_16x16x32_f16(AH[tile][0], wl0, acc[tile][nt], 0,0,0);
        acc[tile][nt] = __builtin_amdgcn_mfma_f32_16x16x32_f16(AH[tile][1], wh1, acc[tile][nt], 0,0,0);
        acc[tile][nt] = __builtin_amdgcn_mfma_f32_16x16x32_f16(AL[tile][1], wh1, acc[tile][nt], 0,0,0);
        acc[tile][nt] = __builtin_amdgcn_mfma_f32_16x16x32_f16(AH[tile][1], wl1, acc[tile][nt], 0,0,0);
      }
    }
  }

  // ---- H2 -> LDS (f32 single copy, swizzled), relu only ----
  float* hb = h2s[w];
  #pragma unroll
  for (int tile=0;tile<3;tile++){
    #pragma unroll
    for (int nt=0;nt<4;nt++){
      #pragma unroll
      for (int r=0;r<4;r++){
        int row = tile*16 + lg*4 + r;
        int col = nt*16 + lr;
        int baddr = (row*256 + col*4) ^ ((row&7)<<4);
        *(float*)((char*)hb + baddr) = fmaxf(acc[tile][nt][r], 0.f);
      }
    }
  }

  // ---- GEMM2 A-fragments from LDS (split on read: identical hi/lo values) ----
  half8 AH2[3][2], AL2[3][2];
  #pragma unroll
  for (int tile=0;tile<3;tile++){
    #pragma unroll
    for (int ks=0;ks<2;ks++){
      int row = tile*16 + lr;
      int byte0 = (row*256 + (ks*32 + lg*8)*4);
      int s = (row&7)<<4;
      f32x4 v0 = *(const f32x4*)((char*)hb + ((byte0)^s));
      f32x4 v1 = *(const f32x4*)((char*)hb + ((byte0+16)^s));
      half8 ah, al;
      #pragma unroll
      for (int q=0;q<4;q++){
        _Float16 h = (_Float16)v0[q];
        ah[q]=h; al[q]=(_Float16)(v0[q]-(float)h);
      }
      #pragma unroll
      for (int q=0;q<4;q++){
        _Float16 h = (_Float16)v1[q];
        ah[4+q]=h; al[4+q]=(_Float16)(v1[q]-(float)h);
      }
      AH2[tile][ks]=ah; AL2[tile][ks]=al;
    }
  }

  // ---- GEMM2: nt-outer, 72 MFMAs ----
  f32x4 acc2[3][4];
  #pragma unroll
  for (int nt=0;nt<4;nt++){
    float bb = ws[oB12p + nt*16 + lr];
    f32x4 v = {bb,bb,bb,bb};
    acc2[0][nt]=v; acc2[1][nt]=v; acc2[2][nt]=v;
  }
  {
    const _Float16* W2hi = (const _Float16*)(ws + oW12hi);
    const _Float16* W2lo = (const _Float16*)(ws + oW12lo);
    #pragma unroll
    for (int nt=0;nt<4;nt++){
      const _Float16* whp = W2hi + (nt*16+lr)*64 + lg*8;
      const _Float16* wlp = W2lo + (nt*16+lr)*64 + lg*8;
      half8 wh0 = *(const half8*)(whp);
      half8 wh1 = *(const half8*)(whp+32);
      half8 wl0 = *(const half8*)(wlp);
      half8 wl1 = *(const half8*)(wlp+32);
      #pragma unroll
      for (int tile=0;tile<3;tile++){
        acc2[tile][nt] = __builtin_amdgcn_mfma_f32_16x16x32_f16(AH2[tile][0], wh0, acc2[tile][nt], 0,0,0);
        acc2[tile][nt] = __builtin_amdgcn_mfma_f32_16x16x32_f16(AL2[tile][0], wh0, acc2[tile][nt], 0,0,0);
        acc2[tile][nt] = __builtin_amdgcn_mfma_f32_16x16x32_f16(AH2[tile][0], wl0, acc2[tile][nt], 0,0,0);
        acc2[tile][nt] = __builtin_amdgcn_mfma_f32_16x16x32_f16(AH2[tile][1], wh1, acc2[tile][nt], 0,0,0);
        acc2[tile][nt] = __builtin_amdgcn_mfma_f32_16x16x32_f16(AL2[tile][1], wh1, acc2[tile][nt], 0,0,0);
        acc2[tile][nt] = __builtin_amdgcn_mfma_f32_16x16x32_f16(AH2[tile][1], wl1, acc2[tile][nt], 0,0,0);
      }
    }
  }

  // ---- epilogue ----
  float finA[4], finB[4];
  float sqA = 0.f, sqB = 0.f;
  #pragma unroll
  for (int nt=0;nt<4;nt++){
    float cvA = -RINF;
    #pragma unroll
    for (int r=0;r<4;r++) cvA = fmaxf(cvA, acc2[0][nt][r]);
    if (lg==0){
      #pragma unroll
      for (int r=0;r<4;r++) cvA = fmaxf(cvA, acc2[2][nt][r]);
    }
    cvA = fmaxf(cvA, __shfl_xor(cvA,16,64));
    cvA = fmaxf(cvA, __shfl_xor(cvA,32,64));
    finA[nt] = fmaxf(cvA, 0.f) + ws[oT12 + nt*16 + lr];
    sqA = fmaf(finA[nt], finA[nt], sqA);

    float cvB = -RINF;
    #pragma unroll
    for (int r=0;r<4;r++) cvB = fmaxf(cvB, acc2[1][nt][r]);
    if (lg==1){
      #pragma unroll
      for (int r=0;r<4;r++) cvB = fmaxf(cvB, acc2[2][nt][r]);
    }
    cvB = fmaxf(cvB, __shfl_xor(cvB,16,64));
    cvB = fmaxf(cvB, __shfl_xor(cvB,32,64));
    finB[nt] = fmaxf(cvB, 0.f) + ws[oT12 + nt*16 + lr];
    sqB = fmaf(finB[nt], finB[nt], sqB);
  }
  if (lane < 16){
    #pragma unroll
    for (int nt=0;nt<4;nt++){
      x1[(size_t)iA*64 + nt*16 + lane] = finA[nt];
      out[(size_t)iA*192 + nt*16 + lane] = finA[nt];
      x1[(size_t)iB*64 + nt*16 + lane] = finB[nt];
      out[(size_t)iB*192 + nt*16 + lane] = finB[nt];
    }
  }
  #pragma unroll
  for (int off=1; off<16; off<<=1){
    sqA += __shfl_xor(sqA, off, 64);
    sqB += __shfl_xor(sqB, off, 64);
  }
  if (lane == 0){ sqv[iA] = sqA; sqv[iB] = sqB; }
}

// ---------------- kNN2 distance GEMM: D = sq_p + sq_q - 2*x1@x1^T ----------------
__global__ __launch_bounds__(256) void k_dist2(const float* __restrict__ x1, const float* __restrict__ sqv,
                                               float* __restrict__ D, int e0, int ce)
{
  __shared__ float As[64][68], Bs[64][68];   // [k][row]
  int b = blockIdx.x;
  int z, inner;
  if (ce == 8){ z = b & 7; inner = b >> 3; }
  else        { z = b / 1024; inner = b % 1024; }
  int by = inner >> 5, bx = inner & 31;
  int e = e0 + z;
  const float* Xe = x1 + (size_t)e*P_PT*64;
  int rb = by*64, cb = bx*64;
  int t = threadIdx.x;
  int tr = t>>4, tk=(t&15)*4;
  #pragma unroll
  for (int rr=0;rr<4;rr++){
    int r = tr + 16*rr;
    float4 va = *(const float4*)(Xe + (size_t)(rb+r)*64 + tk);
    As[tk][r]=va.x; As[tk+1][r]=va.y; As[tk+2][r]=va.z; As[tk+3][r]=va.w;
    float4 vb = *(const float4*)(Xe + (size_t)(cb+r)*64 + tk);
    Bs[tk][r]=vb.x; Bs[tk+1][r]=vb.y; Bs[tk+2][r]=vb.z; Bs[tk+3][r]=vb.w;
  }
  __syncthreads();
  int tx=t&15, ty=t>>4;
  float acc[4][4];
  #pragma unroll
  for (int i=0;i<4;i++){
    #pragma unroll
    for (int j=0;j<4;j++) acc[i][j]=0.f;
  }
  #pragma unroll 4
  for (int k=0;k<64;k++){
    float4 a4 = *(const float4*)(&As[k][ty*4]);
    float4 b4 = *(const float4*)(&Bs[k][tx*4]);
    float a0=a4.x, a1=a4.y, a2=a4.z, a3=a4.w;
    float b0=b4.x, b1=b4.y, b2=b4.z, b3=b4.w;
    acc[0][0]=fmaf(a0,b0,acc[0][0]); acc[0][1]=fmaf(a0,b1,acc[0][1]);
    acc[0][2]=fmaf(a0,b2,acc[0][2]); acc[0][3]=fmaf(a0,b3,acc[0][3]);
    acc[1][0]=fmaf(a1,b0,acc[1][0]); acc[1][1]=fmaf(a1,b1,acc[1][1]);
    acc[1][2]=fmaf(a1,b2,acc[1][2]); acc[1][3]=fmaf(a1,b3,acc[1][3]);
    acc[2][0]=fmaf(a2,b0,acc[2][0]); acc[2][1]=fmaf(a2,b1,acc[2][1]);
    acc[2][2]=fmaf(a2,b2,acc[2][2]); acc[2][3]=fmaf(a2,b3,acc[2][3]);
    acc[3][0]=fmaf(a3,b0,acc[3][0]); acc[3][1]=fmaf(a3,b1,acc[3][1]);
    acc[3][2]=fmaf(a3,b2,acc[3][2]); acc[3][3]=fmaf(a3,b3,acc[3][3]);
  }
  float sr[4], sc[4];
  #pragma unroll
  for (int i=0;i<4;i++){ sr[i]=sqv[e*P_PT + rb+ty*4+i]; sc[i]=sqv[e*P_PT + cb+tx*4+i]; }
  #pragma unroll
  for (int i=0;i<4;i++){
    float4 o;
    o.x = sr[i]+sc[0]-2.f*acc[i][0];
    o.y = sr[i]+sc[1]-2.f*acc[i][1];
    o.z = sr[i]+sc[2]-2.f*acc[i][2];
    o.w = sr[i]+sc[3]-2.f*acc[i][3];
    *(float4*)(D + (size_t)(z*P_PT + rb+ty*4+i)*P_PT + cb + tx*4) = o;
  }
}

// ---------------- kNN2 selection ----------------
__global__ __launch_bounds__(256) void k_sel2(const float* __restrict__ D, int* __restrict__ idxout, int e0)
{
  int t=threadIdx.x, lane=t&63;
  int pl = blockIdx.x*4 + (t>>6);
  int le = pl>>11, pin = pl&(P_PT-1);
  int e = e0 + le;
  int g = e*P_PT + pin;
  const float* Dr = D + (size_t)pl*P_PT;
  float d[32];
  #pragma unroll
  for (int j=0;j<32;j++) d[j]=Dr[j*64+lane];
  select20(d, lane, e*P_PT, g, idxout);
}

// ---------------- EdgeConv2: U = x1@(Wt-Wb)+b, V = x1@Wb ----------------
__global__ __launch_bounds__(256) void k_uv2(const float* __restrict__ x1, const float* __restrict__ W,
                                             float* __restrict__ U2, float* __restrict__ V2)
{
  int g = blockIdx.x*256 + threadIdx.x;
  int half = blockIdx.y & 1;
  bool isU = blockIdx.y < 2;
  const float* Wb = W + (isU?oWA20:oWB20) + half*64;
  float acc[64];
  #pragma unroll
  for (int c=0;c<64;c++) acc[c] = isU ? W[oB20+half*64+c] : 0.f;
  const float* xp = x1 + (size_t)g*64;
  #pragma unroll 1
  for (int i=0;i<64;i+=4){
    float4 xv = *(const float4*)(xp+i);
    #pragma unroll
    for (int c=0;c<64;c++) acc[c]=fmaf(xv.x, Wb[(i+0)*128+c], acc[c]);
    #pragma unroll
    for (int c=0;c<64;c++) acc[c]=fmaf(xv.y, Wb[(i+1)*128+c], acc[c]);
    #pragma unroll
    for (int c=0;c<64;c++) acc[c]=fmaf(xv.z, Wb[(i+2)*128+c], acc[c]);
    #pragma unroll
    for (int c=0;c<64;c++) acc[c]=fmaf(xv.w, Wb[(i+3)*128+c], acc[c]);
  }
  float* dst = (isU?U2:V2) + (size_t)g*128 + half*64;
  #pragma unroll
  for (int c=0;c<64;c+=4){
    float4 o; o.x=acc[c]; o.y=acc[c+1]; o.z=acc[c+2]; o.w=acc[c+3];
    *(float4*)(dst+c)=o;
  }
}

// ---------------- EdgeConv2 gather-max + epilogue ----------------
__global__ __launch_bounds__(256) void k_gather2(const int* __restrict__ idx, const float* __restrict__ U2,
     const float* __restrict__ V2, const float* __restrict__ W, float* __restrict__ out)
{
  int b = blockIdx.x;                    // 256 blocks
  int xcd = b & 7, kk = b >> 3;          // kk in [0,32)
  int ev = xcd + ((kk >> 3) << 3);       // events {xcd, xcd+8, xcd+16, xcd+24}
  int g = ev*P_PT + (kk & 7)*256 + threadIdx.x;
  int half = blockIdx.y;
  float mx[64];
  #pragma unroll
  for (int c=0;c<64;c++) mx[c]=-RINF;
  for (int k=0;k<K_NN;k++){
    int j = idx[(size_t)g*K_NN+k];
    const float4* vp = (const float4*)(V2 + (size_t)j*128 + half*64);
    #pragma unroll
    for (int c4=0;c4<16;c4++){
      float4 v=vp[c4];
      mx[c4*4+0]=fmaxf(mx[c4*4+0],v.x);
      mx[c4*4+1]=fmaxf(mx[c4*4+1],v.y);
      mx[c4*4+2]=fmaxf(mx[c4*4+2],v.z);
      mx[c4*4+3]=fmaxf(mx[c4*4+3],v.w);
    }
  }
  const float* Up = U2 + (size_t)g*128 + half*64;
  float* op = out + (size_t)g*192 + 64 + half*64;
  #pragma unroll
  for (int c=0;c<64;c+=4){
    float4 o;
    o.x = fmaxf(Up[c+0]+mx[c+0],0.f)+W[oT20+half*64+c+0];
    o.y = fmaxf(Up[c+1]+mx[c+1],0.f)+W[oT20+half*64+c+1];
    o.z = fmaxf(Up[c+2]+mx[c+2],0.f)+W[oT20+half*64+c+2];
    o.w = fmaxf(Up[c+3]+mx[c+3],0.f)+W[oT20+half*64+c+3];
    *(float4*)(op+c)=o;
  }
}

// ---------------- batch passthrough ----------------
__global__ __launch_bounds__(256) void k_batchf(const int* __restrict__ batch, float* __restrict__ out){
  int i = blockIdx.x*256+threadIdx.x;
  out[(size_t)NPTS*192 + i] = (float)batch[i];
}

extern "C" void kernel_launch(void* const* d_in, const int* in_sizes, int n_in,
                              void* d_out, int out_size, void* d_ws, size_t ws_size,
                              hipStream_t stream)
{
  const float* x     = (const float*)d_in[0];
  const int*   batch = (const int*)d_in[1];
  const float* w10=(const float*)d_in[2],  *b10=(const float*)d_in[3],  *g10=(const float*)d_in[4],
             *e10=(const float*)d_in[5],  *m10=(const float*)d_in[6],  *v10=(const float*)d_in[7];
  const float* w11=(const float*)d_in[8],  *b11=(const float*)d_in[9],  *g11=(const float*)d_in[10],
             *e11=(const float*)d_in[11], *m11=(const float*)d_in[12], *v11=(const float*)d_in[13];
  const float* w12=(const float*)d_in[14], *b12=(const float*)d_in[15], *g12=(const float*)d_in[16],
             *e12=(const float*)d_in[17], *m12=(const float*)d_in[18], *v12=(const float*)d_in[19];
  const float* w20=(const float*)d_in[20], *b20=(const float*)d_in[21], *g20=(const float*)d_in[22],
             *e20=(const float*)d_in[23], *m20=(const float*)d_in[24], *v20=(const float*)d_in[25];

  float* ws  = (float*)d_ws;
  float* out = (float*)d_out;
  int*   idxp = (int*)(ws + oIDX);

  k_prep<<<1,128,0,stream>>>(w10,b10,g10,e10,m10,v10, w11,b11,g11,e11,m11,v11,
                             w12,b12,g12,e12,m12,v12, w20,b20,g20,e20,m20,v20, ws);
  k_knn1<<<NPTS/16, 1024, 0, stream>>>(x, idxp);
  k_ab1<<<NPTS/256, 256, 0, stream>>>(x, ws, ws+oA1, ws+oB1);
  k_ec1m<<<NPTS/8, 256, 0, stream>>>(idxp, ws, ws+oA1, ws+oB1, ws+oX1, ws+oSQ, out);

  size_t wsFloats = ws_size/4;
  long avail = (long)wsFloats - (long)oD;
  int CE = (int)(avail / (2048L*2048L));
  if (CE < 1) CE = 1;
  if (CE > 8) CE = 8;
  for (int e0=0; e0<B_EV; e0+=CE){
    int ce = (B_EV - e0 < CE) ? (B_EV - e0) : CE;
    k_dist2<<<ce*1024,256,0,stream>>>(ws+oX1, ws+oSQ, ws+oD, e0, ce);
    k_sel2<<<ce*512,256,0,stream>>>(ws+oD, idxp, e0);
  }

  k_uv2<<<dim3(NPTS/256,4),256,0,stream>>>(ws+oX1, ws, ws+oU2, ws+oV2);
  k_gather2<<<dim3(NPTS/256,2),256,0,stream>>>(idxp, ws+oU2, ws+oV2, ws, out);
  k_batchf<<<NPTS/256,256,0,stream>>>(batch, out);
}